// Round 11
// baseline (9454.317 us; speedup 1.0000x reference)
//
#include <hip/hip_runtime.h>
#include <hip/hip_bf16.h>

typedef __attribute__((ext_vector_type(4))) float f32x4;
typedef __attribute__((ext_vector_type(8))) short short8;
typedef __attribute__((ext_vector_type(4))) unsigned short us4;

static __device__ __forceinline__ unsigned short f2bf(float f){
  return __builtin_bit_cast(unsigned short, __float2bfloat16(f));
}
static __device__ __forceinline__ float bf2f(unsigned short u){
  return __bfloat162float(__builtin_bit_cast(__hip_bfloat16, u));
}
static __device__ __forceinline__ short8 zero8(){
  short8 v;
#pragma unroll
  for (int e=0;e<8;++e) v[e]=0;
  return v;
}
// async global->LDS, 16B/lane; lds dest wave-uniform base + lane*16
static __device__ __forceinline__ void g2l16(const void* g, void* l){
  __builtin_amdgcn_global_load_lds(
    (const __attribute__((address_space(1))) unsigned int*)g,
    (__attribute__((address_space(3))) unsigned int*)l, 16, 0, 0);
}

// ---------------------------------------------------------------------------
// QKV GEMM: out[row][0..767] = xln1[row][:] @ Wqkv^T + bias. 128 rows/block.
// A staged ONCE in 64KB swizzled LDS; B fragments direct from L2 (393KB).
// ---------------------------------------------------------------------------
__global__ __launch_bounds__(256)
void qkv_k(const unsigned short* __restrict__ Ap,   // xln1 [..][256]
           const unsigned short* __restrict__ Bp,   // Wqkv [768][256]
           const float* __restrict__ bias,          // [768]
           unsigned short* __restrict__ qk,         // [..][512]
           unsigned short* __restrict__ vT)         // [4096][256][48]
{
  __shared__ __align__(16) unsigned short As[128*256];  // 4 k-tiles [128][64] swizzled

  const int tid = threadIdx.x, lane = tid & 63, w = tid >> 6;
  const int cl = lane & 15, q4 = lane >> 4;
  const long rowBase = (long)blockIdx.x << 7;
  const int wm = (w >> 1) << 6, wn = (w & 1) << 6;

  // stage A: 4096 chunks of 16B; chunk c = kt*1024 + r*8 + x holds global x^(r&7)
#pragma unroll
  for (int it=0; it<16; ++it){
    const int c = (it<<8) + (w<<6) + lane;
    const int kt = c>>10, rem = c & 1023, r = rem>>3, x = rem&7;
    g2l16(Ap + (rowBase + r)*256 + (kt<<6) + (((x ^ (r&7)))<<3),
          As + (((it<<8) + (w<<6))<<3));
  }
  __syncthreads();

  for (int cb=0; cb<6; ++cb){
    f32x4 acc[4][4];
#pragma unroll
    for (int m=0;m<4;++m)
#pragma unroll
      for (int n=0;n<4;++n) acc[m][n] = (f32x4){0.f,0.f,0.f,0.f};
#pragma unroll
    for (int kt=0; kt<4; ++kt)
#pragma unroll
      for (int ks=0; ks<2; ++ks){
        const int kb = ks*64 + (q4<<4);
        short8 af[4], bf_[4];
#pragma unroll
        for (int m=0;m<4;++m){
          const int r = wm + m*16 + cl;
          af[m] = *(const short8*)((const char*)As + (kt<<14) + r*128 + (kb ^ ((r&7)<<4)));
        }
#pragma unroll
        for (int n=0;n<4;++n){
          const long rn = cb*128 + wn + n*16 + cl;
          bf_[n] = *(const short8*)(Bp + rn*256 + (kt<<6) + ks*32 + (q4<<3));
        }
#pragma unroll
        for (int m=0;m<4;++m)
#pragma unroll
          for (int n=0;n<4;++n)
            acc[m][n] = __builtin_amdgcn_mfma_f32_16x16x32_bf16(af[m], bf_[n], acc[m][n], 0,0,0);
      }
    // epilogue for this col-block
#pragma unroll
    for (int n=0;n<4;++n){
      const int col = cb*128 + wn + n*16 + cl;
      const float bi = bias[col];
#pragma unroll
      for (int m=0;m<4;++m){
        const long r0 = rowBase + wm + m*16 + (q4<<2);
#pragma unroll
        for (int i=0;i<4;++i){
          const float v = acc[m][n][i] + bi;
          const long row = r0 + i;
          if (col < 512){
            qk[row*512 + col] = f2bf(v);
          } else {
            const int bb = (int)row / 39;
            const int tt = (int)row - bb*39;
            unsigned short* vrow = vT + ((long)bb*256 + (col - 512))*48;
            vrow[tt] = f2bf(v);
            if (tt < 9) vrow[tt + 39] = 0;   // zero pad (tokens 39..47)
          }
        }
      }
    }
  }
}

// ---------------------------------------------------------------------------
// GEMM (head): C = A @ B^T + bias -> relu -> bf16. 128x128 tile, BK=64.
// ---------------------------------------------------------------------------
__global__ __launch_bounds__(256)
void gemm_k(const unsigned short* __restrict__ Ap, int lda,
            const unsigned short* __restrict__ Bp,
            const float* __restrict__ bias,
            unsigned short* __restrict__ Outp, int ldo, int K, int nColBlk)
{
  const int id = blockIdx.x;
  const int xcd = id & 7; const int t0 = id >> 3;
  const int cb = t0 % nColBlk; const int rb = (t0 / nColBlk)*8 + xcd;
  const long rowBase = (long)rb << 7;
  const long colBase = (long)cb << 7;
  const int tid = threadIdx.x, lane = tid & 63, w = tid >> 6;
  const int wm = (w >> 1) << 6, wn = (w & 1) << 6;
  const int cl = lane & 15, q4 = lane >> 4;

  __shared__ __align__(16) unsigned short As[128*64];
  __shared__ __align__(16) unsigned short Bs[128*64];

  const char* bSrc[4]; unsigned short* bDst[4];
  const char* aSrc[4]; unsigned short* aDst[4];
#pragma unroll
  for (int g=0; g<4; ++g){
    const int c = (w<<8) + (g<<6) + lane;
    const int r = c>>3, x = c&7, c16 = x ^ (r&7);
    bSrc[g] = (const char*)(Bp + (colBase + r)*(long)K) + c16*16;
    bDst[g] = Bs + (((w<<2)+g)<<9);
    aSrc[g] = (const char*)(Ap + (rowBase + r)*(long)lda) + c16*16;
    aDst[g] = As + (((w<<2)+g)<<9);
  }

  f32x4 acc[4][4];
#pragma unroll
  for (int m=0;m<4;++m)
#pragma unroll
    for (int n=0;n<4;++n) acc[m][n] = (f32x4){0.f,0.f,0.f,0.f};

  const int nk = K >> 6;
  for (int t=0; t<nk; ++t){
    if (t) __syncthreads();
    const long tb = (long)t << 7;
#pragma unroll
    for (int g=0; g<4; ++g){
      g2l16(bSrc[g] + tb, bDst[g]);
      g2l16(aSrc[g] + tb, aDst[g]);
    }
    __syncthreads();
#pragma unroll
    for (int ks=0; ks<2; ++ks){
      const int kb = ks*64 + (q4<<4);
      short8 af[4], bf_[4];
#pragma unroll
      for (int m=0;m<4;++m){
        const int r = wm + m*16 + cl;
        af[m] = *(const short8*)((const char*)As + r*128 + (kb ^ ((r&7)<<4)));
      }
#pragma unroll
      for (int n=0;n<4;++n){
        const int r = wn + n*16 + cl;
        bf_[n] = *(const short8*)((const char*)Bs + r*128 + (kb ^ ((r&7)<<4)));
      }
#pragma unroll
      for (int m=0;m<4;++m)
#pragma unroll
        for (int n=0;n<4;++n)
          acc[m][n] = __builtin_amdgcn_mfma_f32_16x16x32_bf16(af[m], bf_[n], acc[m][n], 0,0,0);
    }
  }

#pragma unroll
  for (int n=0;n<4;++n){
    const long col = colBase + wn + n*16 + cl;
    const float bi = bias[col];
#pragma unroll
    for (int m=0;m<4;++m){
      const long r0 = rowBase + wm + m*16 + (q4<<2);
#pragma unroll
      for (int i=0;i<4;++i){
        const float v = acc[m][n][i] + bi;
        Outp[(r0+i)*(long)ldo + col] = f2bf(fmaxf(v,0.f));
      }
    }
  }
}

// ---------------------------------------------------------------------------
// Fused FFN v7: 128 rows/block, 256 threads (4 waves), 2 blocks/CU.
// R10 analysis: ffn is L2-BW-bound on weight staging (each block reads the
// full 4MB W1+W2). 64-row blocks (R10) = 10GB L2 = 290us floor; 128-row
// blocks halve that to 5GB = 145us. 256-thr blocks give per-wave reg budget
// 256 at 2 blocks/CU (R6's 512-thr needed <=128 -> couldn't co-reside).
// Live regs: acc 128 (AGPR) + af 32 + hacc 32 + temps ~= 230 <= 256.
// LDS = W1c(32K)+W2c(32K)+Hs(16K) = 80KB x2 = 160KB exactly.
// ---------------------------------------------------------------------------
__global__ __launch_bounds__(256, 2)
void ffn_k(const float* __restrict__ xf_in,
           const float* __restrict__ sB, const float* __restrict__ cB,
           const unsigned short* __restrict__ W1p,  // [1024][256]
           const float* __restrict__ b1p,           // [1024]
           const unsigned short* __restrict__ W2p,  // [256][1024]
           const float* __restrict__ b2p,           // [256]
           float* __restrict__ xf,
           unsigned short* __restrict__ xln1, int writeXln)
{
  __shared__ __align__(16) unsigned short Wb1[64*256];  // 32KB, 4 k-tiles [64][64]
  __shared__ __align__(16) unsigned short Wb2[256*64];  // 32KB
  __shared__ __align__(16) unsigned short Hs[128*64];   // 16KB
  // epilogue scratch aliased onto Wb1 (dead after last H phase)
  float* part1 = (float*)Wb1;          // 512 f
  float* part2 = part1 + 512;          // 512 f
  float* sln   = part2 + 512;          // 128 f
  float* cln   = sln + 128;            // 128 f

  const int tid = threadIdx.x, lane = tid & 63, w = tid >> 6;
  const int cl = lane & 15, q4 = lane >> 4;
  const long rowBase = (long)blockIdx.x << 7;   // 128 rows/block

  // ---- A = LN2(x) in registers: wave w owns rows [32w, 32w+32) ----
  short8 af[2][8];
#pragma unroll
  for (int p=0; p<2; ++p){
    const int row = (w<<5) + (p<<4) + cl;
    const float s = sB[rowBase + row], c = cB[rowBase + row];
    const float* src = xf_in + (rowBase + row)*256 + (q4<<3);
#pragma unroll
    for (int kt=0; kt<8; ++kt){
      f32x4 a = *(const f32x4*)(src + kt*32);
      f32x4 b = *(const f32x4*)(src + kt*32 + 4);
      short8 v;
#pragma unroll
      for (int e=0;e<4;++e){ v[e] = (short)f2bf(a[e]*s + c); v[4+e] = (short)f2bf(b[e]*s + c); }
      af[p][kt] = v;
    }
  }

  // acc: wave w -> all 128 rows (m=0..7), cols [64w, 64w+64)
  f32x4 acc[8][4];
#pragma unroll
  for (int m=0;m<8;++m)
#pragma unroll
    for (int n=0;n<4;++n) acc[m][n] = (f32x4){0.f,0.f,0.f,0.f};

  for (int j=0; j<16; ++j){
    const int ffbase = j<<6;
    __syncthreads();   // prev chunk's W/Hs readers done
    // stage W1c [64 ff][256 k] (2048x16B) + W2c [256 out][64 ff] (2048x16B)
#pragma unroll
    for (int it=0; it<8; ++it){
      const int c = (it<<8) + tid;
      { // W1: 4 k-tiles of [64][64]; chunk c = kt*512 + rr*8 + xs
        const int kt = c>>9, cc = c&511, rr = cc>>3, xs = cc&7;
        g2l16(W1p + ((long)(ffbase+rr))*256 + (kt<<6) + ((xs^(rr&7))<<3),
              Wb1 + (((it<<8) + (w<<6))<<3));
      }
      { // W2: rows = out cols (256), 64-ff slice; chunk c = rr*8 + xs
        const int rr = c>>3, xs = c&7;
        g2l16(W2p + (long)rr*1024 + ffbase + ((xs^(rr&7))<<3),
              Wb2 + (((it<<8) + (w<<6))<<3));
      }
    }
    float b1v[4];
#pragma unroll
    for (int n=0;n<4;++n) b1v[n] = b1p[ffbase + n*16 + cl];
    __syncthreads();   // staged (vmcnt drained by barrier)

    // H = A @ W1c^T : wave w -> rows [32w,32w+32) x 64 ff cols, A from regs
    f32x4 hacc[2][4];
#pragma unroll
    for (int p=0;p<2;++p)
#pragma unroll
      for (int n=0;n<4;++n) hacc[p][n] = (f32x4){0.f,0.f,0.f,0.f};
#pragma unroll
    for (int kt2=0; kt2<4; ++kt2)
#pragma unroll
      for (int ks=0; ks<2; ++ks){
        const int kb = ks*64 + (q4<<4);
#pragma unroll
        for (int n=0;n<4;++n){
          const int rn = n*16 + cl;
          const short8 bf_ = *(const short8*)((const char*)Wb1 + (kt2<<13) + rn*128 + (kb ^ ((rn&7)<<4)));
#pragma unroll
          for (int p=0;p<2;++p)
            hacc[p][n] = __builtin_amdgcn_mfma_f32_16x16x32_bf16(af[p][kt2*2+ks], bf_, hacc[p][n], 0,0,0);
        }
      }
#pragma unroll
    for (int p=0;p<2;++p)
#pragma unroll
      for (int n=0;n<4;++n)
#pragma unroll
        for (int i=0;i<4;++i){
          const int hr = (w<<5) + (p<<4) + (q4<<2) + i, hc = n*16 + cl;
          const float hv = fmaxf(hacc[p][n][i] + b1v[n], 0.f);
          *(unsigned short*)((char*)Hs + hr*128 + ((hc*2) ^ ((hr&7)<<4))) = f2bf(hv);
        }
    __syncthreads();   // Hs visible

    // OUT += Hs @ W2c^T : wave w -> cols [64w,64w+64), all 128 rows
#pragma unroll
    for (int ks=0; ks<2; ++ks){
      const int kb = ks*64 + (q4<<4);
      short8 bm[4];
#pragma unroll
      for (int n=0;n<4;++n){
        const int r = (w<<6) + n*16 + cl;
        bm[n] = *(const short8*)((const char*)Wb2 + r*128 + (kb ^ ((r&7)<<4)));
      }
#pragma unroll
      for (int m=0;m<8;++m){
        const int r = m*16 + cl;
        const short8 am = *(const short8*)((const char*)Hs + r*128 + (kb ^ ((r&7)<<4)));
#pragma unroll
        for (int n=0;n<4;++n)
          acc[m][n] = __builtin_amdgcn_mfma_f32_16x16x32_bf16(am, bm[n], acc[m][n], 0,0,0);
      }
    }
  }

  // ---- epilogue: residual, xf write, LN1 stats, xln1 write ----
#pragma unroll
  for (int n=0;n<4;++n){
    const int col = (w<<6) + n*16 + cl;
    const float bi = b2p[col];
#pragma unroll
    for (int m=0;m<8;++m)
#pragma unroll
      for (int i=0;i<4;++i){
        const int row = m*16 + (q4<<2) + i;
        const long gi = (rowBase + row)*256 + col;
        const float v = acc[m][n][i] + bi + xf[gi];
        acc[m][n][i] = v;
        xf[gi] = v;
      }
  }
  __syncthreads();   // Wb1/Wb2/Hs fully dead before aliasing scratch
#pragma unroll
  for (int m=0;m<8;++m)
#pragma unroll
    for (int i=0;i<4;++i){
      float s1 = 0.f, s2 = 0.f;
#pragma unroll
      for (int n=0;n<4;++n){ const float v = acc[m][n][i]; s1 += v; s2 += v*v; }
#pragma unroll
      for (int off=8; off; off>>=1){ s1 += __shfl_xor(s1, off, 16); s2 += __shfl_xor(s2, off, 16); }
      const int row = m*16 + (q4<<2) + i;
      if (cl == 0){ part1[row*4 + w] = s1; part2[row*4 + w] = s2; }
    }
  __syncthreads();
  if (tid < 128){
    const float S1 = part1[tid*4]+part1[tid*4+1]+part1[tid*4+2]+part1[tid*4+3];
    const float S2 = part2[tid*4]+part2[tid*4+1]+part2[tid*4+2]+part2[tid*4+3];
    const float mn = S1*(1.f/256.f);
    const float var = S2*(1.f/256.f) - mn*mn;
    const float s = rsqrtf(var + 1e-5f);
    sln[tid] = s; cln[tid] = -mn*s;
  }
  __syncthreads();
  if (writeXln){
#pragma unroll
    for (int m=0;m<8;++m)
#pragma unroll
      for (int i=0;i<4;++i){
        const int row = m*16 + (q4<<2) + i;
        const float s = sln[row], c = cln[row];
#pragma unroll
        for (int n=0;n<4;++n){
          const int col = (w<<6) + n*16 + cl;
          xln1[(rowBase + row)*256 + col] = f2bf(acc[m][n][i]*s + c);
        }
      }
  }
}

// ---------------------------------------------------------------------------
// Sigmoid (HSTU) attention. One block = one batch item, 2 heads/wave.
// ---------------------------------------------------------------------------
__global__ __launch_bounds__(256)
void attn_sig_k(const unsigned short* __restrict__ qkb,
                const unsigned short* __restrict__ vT,
                float* xf, float* __restrict__ sB, float* __restrict__ cB)
{
  __shared__ __align__(16) unsigned short Ps[4*48*64];
  __shared__ float part[312];

  const int b = blockIdx.x;
  const int tid = threadIdx.x, lane = tid & 63, w = tid >> 6;
  const int cl = lane & 15, q4 = lane >> 4;
  unsigned short* P = Ps + w*3072;
  const unsigned short* qb = qkb + (long)b*39*512;
  const unsigned short* vbb = vT + (long)b*256*48;

  if (lane < 48){
    const int r = lane;
    *(short8*)((char*)P + r*128 + (96  ^ ((r&7)<<4))) = zero8();
    *(short8*)((char*)P + r*128 + (112 ^ ((r&7)<<4))) = zero8();
  }

  float ps1[3][4], ps2[3][4];
#pragma unroll
  for (int m=0;m<3;++m)
#pragma unroll
    for (int i=0;i<4;++i){ ps1[m][i]=0.f; ps2[m][i]=0.f; }

#pragma unroll
  for (int hh=0; hh<2; ++hh){
    const int h = (w<<1) + hh;
    f32x4 sac[3][3];
#pragma unroll
    for (int m=0;m<3;++m)
#pragma unroll
      for (int n=0;n<3;++n) sac[m][n] = (f32x4){0.f,0.f,0.f,0.f};
    short8 aq[3], bk8[3];
#pragma unroll
    for (int m=0;m<3;++m){
      const int r = m*16 + cl;
      aq[m] = (r < 39) ? *(const short8*)(qb + (long)r*512 + h*32 + q4*8) : zero8();
    }
#pragma unroll
    for (int n=0;n<3;++n){
      const int r = n*16 + cl;
      bk8[n] = (r < 39) ? *(const short8*)(qb + (long)r*512 + 256 + h*32 + q4*8) : zero8();
    }
#pragma unroll
    for (int m=0;m<3;++m)
#pragma unroll
      for (int n=0;n<3;++n)
        sac[m][n] = __builtin_amdgcn_mfma_f32_16x16x32_bf16(aq[m], bk8[n], sac[m][n], 0,0,0);
#pragma unroll
    for (int m=0;m<3;++m)
#pragma unroll
      for (int n=0;n<3;++n)
#pragma unroll
        for (int i=0;i<4;++i){
          const int row = m*16 + (q4<<2) + i, col = n*16 + cl;
          const float pv = 1.f/(1.f + __expf(-sac[m][n][i]*0.0625f));
          *(unsigned short*)((char*)P + row*128 + ((col*2) ^ ((row&7)<<4))) = f2bf(pv);
        }
    f32x4 aoc[3][2];
#pragma unroll
    for (int m=0;m<3;++m)
#pragma unroll
      for (int n=0;n<2;++n) aoc[m][n] = (f32x4){0.f,0.f,0.f,0.f};
#pragma unroll
    for (int ks=0; ks<2; ++ks){
      const int kb = ks*64 + (q4<<4);
      short8 pa[3], vb[2];
#pragma unroll
      for (int m=0;m<3;++m){
        const int r = m*16 + cl;
        pa[m] = *(const short8*)((const char*)P + r*128 + (kb ^ ((r&7)<<4)));
      }
#pragma unroll
      for (int n=0;n<2;++n){
        vb[n] = zero8();
        if (ks == 0 || q4 < 2)
          vb[n] = *(const short8*)(vbb + (long)(h*32 + n*16 + cl)*48 + ks*32 + q4*8);
      }
#pragma unroll
      for (int m=0;m<3;++m)
#pragma unroll
        for (int n=0;n<2;++n)
          aoc[m][n] = __builtin_amdgcn_mfma_f32_16x16x32_bf16(pa[m], vb[n], aoc[m][n], 0,0,0);
    }
#pragma unroll
    for (int m=0;m<3;++m)
#pragma unroll
      for (int n=0;n<2;++n)
#pragma unroll
        for (int i=0;i<4;++i){
          const int row = m*16 + (q4<<2) + i;
          if (row < 39){
            const long gi = (((long)(b*39+row))<<8) + h*32 + n*16 + cl;
            const float nv = xf[gi] + aoc[m][n][i];
            xf[gi] = nv;
            ps1[m][i] += nv; ps2[m][i] += nv*nv;
          }
        }
  }
#pragma unroll
  for (int m=0;m<3;++m)
#pragma unroll
    for (int i=0;i<4;++i){
      float a1 = ps1[m][i], a2 = ps2[m][i];
#pragma unroll
      for (int off=8; off; off>>=1){ a1 += __shfl_xor(a1, off, 16); a2 += __shfl_xor(a2, off, 16); }
      const int row = m*16 + (q4<<2) + i;
      if (cl == 0 && row < 39){ part[row*8 + (w<<1)] = a1; part[row*8 + (w<<1) + 1] = a2; }
    }
  __syncthreads();
  if (tid < 39){
    const float S1 = part[tid*8]+part[tid*8+2]+part[tid*8+4]+part[tid*8+6];
    const float S2 = part[tid*8+1]+part[tid*8+3]+part[tid*8+5]+part[tid*8+7];
    const float mn = S1*(1.f/256.f);
    const float var = S2*(1.f/256.f) - mn*mn;
    const float s = rsqrtf(var + 1e-5f);
    sB[b*39+tid] = s; cB[b*39+tid] = -mn*s;
  }
}

// ---------------------------------------------------------------------------
// Final softmax MHA + out-proj + residual -> flat bf16 [B][9984]
// ---------------------------------------------------------------------------
__global__ __launch_bounds__(256)
void attn_fin_k(const unsigned short* __restrict__ qkb,
                const unsigned short* __restrict__ vT,
                const float* __restrict__ xf,
                const unsigned short* __restrict__ moW,
                const float* __restrict__ moB,
                unsigned short* __restrict__ flatb)
{
  __shared__ __align__(16) unsigned short Ps[4*48*64];
  __shared__ __align__(16) unsigned short Mo[48*256];

  const int b = blockIdx.x;
  const int tid = threadIdx.x, lane = tid & 63, w = tid >> 6;
  const int cl = lane & 15, q4 = lane >> 4;
  unsigned short* P = Ps + w*3072;
  const unsigned short* qb = qkb + (long)b*39*512;
  const unsigned short* vbb = vT + (long)b*256*48;
  const float SC = 0.17677669529663687f;

  if (lane < 48){
    const int r = lane;
    *(short8*)((char*)P + r*128 + (96  ^ ((r&7)<<4))) = zero8();
    *(short8*)((char*)P + r*128 + (112 ^ ((r&7)<<4))) = zero8();
  }

#pragma unroll
  for (int hh=0; hh<2; ++hh){
    const int h = (w<<1) + hh;
    f32x4 sac[3][3];
#pragma unroll
    for (int m=0;m<3;++m)
#pragma unroll
      for (int n=0;n<3;++n) sac[m][n] = (f32x4){0.f,0.f,0.f,0.f};
    short8 aq[3], bk8[3];
#pragma unroll
    for (int m=0;m<3;++m){
      const int r = m*16 + cl;
      aq[m] = (r < 39) ? *(const short8*)(qb + (long)r*512 + h*32 + q4*8) : zero8();
    }
#pragma unroll
    for (int n=0;n<3;++n){
      const int r = n*16 + cl;
      bk8[n] = (r < 39) ? *(const short8*)(qb + (long)r*512 + 256 + h*32 + q4*8) : zero8();
    }
#pragma unroll
    for (int m=0;m<3;++m)
#pragma unroll
      for (int n=0;n<3;++n)
        sac[m][n] = __builtin_amdgcn_mfma_f32_16x16x32_bf16(aq[m], bk8[n], sac[m][n], 0,0,0);
#pragma unroll
    for (int m=0;m<3;++m)
#pragma unroll
      for (int i=0;i<4;++i){
        const float v0 = sac[m][0][i]*SC, v1 = sac[m][1][i]*SC, v2 = sac[m][2][i]*SC;
        const bool c2ok = (32 + cl) < 39;
        float mx = fmaxf(v0, v1);
        if (c2ok) mx = fmaxf(mx, v2);
#pragma unroll
        for (int off=8; off; off>>=1) mx = fmaxf(mx, __shfl_xor(mx, off, 16));
        const float e0 = __expf(v0-mx), e1 = __expf(v1-mx);
        const float e2 = c2ok ? __expf(v2-mx) : 0.f;
        float s = e0+e1+e2;
#pragma unroll
        for (int off=8; off; off>>=1) s += __shfl_xor(s, off, 16);
        const float inv = 1.f/s;
        const int row = m*16 + (q4<<2) + i;
        *(unsigned short*)((char*)P + row*128 + (((cl   )*2) ^ ((row&7)<<4))) = f2bf(e0*inv);
        *(unsigned short*)((char*)P + row*128 + (((16+cl)*2) ^ ((row&7)<<4))) = f2bf(e1*inv);
        *(unsigned short*)((char*)P + row*128 + (((32+cl)*2) ^ ((row&7)<<4))) = f2bf(e2*inv);
      }
    f32x4 aoc[3][2];
#pragma unroll
    for (int m=0;m<3;++m)
#pragma unroll
      for (int n=0;n<2;++n) aoc[m][n] = (f32x4){0.f,0.f,0.f,0.f};
#pragma unroll
    for (int ks=0; ks<2; ++ks){
      const int kb = ks*64 + (q4<<4);
      short8 pa[3], vb[2];
#pragma unroll
      for (int m=0;m<3;++m){
        const int r = m*16 + cl;
        pa[m] = *(const short8*)((const char*)P + r*128 + (kb ^ ((r&7)<<4)));
      }
#pragma unroll
      for (int n=0;n<2;++n){
        vb[n] = zero8();
        if (ks == 0 || q4 < 2)
          vb[n] = *(const short8*)(vbb + (long)(h*32 + n*16 + cl)*48 + ks*32 + q4*8);
      }
#pragma unroll
      for (int m=0;m<3;++m)
#pragma unroll
        for (int n=0;n<2;++n)
          aoc[m][n] = __builtin_amdgcn_mfma_f32_16x16x32_bf16(pa[m], vb[n], aoc[m][n], 0,0,0);
    }
#pragma unroll
    for (int m=0;m<3;++m)
#pragma unroll
      for (int n=0;n<2;++n)
#pragma unroll
        for (int i=0;i<4;++i){
          const int row = m*16 + (q4<<2) + i;
          const int colq = h*32 + n*16 + cl;
          *(unsigned short*)((char*)Mo + row*512 + ((colq*2) ^ ((row&7)<<4))) = f2bf(aoc[m][n][i]);
        }
  }
  __syncthreads();
  f32x4 oc[3][4];
#pragma unroll
  for (int m=0;m<3;++m)
#pragma unroll
    for (int n=0;n<4;++n) oc[m][n] = (f32x4){0.f,0.f,0.f,0.f};
#pragma unroll
  for (int ks=0; ks<8; ++ks){
    const int kb = ks*64 + (q4<<4);
    short8 am[3], bm[4];
#pragma unroll
    for (int m=0;m<3;++m){
      const int r = m*16 + cl;
      am[m] = *(const short8*)((const char*)Mo + r*512 + (kb ^ ((r&7)<<4)));
    }
#pragma unroll
    for (int n=0;n<4;++n){
      const int nn = (w<<6) + n*16 + cl;
      bm[n] = *(const short8*)(moW + (long)nn*256 + ks*32 + q4*8);
    }
#pragma unroll
    for (int m=0;m<3;++m)
#pragma unroll
      for (int n=0;n<4;++n)
        oc[m][n] = __builtin_amdgcn_mfma_f32_16x16x32_bf16(am[m], bm[n], oc[m][n], 0,0,0);
  }
#pragma unroll
  for (int m=0;m<3;++m)
#pragma unroll
    for (int n=0;n<4;++n)
#pragma unroll
      for (int i=0;i<4;++i){
        const int row = m*16 + (q4<<2) + i;
        if (row < 39){
          const int col = (w<<6) + n*16 + cl;
          const float v = oc[m][n][i] + moB[col] + xf[(((long)(b*39+row))<<8) + col];
          flatb[(long)b*9984 + row*256 + col] = f2bf(v);
        }
      }
}

// ---------------------------------------------------------------------------
// Embedding + x0 bf16 + xln1 (normalized) write
// ---------------------------------------------------------------------------
__global__ __launch_bounds__(256)
void embed_k(const float* __restrict__ dense_x, const int* __restrict__ sparse_x,
             const float* __restrict__ W_dense, const float* __restrict__ b_dense,
             const float* __restrict__ emb,
             float* __restrict__ xf, unsigned short* __restrict__ x0b,
             unsigned short* __restrict__ xln1)
{
  const int bid = blockIdx.x;
  const int b = bid / 39, t = bid - b*39;
  const int c = threadIdx.x;
  float v;
  if (t < 13){
    const int j = t*256 + c;
    v = b_dense[j];
    const float* wr = W_dense + (long)j*13;
    const float* dx = dense_x + (long)b*13;
#pragma unroll
    for (int k2=0;k2<13;++k2) v = fmaf(dx[k2], wr[k2], v);
  } else {
    const int idx = sparse_x[b*26 + (t-13)];
    v = (idx == 0) ? 0.f : emb[((long)(t-13)*10001 + idx)*256 + c];
  }
  const long row = bid;
  xf[row*256 + c] = v;
  x0b[row*256 + c] = f2bf(v);
  float s1 = v, s2 = v*v;
#pragma unroll
  for (int off=32; off; off>>=1){ s1 += __shfl_xor(s1, off); s2 += __shfl_xor(s2, off); }
  __shared__ float r1[4], r2[4];
  const int lane = c & 63, wq = c >> 6;
  if (lane == 0){ r1[wq]=s1; r2[wq]=s2; }
  __syncthreads();
  const float S1 = r1[0]+r1[1]+r1[2]+r1[3];
  const float S2 = r2[0]+r2[1]+r2[2]+r2[3];
  const float mn = S1*(1.f/256.f);
  const float var = S2*(1.f/256.f) - mn*mn;
  const float s = rsqrtf(var+1e-5f);
  xln1[row*256 + c] = f2bf((v - mn)*s);
}

// ---------------------------------------------------------------------------
// AttentionResidual block mixing (+ xln1 write)
// ---------------------------------------------------------------------------
template<int NSRC>
__global__ __launch_bounds__(256)
void mix_k(float* __restrict__ xf,
           const unsigned short* __restrict__ s0,
           const unsigned short* __restrict__ s1p,
           const unsigned short* __restrict__ s2p,
           unsigned short* mout,
           const float* __restrict__ qvec, int qi,
           unsigned short* __restrict__ xln1)
{
  const int b = blockIdx.x;
  const int tid = threadIdx.x, lane = tid&63, w = tid>>6;
  const int c4 = lane << 2;
  f32x4 q = *(const f32x4*)(qvec + qi*256 + c4);
  float qq = q[0]*q[0]+q[1]*q[1]+q[2]*q[2]+q[3]*q[3];
#pragma unroll
  for (int off=32; off; off>>=1) qq += __shfl_xor(qq, off);
  const float qsc = 1.f/fmaxf(sqrtf(qq), 1e-12f);
#pragma unroll
  for (int e=0;e<4;++e) q[e] *= qsc;
  for (int t = w; t < 39; t += 4){
    const long ro = ((long)(b*39+t))*256 + c4;
    f32x4 v[NSRC];
#pragma unroll
    for (int n=0;n<NSRC;++n){
      if (n == NSRC-1) v[n] = *(const f32x4*)(xf + ro);
      else {
        const unsigned short* sp = (n==0)?s0:((n==1)?s1p:s2p);
        us4 u = *(const us4*)(sp + ro);
#pragma unroll
        for (int e=0;e<4;++e) v[n][e] = bf2f(u[e]);
      }
    }
    float lg[NSRC];
#pragma unroll
    for (int n=0;n<NSRC;++n){
      float nn = v[n][0]*v[n][0]+v[n][1]*v[n][1]+v[n][2]*v[n][2]+v[n][3]*v[n][3];
      float dd = q[0]*v[n][0]+q[1]*v[n][1]+q[2]*v[n][2]+q[3]*v[n][3];
#pragma unroll
      for (int off=32; off; off>>=1){ nn += __shfl_xor(nn,off); dd += __shfl_xor(dd,off); }
      lg[n] = dd / fmaxf(sqrtf(nn), 1e-12f);
    }
    float mx = lg[0];
#pragma unroll
    for (int n=1;n<NSRC;++n) mx = fmaxf(mx, lg[n]);
    float es = 0.f, e_[NSRC];
#pragma unroll
    for (int n=0;n<NSRC;++n){ e_[n] = __expf(lg[n]-mx); es += e_[n]; }
    const float inv = 1.f/es;
    f32x4 o = {0.f,0.f,0.f,0.f};
#pragma unroll
    for (int n=0;n<NSRC;++n){
      const float wt = e_[n]*inv;
#pragma unroll
      for (int e=0;e<4;++e) o[e] = fmaf(wt, v[n][e], o[e]);
    }
    *(f32x4*)(xf + ro) = o;
    if (mout){
      us4 u;
#pragma unroll
      for (int e=0;e<4;++e) u[e] = f2bf(o[e]);
      *(us4*)(mout + ro) = u;
    }
    float s1 = o[0]+o[1]+o[2]+o[3];
    float s2 = o[0]*o[0]+o[1]*o[1]+o[2]*o[2]+o[3]*o[3];
#pragma unroll
    for (int off=32; off; off>>=1){ s1 += __shfl_xor(s1,off); s2 += __shfl_xor(s2,off); }
    const float mn = s1*(1.f/256.f);
    const float var = s2*(1.f/256.f)-mn*mn;
    const float s = rsqrtf(var+1e-5f);
    const float c = -mn*s;
    us4 u2;
#pragma unroll
    for (int e=0;e<4;++e) u2[e] = f2bf(o[e]*s + c);
    *(us4*)(xln1 + ro) = u2;
  }
}

__global__ __launch_bounds__(256)
void head2_k(const unsigned short* __restrict__ h1h, const float* __restrict__ Wo2,
             const float* __restrict__ bo2, float* __restrict__ outp)
{
  const int b = blockIdx.x*4 + (threadIdx.x>>6);
  const int lane = threadIdx.x & 63;
  float s = 0.f;
#pragma unroll
  for (int g=0; g<2; ++g){
    const int base = lane*16 + g*8;
    short8 v8 = *(const short8*)(h1h + (long)b*1024 + base);
#pragma unroll
    for (int e=0;e<8;++e) s = fmaf(bf2f((unsigned short)v8[e]), Wo2[base+e], s);
  }
#pragma unroll
  for (int off=32; off; off>>=1) s += __shfl_xor(s, off);
  if (lane==0) outp[b] = s + bo2[0];
}

// ------------------------- weight prep kernels ------------------------------
__global__ void cvt_k(const float* __restrict__ src, unsigned short* __restrict__ dst, long n){
  const long i = (long)blockIdx.x*256 + threadIdx.x;
  if (i < n) dst[i] = f2bf(src[i]);
}
__global__ void prep_qkv_k(const float* Wq, const float* Wk, const float* Wv,
                           const float* g, unsigned short* dst){
  const int n = blockIdx.x, i = blockIdx.y, k = threadIdx.x;
  const int sel = n >> 8, nn = n & 255;
  const float* W = sel==0?Wq:(sel==1?Wk:Wv);
  dst[((long)i*768 + n)*256 + k] = f2bf(W[((long)i*256+nn)*256 + k] * g[i*256+k]);
}
__global__ void prep_qkvb_k(const float* Wq,const float* Wk,const float* Wv,
                            const float* bq,const float* bk,const float* bv,
                            const float* beta, float* dst){
  const int n = blockIdx.x, i = blockIdx.y, k = threadIdx.x;
  const int sel = n>>8, nn = n&255;
  const float* W = sel==0?Wq:(sel==1?Wk:Wv);
  const float* bb = sel==0?bq:(sel==1?bk:bv);
  float v = beta[i*256+k] * W[((long)i*256+nn)*256+k];
  __shared__ float r[4];
#pragma unroll
  for (int off=32; off; off>>=1) v += __shfl_xor(v, off);
  if ((k&63)==0) r[k>>6] = v;
  __syncthreads();
  if (k==0) dst[i*768+n] = bb[i*256+nn] + r[0]+r[1]+r[2]+r[3];
}
__global__ void prep_w1_k(const float* W1, const float* g, unsigned short* dst){
  const int n = blockIdx.x, i = blockIdx.y, k = threadIdx.x;
  const long o = ((long)i*1024+n)*256 + k;
  dst[o] = f2bf(W1[o] * g[i*256+k]);
}
__global__ void prep_w1b_k(const float* W1, const float* b1, const float* beta, float* dst){
  const int n = blockIdx.x, i = blockIdx.y, k = threadIdx.x;
  float v = beta[i*256+k] * W1[((long)i*1024+n)*256+k];
  __shared__ float r[4];
#pragma unroll
  for (int off=32; off; off>>=1) v += __shfl_xor(v, off);
  if ((k&63)==0) r[k>>6] = v;
  __syncthreads();
  if (k==0) dst[i*1024+n] = b1[i*1024+n] + r[0]+r[1]+r[2]+r[3];
}
__global__ void prep_mha_k(const float* W, const float* g, unsigned short* dst){
  const int n = blockIdx.x, k = threadIdx.x;
  dst[n*256+k] = f2bf(W[n*256+k]*g[k]);
}
__global__ void prep_mhab_k(const float* W, const float* bb, const float* beta, float* dst){
  const int n = blockIdx.x, k = threadIdx.x;
  float v = beta[k]*W[n*256+k];
  __shared__ float r[4];
#pragma unroll
  for (int off=32; off; off>>=1) v += __shfl_xor(v, off);
  if ((k&63)==0) r[k>>6] = v;
  __syncthreads();
  if (k==0) dst[n] = bb[n] + r[0]+r[1]+r[2]+r[3];
}

// ---------------------------------------------------------------------------
extern "C" void kernel_launch(void* const* d_in, const int* in_sizes, int n_in,
                              void* d_out, int out_size, void* d_ws, size_t ws_size,
                              hipStream_t stream)
{
  (void)in_sizes; (void)n_in; (void)out_size; (void)ws_size;
  const float* dense_x  = (const float*)d_in[0];
  const int*   sparse_x = (const int*)d_in[1];
  const float* W_dense  = (const float*)d_in[2];
  const float* b_dense  = (const float*)d_in[3];
  const float* emb      = (const float*)d_in[4];
  const float* Wq = (const float*)d_in[5];
  const float* bq = (const float*)d_in[6];
  const float* Wk = (const float*)d_in[7];
  const float* bk = (const float*)d_in[8];
  const float* Wv = (const float*)d_in[9];
  const float* bv = (const float*)d_in[10];
  const float* W1 = (const float*)d_in[11];
  const float* b1 = (const float*)d_in[12];
  const float* W2 = (const float*)d_in[13];
  const float* b2 = (const float*)d_in[14];
  const float* n1g= (const float*)d_in[15];
  const float* n1b= (const float*)d_in[16];
  const float* n2g= (const float*)d_in[17];
  const float* n2b= (const float*)d_in[18];
  const float* qvec=(const float*)d_in[19];
  const float* mha_in_w = (const float*)d_in[20];
  const float* mha_in_b = (const float*)d_in[21];
  const float* mha_out_w= (const float*)d_in[22];
  const float* mha_out_b= (const float*)d_in[23];
  const float* ng = (const float*)d_in[24];
  const float* ngb= (const float*)d_in[25];
  const float* Wo1= (const float*)d_in[26];
  const float* bo1= (const float*)d_in[27];
  const float* Wo2= (const float*)d_in[28];
  const float* bo2= (const float*)d_in[29];

  char* ws = (char*)d_ws;
  size_t off = 0;
  auto alloc = [&](size_t bytes)->void*{ void* p = ws + off; off += (bytes + 255) & ~(size_t)255; return p; };
  float* xf            = (float*)alloc(163577856ull);           // [159744][256] f32
  unsigned short* qkh  = (unsigned short*)alloc(163577856ull);  // [159744][512] bf16 (Q|K)
  unsigned short* vT   = (unsigned short*)alloc(100663296ull);  // [4096][256][48] bf16
  unsigned short* x0b  = (unsigned short*)alloc(81788928ull);
  unsigned short* m1b  = (unsigned short*)alloc(81788928ull);   // aliased as flatb at end
  unsigned short* m2b  = (unsigned short*)alloc(81788928ull);
  unsigned short* xln1 = (unsigned short*)alloc(81788928ull);
  unsigned short* h1h  = (unsigned short*)alloc(8388608ull);    // [4096][1024] bf16
  float* sB = (float*)alloc(638976ull);
  float* cB = (float*)alloc(638976ull);
  unsigned short* Wqkv_f = (unsigned short*)alloc(3145728ull);
  float* bqkv_f = (float*)alloc(24576ull);
  unsigned short* W1_f = (unsigned short*)alloc(4194304ull);
  float* b1_f = (float*)alloc(32768ull);
  unsigned short* W2_f = (unsigned short*)alloc(4194304ull);
  unsigned short* mhain_f = (unsigned short*)alloc(393216ull);
  float* mhainb_f = (float*)alloc(3072ull);
  unsigned short* mhaout_f = (unsigned short*)alloc(131072ull);
  unsigned short* Wo1_f = (unsigned short*)alloc(20447232ull);

  unsigned short* flatb = m1b;   // m1b dead after layer-5 mix

  // weight prep
  cvt_k<<<8192,256,0,stream>>>(W2, W2_f, 2097152L);
  cvt_k<<<256,256,0,stream>>>(mha_out_w, mhaout_f, 65536L);
  cvt_k<<<39936,256,0,stream>>>(Wo1, Wo1_f, 10223616L);
  prep_qkv_k<<<dim3(768,8),256,0,stream>>>(Wq,Wk,Wv,n1g,Wqkv_f);
  prep_qkvb_k<<<dim3(768,8),256,0,stream>>>(Wq,Wk,Wv,bq,bk,bv,n1b,bqkv_f);
  prep_w1_k<<<dim3(1024,8),256,0,stream>>>(W1,n2g,W1_f);
  prep_w1b_k<<<dim3(1024,8),256,0,stream>>>(W1,b1,n2b,b1_f);
  prep_mha_k<<<768,256,0,stream>>>(mha_in_w, ng, mhain_f);
  prep_mhab_k<<<768,256,0,stream>>>(mha_in_w, mha_in_b, ngb, mhainb_f);

  embed_k<<<159744,256,0,stream>>>(dense_x, sparse_x, W_dense, b_dense, emb, xf, x0b, xln1);

  for (int i = 0; i < 8; ++i){
    qkv_k<<<1248,256,0,stream>>>(xln1, Wqkv_f + (size_t)i*196608, bqkv_f + i*768, qkh, vT);
    attn_sig_k<<<4096,256,0,stream>>>(qkh, vT, xf, sB, cB);
    const int wx = (i==1 || i==3 || i==5) ? 0 : 1;
    ffn_k<<<1248,256,0,stream>>>(xf, sB, cB,
        W1_f + (size_t)i*262144, b1_f + i*1024,
        W2_f + (size_t)i*262144, b2 + i*256, xf, xln1, wx);
    if (i == 1)      mix_k<2><<<4096,256,0,stream>>>(xf, x0b, m1b, m2b, m1b, qvec, 1, xln1);
    else if (i == 3) mix_k<3><<<4096,256,0,stream>>>(xf, x0b, m1b, m2b, m2b, qvec, 2, xln1);
    else if (i == 5) mix_k<4><<<4096,256,0,stream>>>(xf, x0b, m1b, m2b, nullptr, qvec, 3, xln1);
  }
  qkv_k<<<1248,256,0,stream>>>(xln1, mhain_f, mhainb_f, qkh, vT);
  attn_fin_k<<<4096,256,0,stream>>>(qkh, vT, xf, mhaout_f, mha_out_b, flatb);
  gemm_k<<<256,256,0,stream>>>(flatb, 9984, Wo1_f, bo1, h1h, 1024, 9984, 8);
  head2_k<<<1024,256,0,stream>>>(h1h, Wo2, bo2, (float*)d_out);
}

// Round 12
// 7911.963 us; speedup vs baseline: 1.1949x; 1.1949x over previous
//
#include <hip/hip_runtime.h>
#include <hip/hip_bf16.h>

typedef __attribute__((ext_vector_type(4))) float f32x4;
typedef __attribute__((ext_vector_type(8))) short short8;
typedef __attribute__((ext_vector_type(4))) unsigned short us4;

static __device__ __forceinline__ unsigned short f2bf(float f){
  return __builtin_bit_cast(unsigned short, __float2bfloat16(f));
}
static __device__ __forceinline__ float bf2f(unsigned short u){
  return __bfloat162float(__builtin_bit_cast(__hip_bfloat16, u));
}
static __device__ __forceinline__ short8 zero8(){
  short8 v;
#pragma unroll
  for (int e=0;e<8;++e) v[e]=0;
  return v;
}
// async global->LDS, 16B/lane; lds dest wave-uniform base + lane*16
static __device__ __forceinline__ void g2l16(const void* g, void* l){
  __builtin_amdgcn_global_load_lds(
    (const __attribute__((address_space(1))) unsigned int*)g,
    (__attribute__((address_space(3))) unsigned int*)l, 16, 0, 0);
}

// ---------------------------------------------------------------------------
// QKV GEMM: out[row][0..767] = xln1[row][:] @ Wqkv^T + bias. 128 rows/block.
// A staged ONCE in 64KB swizzled LDS; B fragments direct from L2 (393KB).
// ---------------------------------------------------------------------------
__global__ __launch_bounds__(256)
void qkv_k(const unsigned short* __restrict__ Ap,   // xln1 [..][256]
           const unsigned short* __restrict__ Bp,   // Wqkv [768][256]
           const float* __restrict__ bias,          // [768]
           unsigned short* __restrict__ qk,         // [..][512]
           unsigned short* __restrict__ vT)         // [4096][256][48]
{
  __shared__ __align__(16) unsigned short As[128*256];  // 4 k-tiles [128][64] swizzled

  const int tid = threadIdx.x, lane = tid & 63, w = tid >> 6;
  const int cl = lane & 15, q4 = lane >> 4;
  const long rowBase = (long)blockIdx.x << 7;
  const int wm = (w >> 1) << 6, wn = (w & 1) << 6;

  // stage A: 4096 chunks of 16B; chunk c = kt*1024 + r*8 + x holds global x^(r&7)
#pragma unroll
  for (int it=0; it<16; ++it){
    const int c = (it<<8) + (w<<6) + lane;
    const int kt = c>>10, rem = c & 1023, r = rem>>3, x = rem&7;
    g2l16(Ap + (rowBase + r)*256 + (kt<<6) + (((x ^ (r&7)))<<3),
          As + (((it<<8) + (w<<6))<<3));
  }
  __syncthreads();

  for (int cb=0; cb<6; ++cb){
    f32x4 acc[4][4];
#pragma unroll
    for (int m=0;m<4;++m)
#pragma unroll
      for (int n=0;n<4;++n) acc[m][n] = (f32x4){0.f,0.f,0.f,0.f};
#pragma unroll
    for (int kt=0; kt<4; ++kt)
#pragma unroll
      for (int ks=0; ks<2; ++ks){
        const int kb = ks*64 + (q4<<4);
        short8 af[4], bf_[4];
#pragma unroll
        for (int m=0;m<4;++m){
          const int r = wm + m*16 + cl;
          af[m] = *(const short8*)((const char*)As + (kt<<14) + r*128 + (kb ^ ((r&7)<<4)));
        }
#pragma unroll
        for (int n=0;n<4;++n){
          const long rn = cb*128 + wn + n*16 + cl;
          bf_[n] = *(const short8*)(Bp + rn*256 + (kt<<6) + ks*32 + (q4<<3));
        }
#pragma unroll
        for (int m=0;m<4;++m)
#pragma unroll
          for (int n=0;n<4;++n)
            acc[m][n] = __builtin_amdgcn_mfma_f32_16x16x32_bf16(af[m], bf_[n], acc[m][n], 0,0,0);
      }
    // epilogue for this col-block
#pragma unroll
    for (int n=0;n<4;++n){
      const int col = cb*128 + wn + n*16 + cl;
      const float bi = bias[col];
#pragma unroll
      for (int m=0;m<4;++m){
        const long r0 = rowBase + wm + m*16 + (q4<<2);
#pragma unroll
        for (int i=0;i<4;++i){
          const float v = acc[m][n][i] + bi;
          const long row = r0 + i;
          if (col < 512){
            qk[row*512 + col] = f2bf(v);
          } else {
            const int bb = (int)row / 39;
            const int tt = (int)row - bb*39;
            unsigned short* vrow = vT + ((long)bb*256 + (col - 512))*48;
            vrow[tt] = f2bf(v);
            if (tt < 9) vrow[tt + 39] = 0;   // zero pad (tokens 39..47)
          }
        }
      }
    }
  }
}

// ---------------------------------------------------------------------------
// GEMM (head): C = A @ B^T + bias -> relu -> bf16. 128x128 tile, BK=64.
// ---------------------------------------------------------------------------
__global__ __launch_bounds__(256)
void gemm_k(const unsigned short* __restrict__ Ap, int lda,
            const unsigned short* __restrict__ Bp,
            const float* __restrict__ bias,
            unsigned short* __restrict__ Outp, int ldo, int K, int nColBlk)
{
  const int id = blockIdx.x;
  const int xcd = id & 7; const int t0 = id >> 3;
  const int cb = t0 % nColBlk; const int rb = (t0 / nColBlk)*8 + xcd;
  const long rowBase = (long)rb << 7;
  const long colBase = (long)cb << 7;
  const int tid = threadIdx.x, lane = tid & 63, w = tid >> 6;
  const int wm = (w >> 1) << 6, wn = (w & 1) << 6;
  const int cl = lane & 15, q4 = lane >> 4;

  __shared__ __align__(16) unsigned short As[128*64];
  __shared__ __align__(16) unsigned short Bs[128*64];

  const char* bSrc[4]; unsigned short* bDst[4];
  const char* aSrc[4]; unsigned short* aDst[4];
#pragma unroll
  for (int g=0; g<4; ++g){
    const int c = (w<<8) + (g<<6) + lane;
    const int r = c>>3, x = c&7, c16 = x ^ (r&7);
    bSrc[g] = (const char*)(Bp + (colBase + r)*(long)K) + c16*16;
    bDst[g] = Bs + (((w<<2)+g)<<9);
    aSrc[g] = (const char*)(Ap + (rowBase + r)*(long)lda) + c16*16;
    aDst[g] = As + (((w<<2)+g)<<9);
  }

  f32x4 acc[4][4];
#pragma unroll
  for (int m=0;m<4;++m)
#pragma unroll
    for (int n=0;n<4;++n) acc[m][n] = (f32x4){0.f,0.f,0.f,0.f};

  const int nk = K >> 6;
  for (int t=0; t<nk; ++t){
    if (t) __syncthreads();
    const long tb = (long)t << 7;
#pragma unroll
    for (int g=0; g<4; ++g){
      g2l16(bSrc[g] + tb, bDst[g]);
      g2l16(aSrc[g] + tb, aDst[g]);
    }
    __syncthreads();
#pragma unroll
    for (int ks=0; ks<2; ++ks){
      const int kb = ks*64 + (q4<<4);
      short8 af[4], bf_[4];
#pragma unroll
      for (int m=0;m<4;++m){
        const int r = wm + m*16 + cl;
        af[m] = *(const short8*)((const char*)As + r*128 + (kb ^ ((r&7)<<4)));
      }
#pragma unroll
      for (int n=0;n<4;++n){
        const int r = wn + n*16 + cl;
        bf_[n] = *(const short8*)((const char*)Bs + r*128 + (kb ^ ((r&7)<<4)));
      }
#pragma unroll
      for (int m=0;m<4;++m)
#pragma unroll
        for (int n=0;n<4;++n)
          acc[m][n] = __builtin_amdgcn_mfma_f32_16x16x32_bf16(af[m], bf_[n], acc[m][n], 0,0,0);
    }
  }

#pragma unroll
  for (int n=0;n<4;++n){
    const long col = colBase + wn + n*16 + cl;
    const float bi = bias[col];
#pragma unroll
    for (int m=0;m<4;++m){
      const long r0 = rowBase + wm + m*16 + (q4<<2);
#pragma unroll
      for (int i=0;i<4;++i){
        const float v = acc[m][n][i] + bi;
        Outp[(r0+i)*(long)ldo + col] = f2bf(fmaxf(v,0.f));
      }
    }
  }
}

// ---------------------------------------------------------------------------
// Fused FFN v7b: 128 rows/block, 256 threads, NO min-waves bound (R11's
// (256,2) forced a 128-reg cap -> acc spilled; R4/R5 same trap). Live regs
// ~= acc 128 AGPR + af 32 + hacc 16 + temps ~= 240 total -> 2 waves/SIMD
// (<=256 step, m69) -> 2 blocks/CU by LDS (80KB x2 = 160KB). Halves L2
// weight traffic vs 64-row blocks (5GB -> ~145us floor). H-phase split
// into two 32-row halves (hacc[4] only; Wb1 re-read from LDS, cheap).
// ---------------------------------------------------------------------------
__global__ __launch_bounds__(256)
void ffn_k(const float* __restrict__ xf_in,
           const float* __restrict__ sB, const float* __restrict__ cB,
           const unsigned short* __restrict__ W1p,  // [1024][256]
           const float* __restrict__ b1p,           // [1024]
           const unsigned short* __restrict__ W2p,  // [256][1024]
           const float* __restrict__ b2p,           // [256]
           float* __restrict__ xf,
           unsigned short* __restrict__ xln1, int writeXln)
{
  __shared__ __align__(16) unsigned short Wb1[64*256];  // 32KB, 4 k-tiles [64][64]
  __shared__ __align__(16) unsigned short Wb2[256*64];  // 32KB
  __shared__ __align__(16) unsigned short Hs[128*64];   // 16KB
  // epilogue scratch aliased onto Wb1 (dead after last H phase)
  float* part1 = (float*)Wb1;          // 512 f
  float* part2 = part1 + 512;          // 512 f
  float* sln   = part2 + 512;          // 128 f
  float* cln   = sln + 128;            // 128 f

  const int tid = threadIdx.x, lane = tid & 63, w = tid >> 6;
  const int cl = lane & 15, q4 = lane >> 4;
  const long rowBase = (long)blockIdx.x << 7;   // 128 rows/block

  // ---- A = LN2(x) in registers: wave w owns rows [32w, 32w+32) ----
  short8 af[2][8];
#pragma unroll
  for (int p=0; p<2; ++p){
    const int row = (w<<5) + (p<<4) + cl;
    const float s = sB[rowBase + row], c = cB[rowBase + row];
    const float* src = xf_in + (rowBase + row)*256 + (q4<<3);
#pragma unroll
    for (int kt=0; kt<8; ++kt){
      f32x4 a = *(const f32x4*)(src + kt*32);
      f32x4 b = *(const f32x4*)(src + kt*32 + 4);
      short8 v;
#pragma unroll
      for (int e=0;e<4;++e){ v[e] = (short)f2bf(a[e]*s + c); v[4+e] = (short)f2bf(b[e]*s + c); }
      af[p][kt] = v;
    }
  }

  // acc: wave w -> all 128 rows (m=0..7), cols [64w, 64w+64)
  f32x4 acc[8][4];
#pragma unroll
  for (int m=0;m<8;++m)
#pragma unroll
    for (int n=0;n<4;++n) acc[m][n] = (f32x4){0.f,0.f,0.f,0.f};

  for (int j=0; j<16; ++j){
    const int ffbase = j<<6;
    __syncthreads();   // prev chunk's W/Hs readers done
    // stage W1c [64 ff][256 k] (2048x16B) + W2c [256 out][64 ff] (2048x16B)
#pragma unroll
    for (int it=0; it<8; ++it){
      const int c = (it<<8) + tid;
      { // W1: 4 k-tiles of [64][64]; chunk c = kt*512 + rr*8 + xs
        const int kt = c>>9, cc = c&511, rr = cc>>3, xs = cc&7;
        g2l16(W1p + ((long)(ffbase+rr))*256 + (kt<<6) + ((xs^(rr&7))<<3),
              Wb1 + (((it<<8) + (w<<6))<<3));
      }
      { // W2: rows = out cols (256), 64-ff slice; chunk c = rr*8 + xs
        const int rr = c>>3, xs = c&7;
        g2l16(W2p + (long)rr*1024 + ffbase + ((xs^(rr&7))<<3),
              Wb2 + (((it<<8) + (w<<6))<<3));
      }
    }
    float b1v[4];
#pragma unroll
    for (int n=0;n<4;++n) b1v[n] = b1p[ffbase + n*16 + cl];
    __syncthreads();   // staged (vmcnt drained by barrier)

    // H = A @ W1c^T : two sequential 32-row halves (halves hacc liveness)
#pragma unroll
    for (int p=0; p<2; ++p){
      f32x4 hacc[4];
#pragma unroll
      for (int n=0;n<4;++n) hacc[n] = (f32x4){0.f,0.f,0.f,0.f};
#pragma unroll
      for (int kt2=0; kt2<4; ++kt2)
#pragma unroll
        for (int ks=0; ks<2; ++ks){
          const int kb = ks*64 + (q4<<4);
          const short8 a = af[p][kt2*2+ks];
#pragma unroll
          for (int n=0;n<4;++n){
            const int rn = n*16 + cl;
            const short8 bf_ = *(const short8*)((const char*)Wb1 + (kt2<<13) + rn*128 + (kb ^ ((rn&7)<<4)));
            hacc[n] = __builtin_amdgcn_mfma_f32_16x16x32_bf16(a, bf_, hacc[n], 0,0,0);
          }
        }
#pragma unroll
      for (int n=0;n<4;++n)
#pragma unroll
        for (int i=0;i<4;++i){
          const int hr = (w<<5) + (p<<4) + (q4<<2) + i, hc = n*16 + cl;
          const float hv = fmaxf(hacc[n][i] + b1v[n], 0.f);
          *(unsigned short*)((char*)Hs + hr*128 + ((hc*2) ^ ((hr&7)<<4))) = f2bf(hv);
        }
    }
    __syncthreads();   // Hs visible

    // OUT += Hs @ W2c^T : wave w -> cols [64w,64w+64), all 128 rows
#pragma unroll
    for (int ks=0; ks<2; ++ks){
      const int kb = ks*64 + (q4<<4);
      short8 bm[4];
#pragma unroll
      for (int n=0;n<4;++n){
        const int r = (w<<6) + n*16 + cl;
        bm[n] = *(const short8*)((const char*)Wb2 + r*128 + (kb ^ ((r&7)<<4)));
      }
#pragma unroll
      for (int m=0;m<8;++m){
        const int r = m*16 + cl;
        const short8 am = *(const short8*)((const char*)Hs + r*128 + (kb ^ ((r&7)<<4)));
#pragma unroll
        for (int n=0;n<4;++n)
          acc[m][n] = __builtin_amdgcn_mfma_f32_16x16x32_bf16(am, bm[n], acc[m][n], 0,0,0);
      }
    }
  }

  // ---- epilogue: residual, xf write, LN1 stats, xln1 write ----
#pragma unroll
  for (int n=0;n<4;++n){
    const int col = (w<<6) + n*16 + cl;
    const float bi = b2p[col];
#pragma unroll
    for (int m=0;m<8;++m)
#pragma unroll
      for (int i=0;i<4;++i){
        const int row = m*16 + (q4<<2) + i;
        const long gi = (rowBase + row)*256 + col;
        const float v = acc[m][n][i] + bi + xf[gi];
        acc[m][n][i] = v;
        xf[gi] = v;
      }
  }
  __syncthreads();   // Wb1/Wb2/Hs fully dead before aliasing scratch
#pragma unroll
  for (int m=0;m<8;++m)
#pragma unroll
    for (int i=0;i<4;++i){
      float s1 = 0.f, s2 = 0.f;
#pragma unroll
      for (int n=0;n<4;++n){ const float v = acc[m][n][i]; s1 += v; s2 += v*v; }
#pragma unroll
      for (int off=8; off; off>>=1){ s1 += __shfl_xor(s1, off, 16); s2 += __shfl_xor(s2, off, 16); }
      const int row = m*16 + (q4<<2) + i;
      if (cl == 0){ part1[row*4 + w] = s1; part2[row*4 + w] = s2; }
    }
  __syncthreads();
  if (tid < 128){
    const float S1 = part1[tid*4]+part1[tid*4+1]+part1[tid*4+2]+part1[tid*4+3];
    const float S2 = part2[tid*4]+part2[tid*4+1]+part2[tid*4+2]+part2[tid*4+3];
    const float mn = S1*(1.f/256.f);
    const float var = S2*(1.f/256.f) - mn*mn;
    const float s = rsqrtf(var + 1e-5f);
    sln[tid] = s; cln[tid] = -mn*s;
  }
  __syncthreads();
  if (writeXln){
#pragma unroll
    for (int m=0;m<8;++m)
#pragma unroll
      for (int i=0;i<4;++i){
        const int row = m*16 + (q4<<2) + i;
        const float s = sln[row], c = cln[row];
#pragma unroll
        for (int n=0;n<4;++n){
          const int col = (w<<6) + n*16 + cl;
          xln1[(rowBase + row)*256 + col] = f2bf(acc[m][n][i]*s + c);
        }
      }
  }
}

// ---------------------------------------------------------------------------
// Sigmoid (HSTU) attention. One block = one batch item, 2 heads/wave.
// ---------------------------------------------------------------------------
__global__ __launch_bounds__(256)
void attn_sig_k(const unsigned short* __restrict__ qkb,
                const unsigned short* __restrict__ vT,
                float* xf, float* __restrict__ sB, float* __restrict__ cB)
{
  __shared__ __align__(16) unsigned short Ps[4*48*64];
  __shared__ float part[312];

  const int b = blockIdx.x;
  const int tid = threadIdx.x, lane = tid & 63, w = tid >> 6;
  const int cl = lane & 15, q4 = lane >> 4;
  unsigned short* P = Ps + w*3072;
  const unsigned short* qb = qkb + (long)b*39*512;
  const unsigned short* vbb = vT + (long)b*256*48;

  if (lane < 48){
    const int r = lane;
    *(short8*)((char*)P + r*128 + (96  ^ ((r&7)<<4))) = zero8();
    *(short8*)((char*)P + r*128 + (112 ^ ((r&7)<<4))) = zero8();
  }

  float ps1[3][4], ps2[3][4];
#pragma unroll
  for (int m=0;m<3;++m)
#pragma unroll
    for (int i=0;i<4;++i){ ps1[m][i]=0.f; ps2[m][i]=0.f; }

#pragma unroll
  for (int hh=0; hh<2; ++hh){
    const int h = (w<<1) + hh;
    f32x4 sac[3][3];
#pragma unroll
    for (int m=0;m<3;++m)
#pragma unroll
      for (int n=0;n<3;++n) sac[m][n] = (f32x4){0.f,0.f,0.f,0.f};
    short8 aq[3], bk8[3];
#pragma unroll
    for (int m=0;m<3;++m){
      const int r = m*16 + cl;
      aq[m] = (r < 39) ? *(const short8*)(qb + (long)r*512 + h*32 + q4*8) : zero8();
    }
#pragma unroll
    for (int n=0;n<3;++n){
      const int r = n*16 + cl;
      bk8[n] = (r < 39) ? *(const short8*)(qb + (long)r*512 + 256 + h*32 + q4*8) : zero8();
    }
#pragma unroll
    for (int m=0;m<3;++m)
#pragma unroll
      for (int n=0;n<3;++n)
        sac[m][n] = __builtin_amdgcn_mfma_f32_16x16x32_bf16(aq[m], bk8[n], sac[m][n], 0,0,0);
#pragma unroll
    for (int m=0;m<3;++m)
#pragma unroll
      for (int n=0;n<3;++n)
#pragma unroll
        for (int i=0;i<4;++i){
          const int row = m*16 + (q4<<2) + i, col = n*16 + cl;
          const float pv = 1.f/(1.f + __expf(-sac[m][n][i]*0.0625f));
          *(unsigned short*)((char*)P + row*128 + ((col*2) ^ ((row&7)<<4))) = f2bf(pv);
        }
    f32x4 aoc[3][2];
#pragma unroll
    for (int m=0;m<3;++m)
#pragma unroll
      for (int n=0;n<2;++n) aoc[m][n] = (f32x4){0.f,0.f,0.f,0.f};
#pragma unroll
    for (int ks=0; ks<2; ++ks){
      const int kb = ks*64 + (q4<<4);
      short8 pa[3], vb[2];
#pragma unroll
      for (int m=0;m<3;++m){
        const int r = m*16 + cl;
        pa[m] = *(const short8*)((const char*)P + r*128 + (kb ^ ((r&7)<<4)));
      }
#pragma unroll
      for (int n=0;n<2;++n){
        vb[n] = zero8();
        if (ks == 0 || q4 < 2)
          vb[n] = *(const short8*)(vbb + (long)(h*32 + n*16 + cl)*48 + ks*32 + q4*8);
      }
#pragma unroll
      for (int m=0;m<3;++m)
#pragma unroll
        for (int n=0;n<2;++n)
          aoc[m][n] = __builtin_amdgcn_mfma_f32_16x16x32_bf16(pa[m], vb[n], aoc[m][n], 0,0,0);
    }
#pragma unroll
    for (int m=0;m<3;++m)
#pragma unroll
      for (int n=0;n<2;++n)
#pragma unroll
        for (int i=0;i<4;++i){
          const int row = m*16 + (q4<<2) + i;
          if (row < 39){
            const long gi = (((long)(b*39+row))<<8) + h*32 + n*16 + cl;
            const float nv = xf[gi] + aoc[m][n][i];
            xf[gi] = nv;
            ps1[m][i] += nv; ps2[m][i] += nv*nv;
          }
        }
  }
#pragma unroll
  for (int m=0;m<3;++m)
#pragma unroll
    for (int i=0;i<4;++i){
      float a1 = ps1[m][i], a2 = ps2[m][i];
#pragma unroll
      for (int off=8; off; off>>=1){ a1 += __shfl_xor(a1, off, 16); a2 += __shfl_xor(a2, off, 16); }
      const int row = m*16 + (q4<<2) + i;
      if (cl == 0 && row < 39){ part[row*8 + (w<<1)] = a1; part[row*8 + (w<<1) + 1] = a2; }
    }
  __syncthreads();
  if (tid < 39){
    const float S1 = part[tid*8]+part[tid*8+2]+part[tid*8+4]+part[tid*8+6];
    const float S2 = part[tid*8+1]+part[tid*8+3]+part[tid*8+5]+part[tid*8+7];
    const float mn = S1*(1.f/256.f);
    const float var = S2*(1.f/256.f) - mn*mn;
    const float s = rsqrtf(var + 1e-5f);
    sB[b*39+tid] = s; cB[b*39+tid] = -mn*s;
  }
}

// ---------------------------------------------------------------------------
// Final softmax MHA + out-proj + residual -> flat bf16 [B][9984]
// ---------------------------------------------------------------------------
__global__ __launch_bounds__(256)
void attn_fin_k(const unsigned short* __restrict__ qkb,
                const unsigned short* __restrict__ vT,
                const float* __restrict__ xf,
                const unsigned short* __restrict__ moW,
                const float* __restrict__ moB,
                unsigned short* __restrict__ flatb)
{
  __shared__ __align__(16) unsigned short Ps[4*48*64];
  __shared__ __align__(16) unsigned short Mo[48*256];

  const int b = blockIdx.x;
  const int tid = threadIdx.x, lane = tid & 63, w = tid >> 6;
  const int cl = lane & 15, q4 = lane >> 4;
  unsigned short* P = Ps + w*3072;
  const unsigned short* qb = qkb + (long)b*39*512;
  const unsigned short* vbb = vT + (long)b*256*48;
  const float SC = 0.17677669529663687f;

  if (lane < 48){
    const int r = lane;
    *(short8*)((char*)P + r*128 + (96  ^ ((r&7)<<4))) = zero8();
    *(short8*)((char*)P + r*128 + (112 ^ ((r&7)<<4))) = zero8();
  }

#pragma unroll
  for (int hh=0; hh<2; ++hh){
    const int h = (w<<1) + hh;
    f32x4 sac[3][3];
#pragma unroll
    for (int m=0;m<3;++m)
#pragma unroll
      for (int n=0;n<3;++n) sac[m][n] = (f32x4){0.f,0.f,0.f,0.f};
    short8 aq[3], bk8[3];
#pragma unroll
    for (int m=0;m<3;++m){
      const int r = m*16 + cl;
      aq[m] = (r < 39) ? *(const short8*)(qb + (long)r*512 + h*32 + q4*8) : zero8();
    }
#pragma unroll
    for (int n=0;n<3;++n){
      const int r = n*16 + cl;
      bk8[n] = (r < 39) ? *(const short8*)(qb + (long)r*512 + 256 + h*32 + q4*8) : zero8();
    }
#pragma unroll
    for (int m=0;m<3;++m)
#pragma unroll
      for (int n=0;n<3;++n)
        sac[m][n] = __builtin_amdgcn_mfma_f32_16x16x32_bf16(aq[m], bk8[n], sac[m][n], 0,0,0);
#pragma unroll
    for (int m=0;m<3;++m)
#pragma unroll
      for (int i=0;i<4;++i){
        const float v0 = sac[m][0][i]*SC, v1 = sac[m][1][i]*SC, v2 = sac[m][2][i]*SC;
        const bool c2ok = (32 + cl) < 39;
        float mx = fmaxf(v0, v1);
        if (c2ok) mx = fmaxf(mx, v2);
#pragma unroll
        for (int off=8; off; off>>=1) mx = fmaxf(mx, __shfl_xor(mx, off, 16));
        const float e0 = __expf(v0-mx), e1 = __expf(v1-mx);
        const float e2 = c2ok ? __expf(v2-mx) : 0.f;
        float s = e0+e1+e2;
#pragma unroll
        for (int off=8; off; off>>=1) s += __shfl_xor(s, off, 16);
        const float inv = 1.f/s;
        const int row = m*16 + (q4<<2) + i;
        *(unsigned short*)((char*)P + row*128 + (((cl   )*2) ^ ((row&7)<<4))) = f2bf(e0*inv);
        *(unsigned short*)((char*)P + row*128 + (((16+cl)*2) ^ ((row&7)<<4))) = f2bf(e1*inv);
        *(unsigned short*)((char*)P + row*128 + (((32+cl)*2) ^ ((row&7)<<4))) = f2bf(e2*inv);
      }
    f32x4 aoc[3][2];
#pragma unroll
    for (int m=0;m<3;++m)
#pragma unroll
      for (int n=0;n<2;++n) aoc[m][n] = (f32x4){0.f,0.f,0.f,0.f};
#pragma unroll
    for (int ks=0; ks<2; ++ks){
      const int kb = ks*64 + (q4<<4);
      short8 pa[3], vb[2];
#pragma unroll
      for (int m=0;m<3;++m){
        const int r = m*16 + cl;
        pa[m] = *(const short8*)((const char*)P + r*128 + (kb ^ ((r&7)<<4)));
      }
#pragma unroll
      for (int n=0;n<2;++n){
        vb[n] = zero8();
        if (ks == 0 || q4 < 2)
          vb[n] = *(const short8*)(vbb + (long)(h*32 + n*16 + cl)*48 + ks*32 + q4*8);
      }
#pragma unroll
      for (int m=0;m<3;++m)
#pragma unroll
        for (int n=0;n<2;++n)
          aoc[m][n] = __builtin_amdgcn_mfma_f32_16x16x32_bf16(pa[m], vb[n], aoc[m][n], 0,0,0);
    }
#pragma unroll
    for (int m=0;m<3;++m)
#pragma unroll
      for (int n=0;n<2;++n)
#pragma unroll
        for (int i=0;i<4;++i){
          const int row = m*16 + (q4<<2) + i;
          const int colq = h*32 + n*16 + cl;
          *(unsigned short*)((char*)Mo + row*512 + ((colq*2) ^ ((row&7)<<4))) = f2bf(aoc[m][n][i]);
        }
  }
  __syncthreads();
  f32x4 oc[3][4];
#pragma unroll
  for (int m=0;m<3;++m)
#pragma unroll
    for (int n=0;n<4;++n) oc[m][n] = (f32x4){0.f,0.f,0.f,0.f};
#pragma unroll
  for (int ks=0; ks<8; ++ks){
    const int kb = ks*64 + (q4<<4);
    short8 am[3], bm[4];
#pragma unroll
    for (int m=0;m<3;++m){
      const int r = m*16 + cl;
      am[m] = *(const short8*)((const char*)Mo + r*512 + (kb ^ ((r&7)<<4)));
    }
#pragma unroll
    for (int n=0;n<4;++n){
      const int nn = (w<<6) + n*16 + cl;
      bm[n] = *(const short8*)(moW + (long)nn*256 + ks*32 + q4*8);
    }
#pragma unroll
    for (int m=0;m<3;++m)
#pragma unroll
      for (int n=0;n<4;++n)
        oc[m][n] = __builtin_amdgcn_mfma_f32_16x16x32_bf16(am[m], bm[n], oc[m][n], 0,0,0);
  }
#pragma unroll
  for (int m=0;m<3;++m)
#pragma unroll
    for (int n=0;n<4;++n)
#pragma unroll
      for (int i=0;i<4;++i){
        const int row = m*16 + (q4<<2) + i;
        if (row < 39){
          const int col = (w<<6) + n*16 + cl;
          const float v = oc[m][n][i] + moB[col] + xf[(((long)(b*39+row))<<8) + col];
          flatb[(long)b*9984 + row*256 + col] = f2bf(v);
        }
      }
}

// ---------------------------------------------------------------------------
// Embedding + x0 bf16 + xln1 (normalized) write
// ---------------------------------------------------------------------------
__global__ __launch_bounds__(256)
void embed_k(const float* __restrict__ dense_x, const int* __restrict__ sparse_x,
             const float* __restrict__ W_dense, const float* __restrict__ b_dense,
             const float* __restrict__ emb,
             float* __restrict__ xf, unsigned short* __restrict__ x0b,
             unsigned short* __restrict__ xln1)
{
  const int bid = blockIdx.x;
  const int b = bid / 39, t = bid - b*39;
  const int c = threadIdx.x;
  float v;
  if (t < 13){
    const int j = t*256 + c;
    v = b_dense[j];
    const float* wr = W_dense + (long)j*13;
    const float* dx = dense_x + (long)b*13;
#pragma unroll
    for (int k2=0;k2<13;++k2) v = fmaf(dx[k2], wr[k2], v);
  } else {
    const int idx = sparse_x[b*26 + (t-13)];
    v = (idx == 0) ? 0.f : emb[((long)(t-13)*10001 + idx)*256 + c];
  }
  const long row = bid;
  xf[row*256 + c] = v;
  x0b[row*256 + c] = f2bf(v);
  float s1 = v, s2 = v*v;
#pragma unroll
  for (int off=32; off; off>>=1){ s1 += __shfl_xor(s1, off); s2 += __shfl_xor(s2, off); }
  __shared__ float r1[4], r2[4];
  const int lane = c & 63, wq = c >> 6;
  if (lane == 0){ r1[wq]=s1; r2[wq]=s2; }
  __syncthreads();
  const float S1 = r1[0]+r1[1]+r1[2]+r1[3];
  const float S2 = r2[0]+r2[1]+r2[2]+r2[3];
  const float mn = S1*(1.f/256.f);
  const float var = S2*(1.f/256.f) - mn*mn;
  const float s = rsqrtf(var+1e-5f);
  xln1[row*256 + c] = f2bf((v - mn)*s);
}

// ---------------------------------------------------------------------------
// AttentionResidual block mixing (+ xln1 write)
// ---------------------------------------------------------------------------
template<int NSRC>
__global__ __launch_bounds__(256)
void mix_k(float* __restrict__ xf,
           const unsigned short* __restrict__ s0,
           const unsigned short* __restrict__ s1p,
           const unsigned short* __restrict__ s2p,
           unsigned short* mout,
           const float* __restrict__ qvec, int qi,
           unsigned short* __restrict__ xln1)
{
  const int b = blockIdx.x;
  const int tid = threadIdx.x, lane = tid&63, w = tid>>6;
  const int c4 = lane << 2;
  f32x4 q = *(const f32x4*)(qvec + qi*256 + c4);
  float qq = q[0]*q[0]+q[1]*q[1]+q[2]*q[2]+q[3]*q[3];
#pragma unroll
  for (int off=32; off; off>>=1) qq += __shfl_xor(qq, off);
  const float qsc = 1.f/fmaxf(sqrtf(qq), 1e-12f);
#pragma unroll
  for (int e=0;e<4;++e) q[e] *= qsc;
  for (int t = w; t < 39; t += 4){
    const long ro = ((long)(b*39+t))*256 + c4;
    f32x4 v[NSRC];
#pragma unroll
    for (int n=0;n<NSRC;++n){
      if (n == NSRC-1) v[n] = *(const f32x4*)(xf + ro);
      else {
        const unsigned short* sp = (n==0)?s0:((n==1)?s1p:s2p);
        us4 u = *(const us4*)(sp + ro);
#pragma unroll
        for (int e=0;e<4;++e) v[n][e] = bf2f(u[e]);
      }
    }
    float lg[NSRC];
#pragma unroll
    for (int n=0;n<NSRC;++n){
      float nn = v[n][0]*v[n][0]+v[n][1]*v[n][1]+v[n][2]*v[n][2]+v[n][3]*v[n][3];
      float dd = q[0]*v[n][0]+q[1]*v[n][1]+q[2]*v[n][2]+q[3]*v[n][3];
#pragma unroll
      for (int off=32; off; off>>=1){ nn += __shfl_xor(nn,off); dd += __shfl_xor(dd,off); }
      lg[n] = dd / fmaxf(sqrtf(nn), 1e-12f);
    }
    float mx = lg[0];
#pragma unroll
    for (int n=1;n<NSRC;++n) mx = fmaxf(mx, lg[n]);
    float es = 0.f, e_[NSRC];
#pragma unroll
    for (int n=0;n<NSRC;++n){ e_[n] = __expf(lg[n]-mx); es += e_[n]; }
    const float inv = 1.f/es;
    f32x4 o = {0.f,0.f,0.f,0.f};
#pragma unroll
    for (int n=0;n<NSRC;++n){
      const float wt = e_[n]*inv;
#pragma unroll
      for (int e=0;e<4;++e) o[e] = fmaf(wt, v[n][e], o[e]);
    }
    *(f32x4*)(xf + ro) = o;
    if (mout){
      us4 u;
#pragma unroll
      for (int e=0;e<4;++e) u[e] = f2bf(o[e]);
      *(us4*)(mout + ro) = u;
    }
    float s1 = o[0]+o[1]+o[2]+o[3];
    float s2 = o[0]*o[0]+o[1]*o[1]+o[2]*o[2]+o[3]*o[3];
#pragma unroll
    for (int off=32; off; off>>=1){ s1 += __shfl_xor(s1,off); s2 += __shfl_xor(s2,off); }
    const float mn = s1*(1.f/256.f);
    const float var = s2*(1.f/256.f)-mn*mn;
    const float s = rsqrtf(var+1e-5f);
    const float c = -mn*s;
    us4 u2;
#pragma unroll
    for (int e=0;e<4;++e) u2[e] = f2bf(o[e]*s + c);
    *(us4*)(xln1 + ro) = u2;
  }
}

__global__ __launch_bounds__(256)
void head2_k(const unsigned short* __restrict__ h1h, const float* __restrict__ Wo2,
             const float* __restrict__ bo2, float* __restrict__ outp)
{
  const int b = blockIdx.x*4 + (threadIdx.x>>6);
  const int lane = threadIdx.x & 63;
  float s = 0.f;
#pragma unroll
  for (int g=0; g<2; ++g){
    const int base = lane*16 + g*8;
    short8 v8 = *(const short8*)(h1h + (long)b*1024 + base);
#pragma unroll
    for (int e=0;e<8;++e) s = fmaf(bf2f((unsigned short)v8[e]), Wo2[base+e], s);
  }
#pragma unroll
  for (int off=32; off; off>>=1) s += __shfl_xor(s, off);
  if (lane==0) outp[b] = s + bo2[0];
}

// ------------------------- weight prep kernels ------------------------------
__global__ void cvt_k(const float* __restrict__ src, unsigned short* __restrict__ dst, long n){
  const long i = (long)blockIdx.x*256 + threadIdx.x;
  if (i < n) dst[i] = f2bf(src[i]);
}
__global__ void prep_qkv_k(const float* Wq, const float* Wk, const float* Wv,
                           const float* g, unsigned short* dst){
  const int n = blockIdx.x, i = blockIdx.y, k = threadIdx.x;
  const int sel = n >> 8, nn = n & 255;
  const float* W = sel==0?Wq:(sel==1?Wk:Wv);
  dst[((long)i*768 + n)*256 + k] = f2bf(W[((long)i*256+nn)*256 + k] * g[i*256+k]);
}
__global__ void prep_qkvb_k(const float* Wq,const float* Wk,const float* Wv,
                            const float* bq,const float* bk,const float* bv,
                            const float* beta, float* dst){
  const int n = blockIdx.x, i = blockIdx.y, k = threadIdx.x;
  const int sel = n>>8, nn = n&255;
  const float* W = sel==0?Wq:(sel==1?Wk:Wv);
  const float* bb = sel==0?bq:(sel==1?bk:bv);
  float v = beta[i*256+k] * W[((long)i*256+nn)*256+k];
  __shared__ float r[4];
#pragma unroll
  for (int off=32; off; off>>=1) v += __shfl_xor(v, off);
  if ((k&63)==0) r[k>>6] = v;
  __syncthreads();
  if (k==0) dst[i*768+n] = bb[i*256+nn] + r[0]+r[1]+r[2]+r[3];
}
__global__ void prep_w1_k(const float* W1, const float* g, unsigned short* dst){
  const int n = blockIdx.x, i = blockIdx.y, k = threadIdx.x;
  const long o = ((long)i*1024+n)*256 + k;
  dst[o] = f2bf(W1[o] * g[i*256+k]);
}
__global__ void prep_w1b_k(const float* W1, const float* b1, const float* beta, float* dst){
  const int n = blockIdx.x, i = blockIdx.y, k = threadIdx.x;
  float v = beta[i*256+k] * W1[((long)i*1024+n)*256+k];
  __shared__ float r[4];
#pragma unroll
  for (int off=32; off; off>>=1) v += __shfl_xor(v, off);
  if ((k&63)==0) r[k>>6] = v;
  __syncthreads();
  if (k==0) dst[i*1024+n] = b1[i*1024+n] + r[0]+r[1]+r[2]+r[3];
}
__global__ void prep_mha_k(const float* W, const float* g, unsigned short* dst){
  const int n = blockIdx.x, k = threadIdx.x;
  dst[n*256+k] = f2bf(W[n*256+k]*g[k]);
}
__global__ void prep_mhab_k(const float* W, const float* bb, const float* beta, float* dst){
  const int n = blockIdx.x, k = threadIdx.x;
  float v = beta[k]*W[n*256+k];
  __shared__ float r[4];
#pragma unroll
  for (int off=32; off; off>>=1) v += __shfl_xor(v, off);
  if ((k&63)==0) r[k>>6] = v;
  __syncthreads();
  if (k==0) dst[n] = bb[n] + r[0]+r[1]+r[2]+r[3];
}

// ---------------------------------------------------------------------------
extern "C" void kernel_launch(void* const* d_in, const int* in_sizes, int n_in,
                              void* d_out, int out_size, void* d_ws, size_t ws_size,
                              hipStream_t stream)
{
  (void)in_sizes; (void)n_in; (void)out_size; (void)ws_size;
  const float* dense_x  = (const float*)d_in[0];
  const int*   sparse_x = (const int*)d_in[1];
  const float* W_dense  = (const float*)d_in[2];
  const float* b_dense  = (const float*)d_in[3];
  const float* emb      = (const float*)d_in[4];
  const float* Wq = (const float*)d_in[5];
  const float* bq = (const float*)d_in[6];
  const float* Wk = (const float*)d_in[7];
  const float* bk = (const float*)d_in[8];
  const float* Wv = (const float*)d_in[9];
  const float* bv = (const float*)d_in[10];
  const float* W1 = (const float*)d_in[11];
  const float* b1 = (const float*)d_in[12];
  const float* W2 = (const float*)d_in[13];
  const float* b2 = (const float*)d_in[14];
  const float* n1g= (const float*)d_in[15];
  const float* n1b= (const float*)d_in[16];
  const float* n2g= (const float*)d_in[17];
  const float* n2b= (const float*)d_in[18];
  const float* qvec=(const float*)d_in[19];
  const float* mha_in_w = (const float*)d_in[20];
  const float* mha_in_b = (const float*)d_in[21];
  const float* mha_out_w= (const float*)d_in[22];
  const float* mha_out_b= (const float*)d_in[23];
  const float* ng = (const float*)d_in[24];
  const float* ngb= (const float*)d_in[25];
  const float* Wo1= (const float*)d_in[26];
  const float* bo1= (const float*)d_in[27];
  const float* Wo2= (const float*)d_in[28];
  const float* bo2= (const float*)d_in[29];

  char* ws = (char*)d_ws;
  size_t off = 0;
  auto alloc = [&](size_t bytes)->void*{ void* p = ws + off; off += (bytes + 255) & ~(size_t)255; return p; };
  float* xf            = (float*)alloc(163577856ull);           // [159744][256] f32
  unsigned short* qkh  = (unsigned short*)alloc(163577856ull);  // [159744][512] bf16 (Q|K)
  unsigned short* vT   = (unsigned short*)alloc(100663296ull);  // [4096][256][48] bf16
  unsigned short* x0b  = (unsigned short*)alloc(81788928ull);
  unsigned short* m1b  = (unsigned short*)alloc(81788928ull);   // aliased as flatb at end
  unsigned short* m2b  = (unsigned short*)alloc(81788928ull);
  unsigned short* xln1 = (unsigned short*)alloc(81788928ull);
  unsigned short* h1h  = (unsigned short*)alloc(8388608ull);    // [4096][1024] bf16
  float* sB = (float*)alloc(638976ull);
  float* cB = (float*)alloc(638976ull);
  unsigned short* Wqkv_f = (unsigned short*)alloc(3145728ull);
  float* bqkv_f = (float*)alloc(24576ull);
  unsigned short* W1_f = (unsigned short*)alloc(4194304ull);
  float* b1_f = (float*)alloc(32768ull);
  unsigned short* W2_f = (unsigned short*)alloc(4194304ull);
  unsigned short* mhain_f = (unsigned short*)alloc(393216ull);
  float* mhainb_f = (float*)alloc(3072ull);
  unsigned short* mhaout_f = (unsigned short*)alloc(131072ull);
  unsigned short* Wo1_f = (unsigned short*)alloc(20447232ull);

  unsigned short* flatb = m1b;   // m1b dead after layer-5 mix

  // weight prep
  cvt_k<<<8192,256,0,stream>>>(W2, W2_f, 2097152L);
  cvt_k<<<256,256,0,stream>>>(mha_out_w, mhaout_f, 65536L);
  cvt_k<<<39936,256,0,stream>>>(Wo1, Wo1_f, 10223616L);
  prep_qkv_k<<<dim3(768,8),256,0,stream>>>(Wq,Wk,Wv,n1g,Wqkv_f);
  prep_qkvb_k<<<dim3(768,8),256,0,stream>>>(Wq,Wk,Wv,bq,bk,bv,n1b,bqkv_f);
  prep_w1_k<<<dim3(1024,8),256,0,stream>>>(W1,n2g,W1_f);
  prep_w1b_k<<<dim3(1024,8),256,0,stream>>>(W1,b1,n2b,b1_f);
  prep_mha_k<<<768,256,0,stream>>>(mha_in_w, ng, mhain_f);
  prep_mhab_k<<<768,256,0,stream>>>(mha_in_w, mha_in_b, ngb, mhainb_f);

  embed_k<<<159744,256,0,stream>>>(dense_x, sparse_x, W_dense, b_dense, emb, xf, x0b, xln1);

  for (int i = 0; i < 8; ++i){
    qkv_k<<<1248,256,0,stream>>>(xln1, Wqkv_f + (size_t)i*196608, bqkv_f + i*768, qkh, vT);
    attn_sig_k<<<4096,256,0,stream>>>(qkh, vT, xf, sB, cB);
    const int wx = (i==1 || i==3 || i==5) ? 0 : 1;
    ffn_k<<<1248,256,0,stream>>>(xf, sB, cB,
        W1_f + (size_t)i*262144, b1_f + i*1024,
        W2_f + (size_t)i*262144, b2 + i*256, xf, xln1, wx);
    if (i == 1)      mix_k<2><<<4096,256,0,stream>>>(xf, x0b, m1b, m2b, m1b, qvec, 1, xln1);
    else if (i == 3) mix_k<3><<<4096,256,0,stream>>>(xf, x0b, m1b, m2b, m2b, qvec, 2, xln1);
    else if (i == 5) mix_k<4><<<4096,256,0,stream>>>(xf, x0b, m1b, m2b, nullptr, qvec, 3, xln1);
  }
  qkv_k<<<1248,256,0,stream>>>(xln1, mhain_f, mhainb_f, qkh, vT);
  attn_fin_k<<<4096,256,0,stream>>>(qkh, vT, xf, mhaout_f, mha_out_b, flatb);
  gemm_k<<<256,256,0,stream>>>(flatb, 9984, Wo1_f, bo1, h1h, 1024, 9984, 8);
  head2_k<<<1024,256,0,stream>>>(h1h, Wo2, bo2, (float*)d_out);
}

// Round 13
// 6719.167 us; speedup vs baseline: 1.4071x; 1.1775x over previous
//
#include <hip/hip_runtime.h>
#include <hip/hip_bf16.h>

typedef __attribute__((ext_vector_type(4))) float f32x4;
typedef __attribute__((ext_vector_type(8))) short short8;
typedef __attribute__((ext_vector_type(4))) unsigned short us4;

static __device__ __forceinline__ unsigned short f2bf(float f){
  return __builtin_bit_cast(unsigned short, __float2bfloat16(f));
}
static __device__ __forceinline__ float bf2f(unsigned short u){
  return __bfloat162float(__builtin_bit_cast(__hip_bfloat16, u));
}
static __device__ __forceinline__ short8 zero8(){
  short8 v;
#pragma unroll
  for (int e=0;e<8;++e) v[e]=0;
  return v;
}
// async global->LDS, 16B/lane; lds dest wave-uniform base + lane*16
static __device__ __forceinline__ void g2l16(const void* g, void* l){
  __builtin_amdgcn_global_load_lds(
    (const __attribute__((address_space(1))) unsigned int*)g,
    (__attribute__((address_space(3))) unsigned int*)l, 16, 0, 0);
}

// ---------------------------------------------------------------------------
// QKV GEMM: out[row][0..767] = xln1[row][:] @ Wqkv^T + bias. 128 rows/block.
// A staged ONCE in 64KB swizzled LDS; B fragments direct from L2 (393KB).
// ---------------------------------------------------------------------------
__global__ __launch_bounds__(256)
void qkv_k(const unsigned short* __restrict__ Ap,   // xln1 [..][256]
           const unsigned short* __restrict__ Bp,   // Wqkv [768][256]
           const float* __restrict__ bias,          // [768]
           unsigned short* __restrict__ qk,         // [..][512]
           unsigned short* __restrict__ vT)         // [4096][256][48]
{
  __shared__ __align__(16) unsigned short As[128*256];  // 4 k-tiles [128][64] swizzled

  const int tid = threadIdx.x, lane = tid & 63, w = tid >> 6;
  const int cl = lane & 15, q4 = lane >> 4;
  const long rowBase = (long)blockIdx.x << 7;
  const int wm = (w >> 1) << 6, wn = (w & 1) << 6;

  // stage A: 4096 chunks of 16B; chunk c = kt*1024 + r*8 + x holds global x^(r&7)
#pragma unroll
  for (int it=0; it<16; ++it){
    const int c = (it<<8) + (w<<6) + lane;
    const int kt = c>>10, rem = c & 1023, r = rem>>3, x = rem&7;
    g2l16(Ap + (rowBase + r)*256 + (kt<<6) + (((x ^ (r&7)))<<3),
          As + (((it<<8) + (w<<6))<<3));
  }
  __syncthreads();

  for (int cb=0; cb<6; ++cb){
    f32x4 acc[4][4];
#pragma unroll
    for (int m=0;m<4;++m)
#pragma unroll
      for (int n=0;n<4;++n) acc[m][n] = (f32x4){0.f,0.f,0.f,0.f};
#pragma unroll
    for (int kt=0; kt<4; ++kt)
#pragma unroll
      for (int ks=0; ks<2; ++ks){
        const int kb = ks*64 + (q4<<4);
        short8 af[4], bf_[4];
#pragma unroll
        for (int m=0;m<4;++m){
          const int r = wm + m*16 + cl;
          af[m] = *(const short8*)((const char*)As + (kt<<14) + r*128 + (kb ^ ((r&7)<<4)));
        }
#pragma unroll
        for (int n=0;n<4;++n){
          const long rn = cb*128 + wn + n*16 + cl;
          bf_[n] = *(const short8*)(Bp + rn*256 + (kt<<6) + ks*32 + (q4<<3));
        }
#pragma unroll
        for (int m=0;m<4;++m)
#pragma unroll
          for (int n=0;n<4;++n)
            acc[m][n] = __builtin_amdgcn_mfma_f32_16x16x32_bf16(af[m], bf_[n], acc[m][n], 0,0,0);
      }
    // epilogue for this col-block
#pragma unroll
    for (int n=0;n<4;++n){
      const int col = cb*128 + wn + n*16 + cl;
      const float bi = bias[col];
#pragma unroll
      for (int m=0;m<4;++m){
        const long r0 = rowBase + wm + m*16 + (q4<<2);
#pragma unroll
        for (int i=0;i<4;++i){
          const float v = acc[m][n][i] + bi;
          const long row = r0 + i;
          if (col < 512){
            qk[row*512 + col] = f2bf(v);
          } else {
            const int bb = (int)row / 39;
            const int tt = (int)row - bb*39;
            unsigned short* vrow = vT + ((long)bb*256 + (col - 512))*48;
            vrow[tt] = f2bf(v);
            if (tt < 9) vrow[tt + 39] = 0;   // zero pad (tokens 39..47)
          }
        }
      }
    }
  }
}

// ---------------------------------------------------------------------------
// GEMM (head): C = A @ B^T + bias -> relu -> bf16. 128x128 tile, BK=64.
// ---------------------------------------------------------------------------
__global__ __launch_bounds__(256)
void gemm_k(const unsigned short* __restrict__ Ap, int lda,
            const unsigned short* __restrict__ Bp,
            const float* __restrict__ bias,
            unsigned short* __restrict__ Outp, int ldo, int K, int nColBlk)
{
  const int id = blockIdx.x;
  const int xcd = id & 7; const int t0 = id >> 3;
  const int cb = t0 % nColBlk; const int rb = (t0 / nColBlk)*8 + xcd;
  const long rowBase = (long)rb << 7;
  const long colBase = (long)cb << 7;
  const int tid = threadIdx.x, lane = tid & 63, w = tid >> 6;
  const int wm = (w >> 1) << 6, wn = (w & 1) << 6;
  const int cl = lane & 15, q4 = lane >> 4;

  __shared__ __align__(16) unsigned short As[128*64];
  __shared__ __align__(16) unsigned short Bs[128*64];

  const char* bSrc[4]; unsigned short* bDst[4];
  const char* aSrc[4]; unsigned short* aDst[4];
#pragma unroll
  for (int g=0; g<4; ++g){
    const int c = (w<<8) + (g<<6) + lane;
    const int r = c>>3, x = c&7, c16 = x ^ (r&7);
    bSrc[g] = (const char*)(Bp + (colBase + r)*(long)K) + c16*16;
    bDst[g] = Bs + (((w<<2)+g)<<9);
    aSrc[g] = (const char*)(Ap + (rowBase + r)*(long)lda) + c16*16;
    aDst[g] = As + (((w<<2)+g)<<9);
  }

  f32x4 acc[4][4];
#pragma unroll
  for (int m=0;m<4;++m)
#pragma unroll
    for (int n=0;n<4;++n) acc[m][n] = (f32x4){0.f,0.f,0.f,0.f};

  const int nk = K >> 6;
  for (int t=0; t<nk; ++t){
    if (t) __syncthreads();
    const long tb = (long)t << 7;
#pragma unroll
    for (int g=0; g<4; ++g){
      g2l16(bSrc[g] + tb, bDst[g]);
      g2l16(aSrc[g] + tb, aDst[g]);
    }
    __syncthreads();
#pragma unroll
    for (int ks=0; ks<2; ++ks){
      const int kb = ks*64 + (q4<<4);
      short8 af[4], bf_[4];
#pragma unroll
      for (int m=0;m<4;++m){
        const int r = wm + m*16 + cl;
        af[m] = *(const short8*)((const char*)As + r*128 + (kb ^ ((r&7)<<4)));
      }
#pragma unroll
      for (int n=0;n<4;++n){
        const int r = wn + n*16 + cl;
        bf_[n] = *(const short8*)((const char*)Bs + r*128 + (kb ^ ((r&7)<<4)));
      }
#pragma unroll
      for (int m=0;m<4;++m)
#pragma unroll
        for (int n=0;n<4;++n)
          acc[m][n] = __builtin_amdgcn_mfma_f32_16x16x32_bf16(af[m], bf_[n], acc[m][n], 0,0,0);
    }
  }

#pragma unroll
  for (int n=0;n<4;++n){
    const long col = colBase + wn + n*16 + cl;
    const float bi = bias[col];
#pragma unroll
    for (int m=0;m<4;++m){
      const long r0 = rowBase + wm + m*16 + (q4<<2);
#pragma unroll
      for (int i=0;i<4;++i){
        const float v = acc[m][n][i] + bi;
        Outp[(r0+i)*(long)ldo + col] = f2bf(fmaxf(v,0.f));
      }
    }
  }
}

// ---------------------------------------------------------------------------
// Fused FFN (R10 v6, best measured: 305us): 64 rows/block, 256 threads,
// LDS = W1c(32K)+W2c(32K)+Hs(8K) = 72KB -> 2 blocks/CU; regs 112+64=176
// under the (256,2) cap of 256 -> no spill, co-resident staging overlap.
// ---------------------------------------------------------------------------
__global__ __launch_bounds__(256, 2)
void ffn_k(const float* __restrict__ xf_in,
           const float* __restrict__ sB, const float* __restrict__ cB,
           const unsigned short* __restrict__ W1p,  // [1024][256]
           const float* __restrict__ b1p,           // [1024]
           const unsigned short* __restrict__ W2p,  // [256][1024]
           const float* __restrict__ b2p,           // [256]
           float* __restrict__ xf,
           unsigned short* __restrict__ xln1, int writeXln)
{
  __shared__ __align__(16) unsigned short Wb1[64*256];  // 32KB, 4 k-tiles [64][64]
  __shared__ __align__(16) unsigned short Wb2[256*64];  // 32KB, [256][64] swizzled
  __shared__ __align__(16) unsigned short Hs[64*64];    // 8KB
  // epilogue scratch aliased onto Wb1 (dead after last H phase)
  float* part1 = (float*)Wb1;          // 256 f
  float* part2 = part1 + 256;          // 256 f
  float* sln   = part2 + 256;          // 64 f
  float* cln   = sln + 64;             // 64 f

  const int tid = threadIdx.x, lane = tid & 63, w = tid >> 6;
  const int cl = lane & 15, q4 = lane >> 4;
  const long rowBase = (long)blockIdx.x << 6;   // 64 rows/block

  // ---- A = LN2(x) in registers, MFMA fragment layout ----
  short8 af[8];
  {
    const int row = (w<<4) + cl;
    const float s = sB[rowBase + row], c = cB[rowBase + row];
    const float* src = xf_in + (rowBase + row)*256 + (q4<<3);
#pragma unroll
    for (int kt=0; kt<8; ++kt){
      f32x4 a = *(const f32x4*)(src + kt*32);
      f32x4 b = *(const f32x4*)(src + kt*32 + 4);
      short8 v;
#pragma unroll
      for (int e=0;e<4;++e){ v[e] = (short)f2bf(a[e]*s + c); v[4+e] = (short)f2bf(b[e]*s + c); }
      af[kt] = v;
    }
  }

  // acc: wave w -> rows 0..63 (m), cols [64w, 64w+64) (n)
  f32x4 acc[4][4];
#pragma unroll
  for (int m=0;m<4;++m)
#pragma unroll
    for (int n=0;n<4;++n) acc[m][n] = (f32x4){0.f,0.f,0.f,0.f};

  for (int j=0; j<16; ++j){
    const int ffbase = j<<6;
    __syncthreads();   // prev chunk's W/Hs readers done
    // stage W1c [64 ff][256 k] (2048x16B) + W2c [256 out][64 ff] (2048x16B)
#pragma unroll
    for (int it=0; it<8; ++it){
      const int c = (it<<8) + tid;
      { // W1: 4 k-tiles of [64][64]; chunk c = kt*512 + rr*8 + xs
        const int kt = c>>9, cc = c&511, rr = cc>>3, xs = cc&7;
        g2l16(W1p + ((long)(ffbase+rr))*256 + (kt<<6) + ((xs^(rr&7))<<3),
              Wb1 + (((it<<8) + (w<<6))<<3));
      }
      { // W2: rows = out cols (256), 64-ff slice; chunk c = rr*8 + xs
        const int rr = c>>3, xs = c&7;
        g2l16(W2p + (long)rr*1024 + ffbase + ((xs^(rr&7))<<3),
              Wb2 + (((it<<8) + (w<<6))<<3));
      }
    }
    float b1v[4];
#pragma unroll
    for (int n=0;n<4;++n) b1v[n] = b1p[ffbase + n*16 + cl];
    __syncthreads();   // staged (vmcnt drained by barrier)

    // H = A @ W1c^T : wave w -> rows [16w,16w+16) x 64 ff cols, A from regs
    f32x4 hacc[4];
#pragma unroll
    for (int n=0;n<4;++n) hacc[n] = (f32x4){0.f,0.f,0.f,0.f};
#pragma unroll
    for (int kt2=0; kt2<4; ++kt2)
#pragma unroll
      for (int ks=0; ks<2; ++ks){
        const int kb = ks*64 + (q4<<4);
        const short8 a = af[kt2*2 + ks];
#pragma unroll
        for (int n=0;n<4;++n){
          const int rn = n*16 + cl;
          short8 bf_ = *(const short8*)((const char*)Wb1 + (kt2<<13) + rn*128 + (kb ^ ((rn&7)<<4)));
          hacc[n] = __builtin_amdgcn_mfma_f32_16x16x32_bf16(a, bf_, hacc[n], 0,0,0);
        }
      }
#pragma unroll
    for (int n=0;n<4;++n)
#pragma unroll
      for (int i=0;i<4;++i){
        const int hr = (w<<4) + (q4<<2) + i, hc = n*16 + cl;
        const float hv = fmaxf(hacc[n][i] + b1v[n], 0.f);
        *(unsigned short*)((char*)Hs + hr*128 + ((hc*2) ^ ((hr&7)<<4))) = f2bf(hv);
      }
    __syncthreads();   // Hs visible

    // OUT += Hs @ W2c^T : wave w -> cols [64w,64w+64); both from LDS
#pragma unroll
    for (int ks=0; ks<2; ++ks){
      const int kb = ks*64 + (q4<<4);
      short8 am[4], bm[4];
#pragma unroll
      for (int m=0;m<4;++m){
        const int r = m*16 + cl;
        am[m] = *(const short8*)((const char*)Hs + r*128 + (kb ^ ((r&7)<<4)));
      }
#pragma unroll
      for (int n=0;n<4;++n){
        const int r = (w<<6) + n*16 + cl;
        bm[n] = *(const short8*)((const char*)Wb2 + r*128 + (kb ^ ((r&7)<<4)));
      }
#pragma unroll
      for (int m=0;m<4;++m)
#pragma unroll
        for (int n=0;n<4;++n)
          acc[m][n] = __builtin_amdgcn_mfma_f32_16x16x32_bf16(am[m], bm[n], acc[m][n], 0,0,0);
    }
  }

  // ---- epilogue: residual, xf write, LN1 stats, xln1 write ----
#pragma unroll
  for (int n=0;n<4;++n){
    const int col = (w<<6) + n*16 + cl;
    const float bi = b2p[col];
#pragma unroll
    for (int m=0;m<4;++m)
#pragma unroll
      for (int i=0;i<4;++i){
        const int row = m*16 + (q4<<2) + i;
        const long gi = (rowBase + row)*256 + col;
        const float v = acc[m][n][i] + bi + xf[gi];
        acc[m][n][i] = v;
        xf[gi] = v;
      }
  }
  __syncthreads();   // Wb1/Wb2/Hs fully dead before aliasing scratch
#pragma unroll
  for (int m=0;m<4;++m)
#pragma unroll
    for (int i=0;i<4;++i){
      float s1 = 0.f, s2 = 0.f;
#pragma unroll
      for (int n=0;n<4;++n){ const float v = acc[m][n][i]; s1 += v; s2 += v*v; }
#pragma unroll
      for (int off=8; off; off>>=1){ s1 += __shfl_xor(s1, off, 16); s2 += __shfl_xor(s2, off, 16); }
      const int row = m*16 + (q4<<2) + i;
      if (cl == 0){ part1[row*4 + w] = s1; part2[row*4 + w] = s2; }
    }
  __syncthreads();
  if (tid < 64){
    const float S1 = part1[tid*4]+part1[tid*4+1]+part1[tid*4+2]+part1[tid*4+3];
    const float S2 = part2[tid*4]+part2[tid*4+1]+part2[tid*4+2]+part2[tid*4+3];
    const float mn = S1*(1.f/256.f);
    const float var = S2*(1.f/256.f) - mn*mn;
    const float s = rsqrtf(var + 1e-5f);
    sln[tid] = s; cln[tid] = -mn*s;
  }
  __syncthreads();
  if (writeXln){
#pragma unroll
    for (int m=0;m<4;++m)
#pragma unroll
      for (int i=0;i<4;++i){
        const int row = m*16 + (q4<<2) + i;
        const float s = sln[row], c = cln[row];
#pragma unroll
        for (int n=0;n<4;++n){
          const int col = (w<<6) + n*16 + cl;
          xln1[(rowBase + row)*256 + col] = f2bf(acc[m][n][i]*s + c);
        }
      }
  }
}

// ---------------------------------------------------------------------------
// Sigmoid (HSTU) attention. One block = one batch item, 2 heads/wave.
// ---------------------------------------------------------------------------
__global__ __launch_bounds__(256)
void attn_sig_k(const unsigned short* __restrict__ qkb,
                const unsigned short* __restrict__ vT,
                float* xf, float* __restrict__ sB, float* __restrict__ cB)
{
  __shared__ __align__(16) unsigned short Ps[4*48*64];
  __shared__ float part[312];

  const int b = blockIdx.x;
  const int tid = threadIdx.x, lane = tid & 63, w = tid >> 6;
  const int cl = lane & 15, q4 = lane >> 4;
  unsigned short* P = Ps + w*3072;
  const unsigned short* qb = qkb + (long)b*39*512;
  const unsigned short* vbb = vT + (long)b*256*48;

  if (lane < 48){
    const int r = lane;
    *(short8*)((char*)P + r*128 + (96  ^ ((r&7)<<4))) = zero8();
    *(short8*)((char*)P + r*128 + (112 ^ ((r&7)<<4))) = zero8();
  }

  float ps1[3][4], ps2[3][4];
#pragma unroll
  for (int m=0;m<3;++m)
#pragma unroll
    for (int i=0;i<4;++i){ ps1[m][i]=0.f; ps2[m][i]=0.f; }

#pragma unroll
  for (int hh=0; hh<2; ++hh){
    const int h = (w<<1) + hh;
    f32x4 sac[3][3];
#pragma unroll
    for (int m=0;m<3;++m)
#pragma unroll
      for (int n=0;n<3;++n) sac[m][n] = (f32x4){0.f,0.f,0.f,0.f};
    short8 aq[3], bk8[3];
#pragma unroll
    for (int m=0;m<3;++m){
      const int r = m*16 + cl;
      aq[m] = (r < 39) ? *(const short8*)(qb + (long)r*512 + h*32 + q4*8) : zero8();
    }
#pragma unroll
    for (int n=0;n<3;++n){
      const int r = n*16 + cl;
      bk8[n] = (r < 39) ? *(const short8*)(qb + (long)r*512 + 256 + h*32 + q4*8) : zero8();
    }
#pragma unroll
    for (int m=0;m<3;++m)
#pragma unroll
      for (int n=0;n<3;++n)
        sac[m][n] = __builtin_amdgcn_mfma_f32_16x16x32_bf16(aq[m], bk8[n], sac[m][n], 0,0,0);
#pragma unroll
    for (int m=0;m<3;++m)
#pragma unroll
      for (int n=0;n<3;++n)
#pragma unroll
        for (int i=0;i<4;++i){
          const int row = m*16 + (q4<<2) + i, col = n*16 + cl;
          const float pv = 1.f/(1.f + __expf(-sac[m][n][i]*0.0625f));
          *(unsigned short*)((char*)P + row*128 + ((col*2) ^ ((row&7)<<4))) = f2bf(pv);
        }
    f32x4 aoc[3][2];
#pragma unroll
    for (int m=0;m<3;++m)
#pragma unroll
      for (int n=0;n<2;++n) aoc[m][n] = (f32x4){0.f,0.f,0.f,0.f};
#pragma unroll
    for (int ks=0; ks<2; ++ks){
      const int kb = ks*64 + (q4<<4);
      short8 pa[3], vb[2];
#pragma unroll
      for (int m=0;m<3;++m){
        const int r = m*16 + cl;
        pa[m] = *(const short8*)((const char*)P + r*128 + (kb ^ ((r&7)<<4)));
      }
#pragma unroll
      for (int n=0;n<2;++n){
        vb[n] = zero8();
        if (ks == 0 || q4 < 2)
          vb[n] = *(const short8*)(vbb + (long)(h*32 + n*16 + cl)*48 + ks*32 + q4*8);
      }
#pragma unroll
      for (int m=0;m<3;++m)
#pragma unroll
        for (int n=0;n<2;++n)
          aoc[m][n] = __builtin_amdgcn_mfma_f32_16x16x32_bf16(pa[m], vb[n], aoc[m][n], 0,0,0);
    }
#pragma unroll
    for (int m=0;m<3;++m)
#pragma unroll
      for (int n=0;n<2;++n)
#pragma unroll
        for (int i=0;i<4;++i){
          const int row = m*16 + (q4<<2) + i;
          if (row < 39){
            const long gi = (((long)(b*39+row))<<8) + h*32 + n*16 + cl;
            const float nv = xf[gi] + aoc[m][n][i];
            xf[gi] = nv;
            ps1[m][i] += nv; ps2[m][i] += nv*nv;
          }
        }
  }
#pragma unroll
  for (int m=0;m<3;++m)
#pragma unroll
    for (int i=0;i<4;++i){
      float a1 = ps1[m][i], a2 = ps2[m][i];
#pragma unroll
      for (int off=8; off; off>>=1){ a1 += __shfl_xor(a1, off, 16); a2 += __shfl_xor(a2, off, 16); }
      const int row = m*16 + (q4<<2) + i;
      if (cl == 0 && row < 39){ part[row*8 + (w<<1)] = a1; part[row*8 + (w<<1) + 1] = a2; }
    }
  __syncthreads();
  if (tid < 39){
    const float S1 = part[tid*8]+part[tid*8+2]+part[tid*8+4]+part[tid*8+6];
    const float S2 = part[tid*8+1]+part[tid*8+3]+part[tid*8+5]+part[tid*8+7];
    const float mn = S1*(1.f/256.f);
    const float var = S2*(1.f/256.f) - mn*mn;
    const float s = rsqrtf(var + 1e-5f);
    sB[b*39+tid] = s; cB[b*39+tid] = -mn*s;
  }
}

// ---------------------------------------------------------------------------
// Final softmax MHA + out-proj + residual -> flat bf16 [B][9984]
// ---------------------------------------------------------------------------
__global__ __launch_bounds__(256)
void attn_fin_k(const unsigned short* __restrict__ qkb,
                const unsigned short* __restrict__ vT,
                const float* __restrict__ xf,
                const unsigned short* __restrict__ moW,
                const float* __restrict__ moB,
                unsigned short* __restrict__ flatb)
{
  __shared__ __align__(16) unsigned short Ps[4*48*64];
  __shared__ __align__(16) unsigned short Mo[48*256];

  const int b = blockIdx.x;
  const int tid = threadIdx.x, lane = tid & 63, w = tid >> 6;
  const int cl = lane & 15, q4 = lane >> 4;
  unsigned short* P = Ps + w*3072;
  const unsigned short* qb = qkb + (long)b*39*512;
  const unsigned short* vbb = vT + (long)b*256*48;
  const float SC = 0.17677669529663687f;

  if (lane < 48){
    const int r = lane;
    *(short8*)((char*)P + r*128 + (96  ^ ((r&7)<<4))) = zero8();
    *(short8*)((char*)P + r*128 + (112 ^ ((r&7)<<4))) = zero8();
  }

#pragma unroll
  for (int hh=0; hh<2; ++hh){
    const int h = (w<<1) + hh;
    f32x4 sac[3][3];
#pragma unroll
    for (int m=0;m<3;++m)
#pragma unroll
      for (int n=0;n<3;++n) sac[m][n] = (f32x4){0.f,0.f,0.f,0.f};
    short8 aq[3], bk8[3];
#pragma unroll
    for (int m=0;m<3;++m){
      const int r = m*16 + cl;
      aq[m] = (r < 39) ? *(const short8*)(qb + (long)r*512 + h*32 + q4*8) : zero8();
    }
#pragma unroll
    for (int n=0;n<3;++n){
      const int r = n*16 + cl;
      bk8[n] = (r < 39) ? *(const short8*)(qb + (long)r*512 + 256 + h*32 + q4*8) : zero8();
    }
#pragma unroll
    for (int m=0;m<3;++m)
#pragma unroll
      for (int n=0;n<3;++n)
        sac[m][n] = __builtin_amdgcn_mfma_f32_16x16x32_bf16(aq[m], bk8[n], sac[m][n], 0,0,0);
#pragma unroll
    for (int m=0;m<3;++m)
#pragma unroll
      for (int i=0;i<4;++i){
        const float v0 = sac[m][0][i]*SC, v1 = sac[m][1][i]*SC, v2 = sac[m][2][i]*SC;
        const bool c2ok = (32 + cl) < 39;
        float mx = fmaxf(v0, v1);
        if (c2ok) mx = fmaxf(mx, v2);
#pragma unroll
        for (int off=8; off; off>>=1) mx = fmaxf(mx, __shfl_xor(mx, off, 16));
        const float e0 = __expf(v0-mx), e1 = __expf(v1-mx);
        const float e2 = c2ok ? __expf(v2-mx) : 0.f;
        float s = e0+e1+e2;
#pragma unroll
        for (int off=8; off; off>>=1) s += __shfl_xor(s, off, 16);
        const float inv = 1.f/s;
        const int row = m*16 + (q4<<2) + i;
        *(unsigned short*)((char*)P + row*128 + (((cl   )*2) ^ ((row&7)<<4))) = f2bf(e0*inv);
        *(unsigned short*)((char*)P + row*128 + (((16+cl)*2) ^ ((row&7)<<4))) = f2bf(e1*inv);
        *(unsigned short*)((char*)P + row*128 + (((32+cl)*2) ^ ((row&7)<<4))) = f2bf(e2*inv);
      }
    f32x4 aoc[3][2];
#pragma unroll
    for (int m=0;m<3;++m)
#pragma unroll
      for (int n=0;n<2;++n) aoc[m][n] = (f32x4){0.f,0.f,0.f,0.f};
#pragma unroll
    for (int ks=0; ks<2; ++ks){
      const int kb = ks*64 + (q4<<4);
      short8 pa[3], vb[2];
#pragma unroll
      for (int m=0;m<3;++m){
        const int r = m*16 + cl;
        pa[m] = *(const short8*)((const char*)P + r*128 + (kb ^ ((r&7)<<4)));
      }
#pragma unroll
      for (int n=0;n<2;++n){
        vb[n] = zero8();
        if (ks == 0 || q4 < 2)
          vb[n] = *(const short8*)(vbb + (long)(h*32 + n*16 + cl)*48 + ks*32 + q4*8);
      }
#pragma unroll
      for (int m=0;m<3;++m)
#pragma unroll
        for (int n=0;n<2;++n)
          aoc[m][n] = __builtin_amdgcn_mfma_f32_16x16x32_bf16(pa[m], vb[n], aoc[m][n], 0,0,0);
    }
#pragma unroll
    for (int m=0;m<3;++m)
#pragma unroll
      for (int n=0;n<2;++n)
#pragma unroll
        for (int i=0;i<4;++i){
          const int row = m*16 + (q4<<2) + i;
          const int colq = h*32 + n*16 + cl;
          *(unsigned short*)((char*)Mo + row*512 + ((colq*2) ^ ((row&7)<<4))) = f2bf(aoc[m][n][i]);
        }
  }
  __syncthreads();
  f32x4 oc[3][4];
#pragma unroll
  for (int m=0;m<3;++m)
#pragma unroll
    for (int n=0;n<4;++n) oc[m][n] = (f32x4){0.f,0.f,0.f,0.f};
#pragma unroll
  for (int ks=0; ks<8; ++ks){
    const int kb = ks*64 + (q4<<4);
    short8 am[3], bm[4];
#pragma unroll
    for (int m=0;m<3;++m){
      const int r = m*16 + cl;
      am[m] = *(const short8*)((const char*)Mo + r*512 + (kb ^ ((r&7)<<4)));
    }
#pragma unroll
    for (int n=0;n<4;++n){
      const int nn = (w<<6) + n*16 + cl;
      bm[n] = *(const short8*)(moW + (long)nn*256 + ks*32 + q4*8);
    }
#pragma unroll
    for (int m=0;m<3;++m)
#pragma unroll
      for (int n=0;n<4;++n)
        oc[m][n] = __builtin_amdgcn_mfma_f32_16x16x32_bf16(am[m], bm[n], oc[m][n], 0,0,0);
  }
#pragma unroll
  for (int m=0;m<3;++m)
#pragma unroll
    for (int n=0;n<4;++n)
#pragma unroll
      for (int i=0;i<4;++i){
        const int row = m*16 + (q4<<2) + i;
        if (row < 39){
          const int col = (w<<6) + n*16 + cl;
          const float v = oc[m][n][i] + moB[col] + xf[(((long)(b*39+row))<<8) + col];
          flatb[(long)b*9984 + row*256 + col] = f2bf(v);
        }
      }
}

// ---------------------------------------------------------------------------
// Embedding + x0 bf16 + xln1 (normalized) write
// ---------------------------------------------------------------------------
__global__ __launch_bounds__(256)
void embed_k(const float* __restrict__ dense_x, const int* __restrict__ sparse_x,
             const float* __restrict__ W_dense, const float* __restrict__ b_dense,
             const float* __restrict__ emb,
             float* __restrict__ xf, unsigned short* __restrict__ x0b,
             unsigned short* __restrict__ xln1)
{
  const int bid = blockIdx.x;
  const int b = bid / 39, t = bid - b*39;
  const int c = threadIdx.x;
  float v;
  if (t < 13){
    const int j = t*256 + c;
    v = b_dense[j];
    const float* wr = W_dense + (long)j*13;
    const float* dx = dense_x + (long)b*13;
#pragma unroll
    for (int k2=0;k2<13;++k2) v = fmaf(dx[k2], wr[k2], v);
  } else {
    const int idx = sparse_x[b*26 + (t-13)];
    v = (idx == 0) ? 0.f : emb[((long)(t-13)*10001 + idx)*256 + c];
  }
  const long row = bid;
  xf[row*256 + c] = v;
  x0b[row*256 + c] = f2bf(v);
  float s1 = v, s2 = v*v;
#pragma unroll
  for (int off=32; off; off>>=1){ s1 += __shfl_xor(s1, off); s2 += __shfl_xor(s2, off); }
  __shared__ float r1[4], r2[4];
  const int lane = c & 63, wq = c >> 6;
  if (lane == 0){ r1[wq]=s1; r2[wq]=s2; }
  __syncthreads();
  const float S1 = r1[0]+r1[1]+r1[2]+r1[3];
  const float S2 = r2[0]+r2[1]+r2[2]+r2[3];
  const float mn = S1*(1.f/256.f);
  const float var = S2*(1.f/256.f) - mn*mn;
  const float s = rsqrtf(var+1e-5f);
  xln1[row*256 + c] = f2bf((v - mn)*s);
}

// ---------------------------------------------------------------------------
// AttentionResidual block mixing (+ xln1 write)
// ---------------------------------------------------------------------------
template<int NSRC>
__global__ __launch_bounds__(256)
void mix_k(float* __restrict__ xf,
           const unsigned short* __restrict__ s0,
           const unsigned short* __restrict__ s1p,
           const unsigned short* __restrict__ s2p,
           unsigned short* mout,
           const float* __restrict__ qvec, int qi,
           unsigned short* __restrict__ xln1)
{
  const int b = blockIdx.x;
  const int tid = threadIdx.x, lane = tid&63, w = tid>>6;
  const int c4 = lane << 2;
  f32x4 q = *(const f32x4*)(qvec + qi*256 + c4);
  float qq = q[0]*q[0]+q[1]*q[1]+q[2]*q[2]+q[3]*q[3];
#pragma unroll
  for (int off=32; off; off>>=1) qq += __shfl_xor(qq, off);
  const float qsc = 1.f/fmaxf(sqrtf(qq), 1e-12f);
#pragma unroll
  for (int e=0;e<4;++e) q[e] *= qsc;
  for (int t = w; t < 39; t += 4){
    const long ro = ((long)(b*39+t))*256 + c4;
    f32x4 v[NSRC];
#pragma unroll
    for (int n=0;n<NSRC;++n){
      if (n == NSRC-1) v[n] = *(const f32x4*)(xf + ro);
      else {
        const unsigned short* sp = (n==0)?s0:((n==1)?s1p:s2p);
        us4 u = *(const us4*)(sp + ro);
#pragma unroll
        for (int e=0;e<4;++e) v[n][e] = bf2f(u[e]);
      }
    }
    float lg[NSRC];
#pragma unroll
    for (int n=0;n<NSRC;++n){
      float nn = v[n][0]*v[n][0]+v[n][1]*v[n][1]+v[n][2]*v[n][2]+v[n][3]*v[n][3];
      float dd = q[0]*v[n][0]+q[1]*v[n][1]+q[2]*v[n][2]+q[3]*v[n][3];
#pragma unroll
      for (int off=32; off; off>>=1){ nn += __shfl_xor(nn,off); dd += __shfl_xor(dd,off); }
      lg[n] = dd / fmaxf(sqrtf(nn), 1e-12f);
    }
    float mx = lg[0];
#pragma unroll
    for (int n=1;n<NSRC;++n) mx = fmaxf(mx, lg[n]);
    float es = 0.f, e_[NSRC];
#pragma unroll
    for (int n=0;n<NSRC;++n){ e_[n] = __expf(lg[n]-mx); es += e_[n]; }
    const float inv = 1.f/es;
    f32x4 o = {0.f,0.f,0.f,0.f};
#pragma unroll
    for (int n=0;n<NSRC;++n){
      const float wt = e_[n]*inv;
#pragma unroll
      for (int e=0;e<4;++e) o[e] = fmaf(wt, v[n][e], o[e]);
    }
    *(f32x4*)(xf + ro) = o;
    if (mout){
      us4 u;
#pragma unroll
      for (int e=0;e<4;++e) u[e] = f2bf(o[e]);
      *(us4*)(mout + ro) = u;
    }
    float s1 = o[0]+o[1]+o[2]+o[3];
    float s2 = o[0]*o[0]+o[1]*o[1]+o[2]*o[2]+o[3]*o[3];
#pragma unroll
    for (int off=32; off; off>>=1){ s1 += __shfl_xor(s1,off); s2 += __shfl_xor(s2,off); }
    const float mn = s1*(1.f/256.f);
    const float var = s2*(1.f/256.f)-mn*mn;
    const float s = rsqrtf(var+1e-5f);
    const float c = -mn*s;
    us4 u2;
#pragma unroll
    for (int e=0;e<4;++e) u2[e] = f2bf(o[e]*s + c);
    *(us4*)(xln1 + ro) = u2;
  }
}

__global__ __launch_bounds__(256)
void head2_k(const unsigned short* __restrict__ h1h, const float* __restrict__ Wo2,
             const float* __restrict__ bo2, float* __restrict__ outp)
{
  const int b = blockIdx.x*4 + (threadIdx.x>>6);
  const int lane = threadIdx.x & 63;
  float s = 0.f;
#pragma unroll
  for (int g=0; g<2; ++g){
    const int base = lane*16 + g*8;
    short8 v8 = *(const short8*)(h1h + (long)b*1024 + base);
#pragma unroll
    for (int e=0;e<8;++e) s = fmaf(bf2f((unsigned short)v8[e]), Wo2[base+e], s);
  }
#pragma unroll
  for (int off=32; off; off>>=1) s += __shfl_xor(s, off);
  if (lane==0) outp[b] = s + bo2[0];
}

// ------------------------- weight prep kernels ------------------------------
__global__ void cvt_k(const float* __restrict__ src, unsigned short* __restrict__ dst, long n){
  const long i = (long)blockIdx.x*256 + threadIdx.x;
  if (i < n) dst[i] = f2bf(src[i]);
}
__global__ void prep_qkv_k(const float* Wq, const float* Wk, const float* Wv,
                           const float* g, unsigned short* dst){
  const int n = blockIdx.x, i = blockIdx.y, k = threadIdx.x;
  const int sel = n >> 8, nn = n & 255;
  const float* W = sel==0?Wq:(sel==1?Wk:Wv);
  dst[((long)i*768 + n)*256 + k] = f2bf(W[((long)i*256+nn)*256 + k] * g[i*256+k]);
}
__global__ void prep_qkvb_k(const float* Wq,const float* Wk,const float* Wv,
                            const float* bq,const float* bk,const float* bv,
                            const float* beta, float* dst){
  const int n = blockIdx.x, i = blockIdx.y, k = threadIdx.x;
  const int sel = n>>8, nn = n&255;
  const float* W = sel==0?Wq:(sel==1?Wk:Wv);
  const float* bb = sel==0?bq:(sel==1?bk:bv);
  float v = beta[i*256+k] * W[((long)i*256+nn)*256+k];
  __shared__ float r[4];
#pragma unroll
  for (int off=32; off; off>>=1) v += __shfl_xor(v, off);
  if ((k&63)==0) r[k>>6] = v;
  __syncthreads();
  if (k==0) dst[i*768+n] = bb[i*256+nn] + r[0]+r[1]+r[2]+r[3];
}
__global__ void prep_w1_k(const float* W1, const float* g, unsigned short* dst){
  const int n = blockIdx.x, i = blockIdx.y, k = threadIdx.x;
  const long o = ((long)i*1024+n)*256 + k;
  dst[o] = f2bf(W1[o] * g[i*256+k]);
}
__global__ void prep_w1b_k(const float* W1, const float* b1, const float* beta, float* dst){
  const int n = blockIdx.x, i = blockIdx.y, k = threadIdx.x;
  float v = beta[i*256+k] * W1[((long)i*1024+n)*256+k];
  __shared__ float r[4];
#pragma unroll
  for (int off=32; off; off>>=1) v += __shfl_xor(v, off);
  if ((k&63)==0) r[k>>6] = v;
  __syncthreads();
  if (k==0) dst[i*1024+n] = b1[i*1024+n] + r[0]+r[1]+r[2]+r[3];
}
__global__ void prep_mha_k(const float* W, const float* g, unsigned short* dst){
  const int n = blockIdx.x, k = threadIdx.x;
  dst[n*256+k] = f2bf(W[n*256+k]*g[k]);
}
__global__ void prep_mhab_k(const float* W, const float* bb, const float* beta, float* dst){
  const int n = blockIdx.x, k = threadIdx.x;
  float v = beta[k]*W[n*256+k];
  __shared__ float r[4];
#pragma unroll
  for (int off=32; off; off>>=1) v += __shfl_xor(v, off);
  if ((k&63)==0) r[k>>6] = v;
  __syncthreads();
  if (k==0) dst[n] = bb[n] + r[0]+r[1]+r[2]+r[3];
}

// ---------------------------------------------------------------------------
extern "C" void kernel_launch(void* const* d_in, const int* in_sizes, int n_in,
                              void* d_out, int out_size, void* d_ws, size_t ws_size,
                              hipStream_t stream)
{
  (void)in_sizes; (void)n_in; (void)out_size; (void)ws_size;
  const float* dense_x  = (const float*)d_in[0];
  const int*   sparse_x = (const int*)d_in[1];
  const float* W_dense  = (const float*)d_in[2];
  const float* b_dense  = (const float*)d_in[3];
  const float* emb      = (const float*)d_in[4];
  const float* Wq = (const float*)d_in[5];
  const float* bq = (const float*)d_in[6];
  const float* Wk = (const float*)d_in[7];
  const float* bk = (const float*)d_in[8];
  const float* Wv = (const float*)d_in[9];
  const float* bv = (const float*)d_in[10];
  const float* W1 = (const float*)d_in[11];
  const float* b1 = (const float*)d_in[12];
  const float* W2 = (const float*)d_in[13];
  const float* b2 = (const float*)d_in[14];
  const float* n1g= (const float*)d_in[15];
  const float* n1b= (const float*)d_in[16];
  const float* n2g= (const float*)d_in[17];
  const float* n2b= (const float*)d_in[18];
  const float* qvec=(const float*)d_in[19];
  const float* mha_in_w = (const float*)d_in[20];
  const float* mha_in_b = (const float*)d_in[21];
  const float* mha_out_w= (const float*)d_in[22];
  const float* mha_out_b= (const float*)d_in[23];
  const float* ng = (const float*)d_in[24];
  const float* ngb= (const float*)d_in[25];
  const float* Wo1= (const float*)d_in[26];
  const float* bo1= (const float*)d_in[27];
  const float* Wo2= (const float*)d_in[28];
  const float* bo2= (const float*)d_in[29];

  char* ws = (char*)d_ws;
  size_t off = 0;
  auto alloc = [&](size_t bytes)->void*{ void* p = ws + off; off += (bytes + 255) & ~(size_t)255; return p; };
  float* xf            = (float*)alloc(163577856ull);           // [159744][256] f32
  unsigned short* qkh  = (unsigned short*)alloc(163577856ull);  // [159744][512] bf16 (Q|K)
  unsigned short* vT   = (unsigned short*)alloc(100663296ull);  // [4096][256][48] bf16
  unsigned short* x0b  = (unsigned short*)alloc(81788928ull);
  unsigned short* m1b  = (unsigned short*)alloc(81788928ull);   // aliased as flatb at end
  unsigned short* m2b  = (unsigned short*)alloc(81788928ull);
  unsigned short* xln1 = (unsigned short*)alloc(81788928ull);
  unsigned short* h1h  = (unsigned short*)alloc(8388608ull);    // [4096][1024] bf16
  float* sB = (float*)alloc(638976ull);
  float* cB = (float*)alloc(638976ull);
  unsigned short* Wqkv_f = (unsigned short*)alloc(3145728ull);
  float* bqkv_f = (float*)alloc(24576ull);
  unsigned short* W1_f = (unsigned short*)alloc(4194304ull);
  float* b1_f = (float*)alloc(32768ull);
  unsigned short* W2_f = (unsigned short*)alloc(4194304ull);
  unsigned short* mhain_f = (unsigned short*)alloc(393216ull);
  float* mhainb_f = (float*)alloc(3072ull);
  unsigned short* mhaout_f = (unsigned short*)alloc(131072ull);
  unsigned short* Wo1_f = (unsigned short*)alloc(20447232ull);

  unsigned short* flatb = m1b;   // m1b dead after layer-5 mix

  // weight prep
  cvt_k<<<8192,256,0,stream>>>(W2, W2_f, 2097152L);
  cvt_k<<<256,256,0,stream>>>(mha_out_w, mhaout_f, 65536L);
  cvt_k<<<39936,256,0,stream>>>(Wo1, Wo1_f, 10223616L);
  prep_qkv_k<<<dim3(768,8),256,0,stream>>>(Wq,Wk,Wv,n1g,Wqkv_f);
  prep_qkvb_k<<<dim3(768,8),256,0,stream>>>(Wq,Wk,Wv,bq,bk,bv,n1b,bqkv_f);
  prep_w1_k<<<dim3(1024,8),256,0,stream>>>(W1,n2g,W1_f);
  prep_w1b_k<<<dim3(1024,8),256,0,stream>>>(W1,b1,n2b,b1_f);
  prep_mha_k<<<768,256,0,stream>>>(mha_in_w, ng, mhain_f);
  prep_mhab_k<<<768,256,0,stream>>>(mha_in_w, mha_in_b, ngb, mhainb_f);

  embed_k<<<159744,256,0,stream>>>(dense_x, sparse_x, W_dense, b_dense, emb, xf, x0b, xln1);

  for (int i = 0; i < 8; ++i){
    qkv_k<<<1248,256,0,stream>>>(xln1, Wqkv_f + (size_t)i*196608, bqkv_f + i*768, qkh, vT);
    attn_sig_k<<<4096,256,0,stream>>>(qkh, vT, xf, sB, cB);
    const int wx = (i==1 || i==3 || i==5) ? 0 : 1;
    ffn_k<<<2496,256,0,stream>>>(xf, sB, cB,
        W1_f + (size_t)i*262144, b1_f + i*1024,
        W2_f + (size_t)i*262144, b2 + i*256, xf, xln1, wx);
    if (i == 1)      mix_k<2><<<4096,256,0,stream>>>(xf, x0b, m1b, m2b, m1b, qvec, 1, xln1);
    else if (i == 3) mix_k<3><<<4096,256,0,stream>>>(xf, x0b, m1b, m2b, m2b, qvec, 2, xln1);
    else if (i == 5) mix_k<4><<<4096,256,0,stream>>>(xf, x0b, m1b, m2b, nullptr, qvec, 3, xln1);
  }
  qkv_k<<<1248,256,0,stream>>>(xln1, mhain_f, mhainb_f, qkh, vT);
  attn_fin_k<<<4096,256,0,stream>>>(qkh, vT, xf, mhaout_f, mha_out_b, flatb);
  gemm_k<<<256,256,0,stream>>>(flatb, 9984, Wo1_f, bo1, h1h, 1024, 9984, 8);
  head2_k<<<1024,256,0,stream>>>(h1h, Wo2, bo2, (float*)d_out);
}

// Round 14
// 6650.424 us; speedup vs baseline: 1.4216x; 1.0103x over previous
//
#include <hip/hip_runtime.h>
#include <hip/hip_bf16.h>

typedef __attribute__((ext_vector_type(4))) float f32x4;
typedef __attribute__((ext_vector_type(8))) short short8;
typedef __attribute__((ext_vector_type(4))) unsigned short us4;

static __device__ __forceinline__ unsigned short f2bf(float f){
  return __builtin_bit_cast(unsigned short, __float2bfloat16(f));
}
static __device__ __forceinline__ float bf2f(unsigned short u){
  return __bfloat162float(__builtin_bit_cast(__hip_bfloat16, u));
}
static __device__ __forceinline__ short8 zero8(){
  short8 v;
#pragma unroll
  for (int e=0;e<8;++e) v[e]=0;
  return v;
}
// async global->LDS, 16B/lane; lds dest wave-uniform base + lane*16
static __device__ __forceinline__ void g2l16(const void* g, void* l){
  __builtin_amdgcn_global_load_lds(
    (const __attribute__((address_space(1))) unsigned int*)g,
    (__attribute__((address_space(3))) unsigned int*)l, 16, 0, 0);
}

// ---------------------------------------------------------------------------
// QKV GEMM: out[row][0..767] = xln1[row][:] @ Wqkv^T + bias. 128 rows/block.
// A staged ONCE in 64KB swizzled LDS; B fragments direct from L2 (393KB).
// ---------------------------------------------------------------------------
__global__ __launch_bounds__(256)
void qkv_k(const unsigned short* __restrict__ Ap,   // xln1 [..][256]
           const unsigned short* __restrict__ Bp,   // Wqkv [768][256]
           const float* __restrict__ bias,          // [768]
           unsigned short* __restrict__ qk,         // [..][512]
           unsigned short* __restrict__ vT)         // [4096][256][48]
{
  __shared__ __align__(16) unsigned short As[128*256];  // 4 k-tiles [128][64] swizzled

  const int tid = threadIdx.x, lane = tid & 63, w = tid >> 6;
  const int cl = lane & 15, q4 = lane >> 4;
  const long rowBase = (long)blockIdx.x << 7;
  const int wm = (w >> 1) << 6, wn = (w & 1) << 6;

  // stage A: 4096 chunks of 16B; chunk c = kt*1024 + r*8 + x holds global x^(r&7)
#pragma unroll
  for (int it=0; it<16; ++it){
    const int c = (it<<8) + (w<<6) + lane;
    const int kt = c>>10, rem = c & 1023, r = rem>>3, x = rem&7;
    g2l16(Ap + (rowBase + r)*256 + (kt<<6) + (((x ^ (r&7)))<<3),
          As + (((it<<8) + (w<<6))<<3));
  }
  __syncthreads();

  for (int cb=0; cb<6; ++cb){
    f32x4 acc[4][4];
#pragma unroll
    for (int m=0;m<4;++m)
#pragma unroll
      for (int n=0;n<4;++n) acc[m][n] = (f32x4){0.f,0.f,0.f,0.f};
#pragma unroll
    for (int kt=0; kt<4; ++kt)
#pragma unroll
      for (int ks=0; ks<2; ++ks){
        const int kb = ks*64 + (q4<<4);
        short8 af[4], bf_[4];
#pragma unroll
        for (int m=0;m<4;++m){
          const int r = wm + m*16 + cl;
          af[m] = *(const short8*)((const char*)As + (kt<<14) + r*128 + (kb ^ ((r&7)<<4)));
        }
#pragma unroll
        for (int n=0;n<4;++n){
          const long rn = cb*128 + wn + n*16 + cl;
          bf_[n] = *(const short8*)(Bp + rn*256 + (kt<<6) + ks*32 + (q4<<3));
        }
#pragma unroll
        for (int m=0;m<4;++m)
#pragma unroll
          for (int n=0;n<4;++n)
            acc[m][n] = __builtin_amdgcn_mfma_f32_16x16x32_bf16(af[m], bf_[n], acc[m][n], 0,0,0);
      }
    // epilogue for this col-block
#pragma unroll
    for (int n=0;n<4;++n){
      const int col = cb*128 + wn + n*16 + cl;
      const float bi = bias[col];
#pragma unroll
      for (int m=0;m<4;++m){
        const long r0 = rowBase + wm + m*16 + (q4<<2);
#pragma unroll
        for (int i=0;i<4;++i){
          const float v = acc[m][n][i] + bi;
          const long row = r0 + i;
          if (col < 512){
            qk[row*512 + col] = f2bf(v);
          } else {
            const int bb = (int)row / 39;
            const int tt = (int)row - bb*39;
            unsigned short* vrow = vT + ((long)bb*256 + (col - 512))*48;
            vrow[tt] = f2bf(v);
            if (tt < 9) vrow[tt + 39] = 0;   // zero pad (tokens 39..47)
          }
        }
      }
    }
  }
}

// ---------------------------------------------------------------------------
// Head GEMM split-K: partial[ks][4096][1024] f32 over K-slice of 2496.
// grid = 4 kslices x 32 rowPanels x 8 colPanels = 1024 blocks (4/CU) -> the
// 2-barrier staging loop overlaps across co-resident blocks (R13: 256 blocks
// = 1/CU was the serialized m97 structure).
// ---------------------------------------------------------------------------
__global__ __launch_bounds__(256)
void hgemm_k(const unsigned short* __restrict__ Ap,   // flatb [4096][9984]
             const unsigned short* __restrict__ Bp,   // Wo1_f [1024][9984]
             float* __restrict__ part)                // [4][4096][1024] f32
{
  const int t0 = blockIdx.x;
  const int kslice = t0 >> 8, rem = t0 & 255, cb = rem & 7, rb = rem >> 3;
  const long rowBase = (long)rb << 7;
  const long colBase = (long)cb << 7;
  const int kBase = kslice * 2496;
  const int tid = threadIdx.x, lane = tid & 63, w = tid >> 6;
  const int wm = (w >> 1) << 6, wn = (w & 1) << 6;
  const int cl = lane & 15, q4 = lane >> 4;

  __shared__ __align__(16) unsigned short As[128*64];
  __shared__ __align__(16) unsigned short Bs[128*64];

  const char* bSrc[4]; unsigned short* bDst[4];
  const char* aSrc[4]; unsigned short* aDst[4];
#pragma unroll
  for (int g=0; g<4; ++g){
    const int c = (w<<8) + (g<<6) + lane;
    const int r = c>>3, x = c&7, c16 = x ^ (r&7);
    bSrc[g] = (const char*)(Bp + (colBase + r)*9984L + kBase) + c16*16;
    bDst[g] = Bs + (((w<<2)+g)<<9);
    aSrc[g] = (const char*)(Ap + (rowBase + r)*9984L + kBase) + c16*16;
    aDst[g] = As + (((w<<2)+g)<<9);
  }

  f32x4 acc[4][4];
#pragma unroll
  for (int m=0;m<4;++m)
#pragma unroll
    for (int n=0;n<4;++n) acc[m][n] = (f32x4){0.f,0.f,0.f,0.f};

  const int nk = 39;   // 2496 / 64
  for (int t=0; t<nk; ++t){
    if (t) __syncthreads();
    const long tb = (long)t << 7;
#pragma unroll
    for (int g=0; g<4; ++g){
      g2l16(bSrc[g] + tb, bDst[g]);
      g2l16(aSrc[g] + tb, aDst[g]);
    }
    __syncthreads();
#pragma unroll
    for (int ks=0; ks<2; ++ks){
      const int kb = ks*64 + (q4<<4);
      short8 af[4], bf_[4];
#pragma unroll
      for (int m=0;m<4;++m){
        const int r = wm + m*16 + cl;
        af[m] = *(const short8*)((const char*)As + r*128 + (kb ^ ((r&7)<<4)));
      }
#pragma unroll
      for (int n=0;n<4;++n){
        const int r = wn + n*16 + cl;
        bf_[n] = *(const short8*)((const char*)Bs + r*128 + (kb ^ ((r&7)<<4)));
      }
#pragma unroll
      for (int m=0;m<4;++m)
#pragma unroll
        for (int n=0;n<4;++n)
          acc[m][n] = __builtin_amdgcn_mfma_f32_16x16x32_bf16(af[m], bf_[n], acc[m][n], 0,0,0);
    }
  }

#pragma unroll
  for (int n=0;n<4;++n){
    const long col = colBase + wn + n*16 + cl;
#pragma unroll
    for (int m=0;m<4;++m){
      const long r0 = rowBase + wm + m*16 + (q4<<2);
#pragma unroll
      for (int i=0;i<4;++i)
        part[((long)kslice*4096 + r0 + i)*1024 + col] = acc[m][n][i];
    }
  }
}

// reduce 4 K-slices + bias -> relu -> bf16 h1h. 4096 blocks x 256 thr x 4 elems.
__global__ __launch_bounds__(256)
void hred_k(const float* __restrict__ part, const float* __restrict__ bo1,
            unsigned short* __restrict__ h1h)
{
  const long i4 = (((long)blockIdx.x << 8) + threadIdx.x) << 2;
  const int col = (int)(i4 & 1023);
  f32x4 s0 = *(const f32x4*)(part + i4);
  f32x4 s1 = *(const f32x4*)(part + 4194304L + i4);
  f32x4 s2 = *(const f32x4*)(part + 8388608L + i4);
  f32x4 s3 = *(const f32x4*)(part + 12582912L + i4);
  us4 u;
#pragma unroll
  for (int e=0;e<4;++e){
    const float v = s0[e] + s1[e] + s2[e] + s3[e] + bo1[col + e];
    u[e] = f2bf(fmaxf(v, 0.f));
  }
  *(us4*)(h1h + i4) = u;
}

// ---------------------------------------------------------------------------
// Fused FFN (R10 v6, best measured: 305us): 64 rows/block, 256 threads,
// LDS = W1c(32K)+W2c(32K)+Hs(8K) = 72KB -> 2 blocks/CU; regs 112+64=176
// under the (256,2) cap of 256 -> no spill, co-resident staging overlap.
// At its L2-BW roofline: 2496 blocks x 4MB weights = 10GB @ ~33 TB/s.
// ---------------------------------------------------------------------------
__global__ __launch_bounds__(256, 2)
void ffn_k(const float* __restrict__ xf_in,
           const float* __restrict__ sB, const float* __restrict__ cB,
           const unsigned short* __restrict__ W1p,  // [1024][256]
           const float* __restrict__ b1p,           // [1024]
           const unsigned short* __restrict__ W2p,  // [256][1024]
           const float* __restrict__ b2p,           // [256]
           float* __restrict__ xf,
           unsigned short* __restrict__ xln1, int writeXln)
{
  __shared__ __align__(16) unsigned short Wb1[64*256];  // 32KB, 4 k-tiles [64][64]
  __shared__ __align__(16) unsigned short Wb2[256*64];  // 32KB, [256][64] swizzled
  __shared__ __align__(16) unsigned short Hs[64*64];    // 8KB
  // epilogue scratch aliased onto Wb1 (dead after last H phase)
  float* part1 = (float*)Wb1;          // 256 f
  float* part2 = part1 + 256;          // 256 f
  float* sln   = part2 + 256;          // 64 f
  float* cln   = sln + 64;             // 64 f

  const int tid = threadIdx.x, lane = tid & 63, w = tid >> 6;
  const int cl = lane & 15, q4 = lane >> 4;
  const long rowBase = (long)blockIdx.x << 6;   // 64 rows/block

  // ---- A = LN2(x) in registers, MFMA fragment layout ----
  short8 af[8];
  {
    const int row = (w<<4) + cl;
    const float s = sB[rowBase + row], c = cB[rowBase + row];
    const float* src = xf_in + (rowBase + row)*256 + (q4<<3);
#pragma unroll
    for (int kt=0; kt<8; ++kt){
      f32x4 a = *(const f32x4*)(src + kt*32);
      f32x4 b = *(const f32x4*)(src + kt*32 + 4);
      short8 v;
#pragma unroll
      for (int e=0;e<4;++e){ v[e] = (short)f2bf(a[e]*s + c); v[4+e] = (short)f2bf(b[e]*s + c); }
      af[kt] = v;
    }
  }

  // acc: wave w -> rows 0..63 (m), cols [64w, 64w+64) (n)
  f32x4 acc[4][4];
#pragma unroll
  for (int m=0;m<4;++m)
#pragma unroll
    for (int n=0;n<4;++n) acc[m][n] = (f32x4){0.f,0.f,0.f,0.f};

  for (int j=0; j<16; ++j){
    const int ffbase = j<<6;
    __syncthreads();   // prev chunk's W/Hs readers done
    // stage W1c [64 ff][256 k] (2048x16B) + W2c [256 out][64 ff] (2048x16B)
#pragma unroll
    for (int it=0; it<8; ++it){
      const int c = (it<<8) + tid;
      { // W1: 4 k-tiles of [64][64]; chunk c = kt*512 + rr*8 + xs
        const int kt = c>>9, cc = c&511, rr = cc>>3, xs = cc&7;
        g2l16(W1p + ((long)(ffbase+rr))*256 + (kt<<6) + ((xs^(rr&7))<<3),
              Wb1 + (((it<<8) + (w<<6))<<3));
      }
      { // W2: rows = out cols (256), 64-ff slice; chunk c = rr*8 + xs
        const int rr = c>>3, xs = c&7;
        g2l16(W2p + (long)rr*1024 + ffbase + ((xs^(rr&7))<<3),
              Wb2 + (((it<<8) + (w<<6))<<3));
      }
    }
    float b1v[4];
#pragma unroll
    for (int n=0;n<4;++n) b1v[n] = b1p[ffbase + n*16 + cl];
    __syncthreads();   // staged (vmcnt drained by barrier)

    // H = A @ W1c^T : wave w -> rows [16w,16w+16) x 64 ff cols, A from regs
    f32x4 hacc[4];
#pragma unroll
    for (int n=0;n<4;++n) hacc[n] = (f32x4){0.f,0.f,0.f,0.f};
#pragma unroll
    for (int kt2=0; kt2<4; ++kt2)
#pragma unroll
      for (int ks=0; ks<2; ++ks){
        const int kb = ks*64 + (q4<<4);
        const short8 a = af[kt2*2 + ks];
#pragma unroll
        for (int n=0;n<4;++n){
          const int rn = n*16 + cl;
          short8 bf_ = *(const short8*)((const char*)Wb1 + (kt2<<13) + rn*128 + (kb ^ ((rn&7)<<4)));
          hacc[n] = __builtin_amdgcn_mfma_f32_16x16x32_bf16(a, bf_, hacc[n], 0,0,0);
        }
      }
#pragma unroll
    for (int n=0;n<4;++n)
#pragma unroll
      for (int i=0;i<4;++i){
        const int hr = (w<<4) + (q4<<2) + i, hc = n*16 + cl;
        const float hv = fmaxf(hacc[n][i] + b1v[n], 0.f);
        *(unsigned short*)((char*)Hs + hr*128 + ((hc*2) ^ ((hr&7)<<4))) = f2bf(hv);
      }
    __syncthreads();   // Hs visible

    // OUT += Hs @ W2c^T : wave w -> cols [64w,64w+64); both from LDS
#pragma unroll
    for (int ks=0; ks<2; ++ks){
      const int kb = ks*64 + (q4<<4);
      short8 am[4], bm[4];
#pragma unroll
      for (int m=0;m<4;++m){
        const int r = m*16 + cl;
        am[m] = *(const short8*)((const char*)Hs + r*128 + (kb ^ ((r&7)<<4)));
      }
#pragma unroll
      for (int n=0;n<4;++n){
        const int r = (w<<6) + n*16 + cl;
        bm[n] = *(const short8*)((const char*)Wb2 + r*128 + (kb ^ ((r&7)<<4)));
      }
#pragma unroll
      for (int m=0;m<4;++m)
#pragma unroll
        for (int n=0;n<4;++n)
          acc[m][n] = __builtin_amdgcn_mfma_f32_16x16x32_bf16(am[m], bm[n], acc[m][n], 0,0,0);
    }
  }

  // ---- epilogue: residual, xf write, LN1 stats, xln1 write ----
#pragma unroll
  for (int n=0;n<4;++n){
    const int col = (w<<6) + n*16 + cl;
    const float bi = b2p[col];
#pragma unroll
    for (int m=0;m<4;++m)
#pragma unroll
      for (int i=0;i<4;++i){
        const int row = m*16 + (q4<<2) + i;
        const long gi = (rowBase + row)*256 + col;
        const float v = acc[m][n][i] + bi + xf[gi];
        acc[m][n][i] = v;
        xf[gi] = v;
      }
  }
  __syncthreads();   // Wb1/Wb2/Hs fully dead before aliasing scratch
#pragma unroll
  for (int m=0;m<4;++m)
#pragma unroll
    for (int i=0;i<4;++i){
      float s1 = 0.f, s2 = 0.f;
#pragma unroll
      for (int n=0;n<4;++n){ const float v = acc[m][n][i]; s1 += v; s2 += v*v; }
#pragma unroll
      for (int off=8; off; off>>=1){ s1 += __shfl_xor(s1, off, 16); s2 += __shfl_xor(s2, off, 16); }
      const int row = m*16 + (q4<<2) + i;
      if (cl == 0){ part1[row*4 + w] = s1; part2[row*4 + w] = s2; }
    }
  __syncthreads();
  if (tid < 64){
    const float S1 = part1[tid*4]+part1[tid*4+1]+part1[tid*4+2]+part1[tid*4+3];
    const float S2 = part2[tid*4]+part2[tid*4+1]+part2[tid*4+2]+part2[tid*4+3];
    const float mn = S1*(1.f/256.f);
    const float var = S2*(1.f/256.f) - mn*mn;
    const float s = rsqrtf(var + 1e-5f);
    sln[tid] = s; cln[tid] = -mn*s;
  }
  __syncthreads();
  if (writeXln){
#pragma unroll
    for (int m=0;m<4;++m)
#pragma unroll
      for (int i=0;i<4;++i){
        const int row = m*16 + (q4<<2) + i;
        const float s = sln[row], c = cln[row];
#pragma unroll
        for (int n=0;n<4;++n){
          const int col = (w<<6) + n*16 + cl;
          xln1[(rowBase + row)*256 + col] = f2bf(acc[m][n][i]*s + c);
        }
      }
  }
}

// ---------------------------------------------------------------------------
// Sigmoid (HSTU) attention. One block = one batch item, 2 heads/wave.
// ---------------------------------------------------------------------------
__global__ __launch_bounds__(256)
void attn_sig_k(const unsigned short* __restrict__ qkb,
                const unsigned short* __restrict__ vT,
                float* xf, float* __restrict__ sB, float* __restrict__ cB)
{
  __shared__ __align__(16) unsigned short Ps[4*48*64];
  __shared__ float part[312];

  const int b = blockIdx.x;
  const int tid = threadIdx.x, lane = tid & 63, w = tid >> 6;
  const int cl = lane & 15, q4 = lane >> 4;
  unsigned short* P = Ps + w*3072;
  const unsigned short* qb = qkb + (long)b*39*512;
  const unsigned short* vbb = vT + (long)b*256*48;

  if (lane < 48){
    const int r = lane;
    *(short8*)((char*)P + r*128 + (96  ^ ((r&7)<<4))) = zero8();
    *(short8*)((char*)P + r*128 + (112 ^ ((r&7)<<4))) = zero8();
  }

  float ps1[3][4], ps2[3][4];
#pragma unroll
  for (int m=0;m<3;++m)
#pragma unroll
    for (int i=0;i<4;++i){ ps1[m][i]=0.f; ps2[m][i]=0.f; }

#pragma unroll
  for (int hh=0; hh<2; ++hh){
    const int h = (w<<1) + hh;
    f32x4 sac[3][3];
#pragma unroll
    for (int m=0;m<3;++m)
#pragma unroll
      for (int n=0;n<3;++n) sac[m][n] = (f32x4){0.f,0.f,0.f,0.f};
    short8 aq[3], bk8[3];
#pragma unroll
    for (int m=0;m<3;++m){
      const int r = m*16 + cl;
      aq[m] = (r < 39) ? *(const short8*)(qb + (long)r*512 + h*32 + q4*8) : zero8();
    }
#pragma unroll
    for (int n=0;n<3;++n){
      const int r = n*16 + cl;
      bk8[n] = (r < 39) ? *(const short8*)(qb + (long)r*512 + 256 + h*32 + q4*8) : zero8();
    }
#pragma unroll
    for (int m=0;m<3;++m)
#pragma unroll
      for (int n=0;n<3;++n)
        sac[m][n] = __builtin_amdgcn_mfma_f32_16x16x32_bf16(aq[m], bk8[n], sac[m][n], 0,0,0);
#pragma unroll
    for (int m=0;m<3;++m)
#pragma unroll
      for (int n=0;n<3;++n)
#pragma unroll
        for (int i=0;i<4;++i){
          const int row = m*16 + (q4<<2) + i, col = n*16 + cl;
          const float pv = 1.f/(1.f + __expf(-sac[m][n][i]*0.0625f));
          *(unsigned short*)((char*)P + row*128 + ((col*2) ^ ((row&7)<<4))) = f2bf(pv);
        }
    f32x4 aoc[3][2];
#pragma unroll
    for (int m=0;m<3;++m)
#pragma unroll
      for (int n=0;n<2;++n) aoc[m][n] = (f32x4){0.f,0.f,0.f,0.f};
#pragma unroll
    for (int ks=0; ks<2; ++ks){
      const int kb = ks*64 + (q4<<4);
      short8 pa[3], vb[2];
#pragma unroll
      for (int m=0;m<3;++m){
        const int r = m*16 + cl;
        pa[m] = *(const short8*)((const char*)P + r*128 + (kb ^ ((r&7)<<4)));
      }
#pragma unroll
      for (int n=0;n<2;++n){
        vb[n] = zero8();
        if (ks == 0 || q4 < 2)
          vb[n] = *(const short8*)(vbb + (long)(h*32 + n*16 + cl)*48 + ks*32 + q4*8);
      }
#pragma unroll
      for (int m=0;m<3;++m)
#pragma unroll
        for (int n=0;n<2;++n)
          aoc[m][n] = __builtin_amdgcn_mfma_f32_16x16x32_bf16(pa[m], vb[n], aoc[m][n], 0,0,0);
    }
#pragma unroll
    for (int m=0;m<3;++m)
#pragma unroll
      for (int n=0;n<2;++n)
#pragma unroll
        for (int i=0;i<4;++i){
          const int row = m*16 + (q4<<2) + i;
          if (row < 39){
            const long gi = (((long)(b*39+row))<<8) + h*32 + n*16 + cl;
            const float nv = xf[gi] + aoc[m][n][i];
            xf[gi] = nv;
            ps1[m][i] += nv; ps2[m][i] += nv*nv;
          }
        }
  }
#pragma unroll
  for (int m=0;m<3;++m)
#pragma unroll
    for (int i=0;i<4;++i){
      float a1 = ps1[m][i], a2 = ps2[m][i];
#pragma unroll
      for (int off=8; off; off>>=1){ a1 += __shfl_xor(a1, off, 16); a2 += __shfl_xor(a2, off, 16); }
      const int row = m*16 + (q4<<2) + i;
      if (cl == 0 && row < 39){ part[row*8 + (w<<1)] = a1; part[row*8 + (w<<1) + 1] = a2; }
    }
  __syncthreads();
  if (tid < 39){
    const float S1 = part[tid*8]+part[tid*8+2]+part[tid*8+4]+part[tid*8+6];
    const float S2 = part[tid*8+1]+part[tid*8+3]+part[tid*8+5]+part[tid*8+7];
    const float mn = S1*(1.f/256.f);
    const float var = S2*(1.f/256.f) - mn*mn;
    const float s = rsqrtf(var + 1e-5f);
    sB[b*39+tid] = s; cB[b*39+tid] = -mn*s;
  }
}

// ---------------------------------------------------------------------------
// Final softmax MHA + out-proj + residual -> flat bf16 [B][9984]
// ---------------------------------------------------------------------------
__global__ __launch_bounds__(256)
void attn_fin_k(const unsigned short* __restrict__ qkb,
                const unsigned short* __restrict__ vT,
                const float* __restrict__ xf,
                const unsigned short* __restrict__ moW,
                const float* __restrict__ moB,
                unsigned short* __restrict__ flatb)
{
  __shared__ __align__(16) unsigned short Ps[4*48*64];
  __shared__ __align__(16) unsigned short Mo[48*256];

  const int b = blockIdx.x;
  const int tid = threadIdx.x, lane = tid & 63, w = tid >> 6;
  const int cl = lane & 15, q4 = lane >> 4;
  unsigned short* P = Ps + w*3072;
  const unsigned short* qb = qkb + (long)b*39*512;
  const unsigned short* vbb = vT + (long)b*256*48;
  const float SC = 0.17677669529663687f;

  if (lane < 48){
    const int r = lane;
    *(short8*)((char*)P + r*128 + (96  ^ ((r&7)<<4))) = zero8();
    *(short8*)((char*)P + r*128 + (112 ^ ((r&7)<<4))) = zero8();
  }

#pragma unroll
  for (int hh=0; hh<2; ++hh){
    const int h = (w<<1) + hh;
    f32x4 sac[3][3];
#pragma unroll
    for (int m=0;m<3;++m)
#pragma unroll
      for (int n=0;n<3;++n) sac[m][n] = (f32x4){0.f,0.f,0.f,0.f};
    short8 aq[3], bk8[3];
#pragma unroll
    for (int m=0;m<3;++m){
      const int r = m*16 + cl;
      aq[m] = (r < 39) ? *(const short8*)(qb + (long)r*512 + h*32 + q4*8) : zero8();
    }
#pragma unroll
    for (int n=0;n<3;++n){
      const int r = n*16 + cl;
      bk8[n] = (r < 39) ? *(const short8*)(qb + (long)r*512 + 256 + h*32 + q4*8) : zero8();
    }
#pragma unroll
    for (int m=0;m<3;++m)
#pragma unroll
      for (int n=0;n<3;++n)
        sac[m][n] = __builtin_amdgcn_mfma_f32_16x16x32_bf16(aq[m], bk8[n], sac[m][n], 0,0,0);
#pragma unroll
    for (int m=0;m<3;++m)
#pragma unroll
      for (int i=0;i<4;++i){
        const float v0 = sac[m][0][i]*SC, v1 = sac[m][1][i]*SC, v2 = sac[m][2][i]*SC;
        const bool c2ok = (32 + cl) < 39;
        float mx = fmaxf(v0, v1);
        if (c2ok) mx = fmaxf(mx, v2);
#pragma unroll
        for (int off=8; off; off>>=1) mx = fmaxf(mx, __shfl_xor(mx, off, 16));
        const float e0 = __expf(v0-mx), e1 = __expf(v1-mx);
        const float e2 = c2ok ? __expf(v2-mx) : 0.f;
        float s = e0+e1+e2;
#pragma unroll
        for (int off=8; off; off>>=1) s += __shfl_xor(s, off, 16);
        const float inv = 1.f/s;
        const int row = m*16 + (q4<<2) + i;
        *(unsigned short*)((char*)P + row*128 + (((cl   )*2) ^ ((row&7)<<4))) = f2bf(e0*inv);
        *(unsigned short*)((char*)P + row*128 + (((16+cl)*2) ^ ((row&7)<<4))) = f2bf(e1*inv);
        *(unsigned short*)((char*)P + row*128 + (((32+cl)*2) ^ ((row&7)<<4))) = f2bf(e2*inv);
      }
    f32x4 aoc[3][2];
#pragma unroll
    for (int m=0;m<3;++m)
#pragma unroll
      for (int n=0;n<2;++n) aoc[m][n] = (f32x4){0.f,0.f,0.f,0.f};
#pragma unroll
    for (int ks=0; ks<2; ++ks){
      const int kb = ks*64 + (q4<<4);
      short8 pa[3], vb[2];
#pragma unroll
      for (int m=0;m<3;++m){
        const int r = m*16 + cl;
        pa[m] = *(const short8*)((const char*)P + r*128 + (kb ^ ((r&7)<<4)));
      }
#pragma unroll
      for (int n=0;n<2;++n){
        vb[n] = zero8();
        if (ks == 0 || q4 < 2)
          vb[n] = *(const short8*)(vbb + (long)(h*32 + n*16 + cl)*48 + ks*32 + q4*8);
      }
#pragma unroll
      for (int m=0;m<3;++m)
#pragma unroll
        for (int n=0;n<2;++n)
          aoc[m][n] = __builtin_amdgcn_mfma_f32_16x16x32_bf16(pa[m], vb[n], aoc[m][n], 0,0,0);
    }
#pragma unroll
    for (int m=0;m<3;++m)
#pragma unroll
      for (int n=0;n<2;++n)
#pragma unroll
        for (int i=0;i<4;++i){
          const int row = m*16 + (q4<<2) + i;
          const int colq = h*32 + n*16 + cl;
          *(unsigned short*)((char*)Mo + row*512 + ((colq*2) ^ ((row&7)<<4))) = f2bf(aoc[m][n][i]);
        }
  }
  __syncthreads();
  f32x4 oc[3][4];
#pragma unroll
  for (int m=0;m<3;++m)
#pragma unroll
    for (int n=0;n<4;++n) oc[m][n] = (f32x4){0.f,0.f,0.f,0.f};
#pragma unroll
  for (int ks=0; ks<8; ++ks){
    const int kb = ks*64 + (q4<<4);
    short8 am[3], bm[4];
#pragma unroll
    for (int m=0;m<3;++m){
      const int r = m*16 + cl;
      am[m] = *(const short8*)((const char*)Mo + r*512 + (kb ^ ((r&7)<<4)));
    }
#pragma unroll
    for (int n=0;n<4;++n){
      const int nn = (w<<6) + n*16 + cl;
      bm[n] = *(const short8*)(moW + (long)nn*256 + ks*32 + q4*8);
    }
#pragma unroll
    for (int m=0;m<3;++m)
#pragma unroll
      for (int n=0;n<4;++n)
        oc[m][n] = __builtin_amdgcn_mfma_f32_16x16x32_bf16(am[m], bm[n], oc[m][n], 0,0,0);
  }
#pragma unroll
  for (int m=0;m<3;++m)
#pragma unroll
    for (int n=0;n<4;++n)
#pragma unroll
      for (int i=0;i<4;++i){
        const int row = m*16 + (q4<<2) + i;
        if (row < 39){
          const int col = (w<<6) + n*16 + cl;
          const float v = oc[m][n][i] + moB[col] + xf[(((long)(b*39+row))<<8) + col];
          flatb[(long)b*9984 + row*256 + col] = f2bf(v);
        }
      }
}

// ---------------------------------------------------------------------------
// Embedding + x0 bf16 + xln1 (normalized) write
// ---------------------------------------------------------------------------
__global__ __launch_bounds__(256)
void embed_k(const float* __restrict__ dense_x, const int* __restrict__ sparse_x,
             const float* __restrict__ W_dense, const float* __restrict__ b_dense,
             const float* __restrict__ emb,
             float* __restrict__ xf, unsigned short* __restrict__ x0b,
             unsigned short* __restrict__ xln1)
{
  const int bid = blockIdx.x;
  const int b = bid / 39, t = bid - b*39;
  const int c = threadIdx.x;
  float v;
  if (t < 13){
    const int j = t*256 + c;
    v = b_dense[j];
    const float* wr = W_dense + (long)j*13;
    const float* dx = dense_x + (long)b*13;
#pragma unroll
    for (int k2=0;k2<13;++k2) v = fmaf(dx[k2], wr[k2], v);
  } else {
    const int idx = sparse_x[b*26 + (t-13)];
    v = (idx == 0) ? 0.f : emb[((long)(t-13)*10001 + idx)*256 + c];
  }
  const long row = bid;
  xf[row*256 + c] = v;
  x0b[row*256 + c] = f2bf(v);
  float s1 = v, s2 = v*v;
#pragma unroll
  for (int off=32; off; off>>=1){ s1 += __shfl_xor(s1, off); s2 += __shfl_xor(s2, off); }
  __shared__ float r1[4], r2[4];
  const int lane = c & 63, wq = c >> 6;
  if (lane == 0){ r1[wq]=s1; r2[wq]=s2; }
  __syncthreads();
  const float S1 = r1[0]+r1[1]+r1[2]+r1[3];
  const float S2 = r2[0]+r2[1]+r2[2]+r2[3];
  const float mn = S1*(1.f/256.f);
  const float var = S2*(1.f/256.f) - mn*mn;
  const float s = rsqrtf(var+1e-5f);
  xln1[row*256 + c] = f2bf((v - mn)*s);
}

// ---------------------------------------------------------------------------
// AttentionResidual block mixing (+ xln1 write)
// ---------------------------------------------------------------------------
template<int NSRC>
__global__ __launch_bounds__(256)
void mix_k(float* __restrict__ xf,
           const unsigned short* __restrict__ s0,
           const unsigned short* __restrict__ s1p,
           const unsigned short* __restrict__ s2p,
           unsigned short* mout,
           const float* __restrict__ qvec, int qi,
           unsigned short* __restrict__ xln1)
{
  const int b = blockIdx.x;
  const int tid = threadIdx.x, lane = tid&63, w = tid>>6;
  const int c4 = lane << 2;
  f32x4 q = *(const f32x4*)(qvec + qi*256 + c4);
  float qq = q[0]*q[0]+q[1]*q[1]+q[2]*q[2]+q[3]*q[3];
#pragma unroll
  for (int off=32; off; off>>=1) qq += __shfl_xor(qq, off);
  const float qsc = 1.f/fmaxf(sqrtf(qq), 1e-12f);
#pragma unroll
  for (int e=0;e<4;++e) q[e] *= qsc;
  for (int t = w; t < 39; t += 4){
    const long ro = ((long)(b*39+t))*256 + c4;
    f32x4 v[NSRC];
#pragma unroll
    for (int n=0;n<NSRC;++n){
      if (n == NSRC-1) v[n] = *(const f32x4*)(xf + ro);
      else {
        const unsigned short* sp = (n==0)?s0:((n==1)?s1p:s2p);
        us4 u = *(const us4*)(sp + ro);
#pragma unroll
        for (int e=0;e<4;++e) v[n][e] = bf2f(u[e]);
      }
    }
    float lg[NSRC];
#pragma unroll
    for (int n=0;n<NSRC;++n){
      float nn = v[n][0]*v[n][0]+v[n][1]*v[n][1]+v[n][2]*v[n][2]+v[n][3]*v[n][3];
      float dd = q[0]*v[n][0]+q[1]*v[n][1]+q[2]*v[n][2]+q[3]*v[n][3];
#pragma unroll
      for (int off=32; off; off>>=1){ nn += __shfl_xor(nn,off); dd += __shfl_xor(dd,off); }
      lg[n] = dd / fmaxf(sqrtf(nn), 1e-12f);
    }
    float mx = lg[0];
#pragma unroll
    for (int n=1;n<NSRC;++n) mx = fmaxf(mx, lg[n]);
    float es = 0.f, e_[NSRC];
#pragma unroll
    for (int n=0;n<NSRC;++n){ e_[n] = __expf(lg[n]-mx); es += e_[n]; }
    const float inv = 1.f/es;
    f32x4 o = {0.f,0.f,0.f,0.f};
#pragma unroll
    for (int n=0;n<NSRC;++n){
      const float wt = e_[n]*inv;
#pragma unroll
      for (int e=0;e<4;++e) o[e] = fmaf(wt, v[n][e], o[e]);
    }
    *(f32x4*)(xf + ro) = o;
    if (mout){
      us4 u;
#pragma unroll
      for (int e=0;e<4;++e) u[e] = f2bf(o[e]);
      *(us4*)(mout + ro) = u;
    }
    float s1 = o[0]+o[1]+o[2]+o[3];
    float s2 = o[0]*o[0]+o[1]*o[1]+o[2]*o[2]+o[3]*o[3];
#pragma unroll
    for (int off=32; off; off>>=1){ s1 += __shfl_xor(s1,off); s2 += __shfl_xor(s2,off); }
    const float mn = s1*(1.f/256.f);
    const float var = s2*(1.f/256.f)-mn*mn;
    const float s = rsqrtf(var+1e-5f);
    const float c = -mn*s;
    us4 u2;
#pragma unroll
    for (int e=0;e<4;++e) u2[e] = f2bf(o[e]*s + c);
    *(us4*)(xln1 + ro) = u2;
  }
}

__global__ __launch_bounds__(256)
void head2_k(const unsigned short* __restrict__ h1h, const float* __restrict__ Wo2,
             const float* __restrict__ bo2, float* __restrict__ outp)
{
  const int b = blockIdx.x*4 + (threadIdx.x>>6);
  const int lane = threadIdx.x & 63;
  float s = 0.f;
#pragma unroll
  for (int g=0; g<2; ++g){
    const int base = lane*16 + g*8;
    short8 v8 = *(const short8*)(h1h + (long)b*1024 + base);
#pragma unroll
    for (int e=0;e<8;++e) s = fmaf(bf2f((unsigned short)v8[e]), Wo2[base+e], s);
  }
#pragma unroll
  for (int off=32; off; off>>=1) s += __shfl_xor(s, off);
  if (lane==0) outp[b] = s + bo2[0];
}

// ------------------------- weight prep kernels ------------------------------
__global__ void cvt_k(const float* __restrict__ src, unsigned short* __restrict__ dst, long n){
  const long i = (long)blockIdx.x*256 + threadIdx.x;
  if (i < n) dst[i] = f2bf(src[i]);
}
__global__ void prep_qkv_k(const float* Wq, const float* Wk, const float* Wv,
                           const float* g, unsigned short* dst){
  const int n = blockIdx.x, i = blockIdx.y, k = threadIdx.x;
  const int sel = n >> 8, nn = n & 255;
  const float* W = sel==0?Wq:(sel==1?Wk:Wv);
  dst[((long)i*768 + n)*256 + k] = f2bf(W[((long)i*256+nn)*256 + k] * g[i*256+k]);
}
__global__ void prep_qkvb_k(const float* Wq,const float* Wk,const float* Wv,
                            const float* bq,const float* bk,const float* bv,
                            const float* beta, float* dst){
  const int n = blockIdx.x, i = blockIdx.y, k = threadIdx.x;
  const int sel = n>>8, nn = n&255;
  const float* W = sel==0?Wq:(sel==1?Wk:Wv);
  const float* bb = sel==0?bq:(sel==1?bk:bv);
  float v = beta[i*256+k] * W[((long)i*256+nn)*256+k];
  __shared__ float r[4];
#pragma unroll
  for (int off=32; off; off>>=1) v += __shfl_xor(v, off);
  if ((k&63)==0) r[k>>6] = v;
  __syncthreads();
  if (k==0) dst[i*768+n] = bb[i*256+nn] + r[0]+r[1]+r[2]+r[3];
}
__global__ void prep_w1_k(const float* W1, const float* g, unsigned short* dst){
  const int n = blockIdx.x, i = blockIdx.y, k = threadIdx.x;
  const long o = ((long)i*1024+n)*256 + k;
  dst[o] = f2bf(W1[o] * g[i*256+k]);
}
__global__ void prep_w1b_k(const float* W1, const float* b1, const float* beta, float* dst){
  const int n = blockIdx.x, i = blockIdx.y, k = threadIdx.x;
  float v = beta[i*256+k] * W1[((long)i*1024+n)*256+k];
  __shared__ float r[4];
#pragma unroll
  for (int off=32; off; off>>=1) v += __shfl_xor(v, off);
  if ((k&63)==0) r[k>>6] = v;
  __syncthreads();
  if (k==0) dst[i*1024+n] = b1[i*1024+n] + r[0]+r[1]+r[2]+r[3];
}
__global__ void prep_mha_k(const float* W, const float* g, unsigned short* dst){
  const int n = blockIdx.x, k = threadIdx.x;
  dst[n*256+k] = f2bf(W[n*256+k]*g[k]);
}
__global__ void prep_mhab_k(const float* W, const float* bb, const float* beta, float* dst){
  const int n = blockIdx.x, k = threadIdx.x;
  float v = beta[k]*W[n*256+k];
  __shared__ float r[4];
#pragma unroll
  for (int off=32; off; off>>=1) v += __shfl_xor(v, off);
  if ((k&63)==0) r[k>>6] = v;
  __syncthreads();
  if (k==0) dst[n] = bb[n] + r[0]+r[1]+r[2]+r[3];
}

// ---------------------------------------------------------------------------
extern "C" void kernel_launch(void* const* d_in, const int* in_sizes, int n_in,
                              void* d_out, int out_size, void* d_ws, size_t ws_size,
                              hipStream_t stream)
{
  (void)in_sizes; (void)n_in; (void)out_size; (void)ws_size;
  const float* dense_x  = (const float*)d_in[0];
  const int*   sparse_x = (const int*)d_in[1];
  const float* W_dense  = (const float*)d_in[2];
  const float* b_dense  = (const float*)d_in[3];
  const float* emb      = (const float*)d_in[4];
  const float* Wq = (const float*)d_in[5];
  const float* bq = (const float*)d_in[6];
  const float* Wk = (const float*)d_in[7];
  const float* bk = (const float*)d_in[8];
  const float* Wv = (const float*)d_in[9];
  const float* bv = (const float*)d_in[10];
  const float* W1 = (const float*)d_in[11];
  const float* b1 = (const float*)d_in[12];
  const float* W2 = (const float*)d_in[13];
  const float* b2 = (const float*)d_in[14];
  const float* n1g= (const float*)d_in[15];
  const float* n1b= (const float*)d_in[16];
  const float* n2g= (const float*)d_in[17];
  const float* n2b= (const float*)d_in[18];
  const float* qvec=(const float*)d_in[19];
  const float* mha_in_w = (const float*)d_in[20];
  const float* mha_in_b = (const float*)d_in[21];
  const float* mha_out_w= (const float*)d_in[22];
  const float* mha_out_b= (const float*)d_in[23];
  const float* ng = (const float*)d_in[24];
  const float* ngb= (const float*)d_in[25];
  const float* Wo1= (const float*)d_in[26];
  const float* bo1= (const float*)d_in[27];
  const float* Wo2= (const float*)d_in[28];
  const float* bo2= (const float*)d_in[29];

  char* ws = (char*)d_ws;
  size_t off = 0;
  auto alloc = [&](size_t bytes)->void*{ void* p = ws + off; off += (bytes + 255) & ~(size_t)255; return p; };
  float* xf            = (float*)alloc(163577856ull);           // [159744][256] f32
  unsigned short* qkh  = (unsigned short*)alloc(163577856ull);  // [159744][512] bf16 (Q|K)
  unsigned short* vT   = (unsigned short*)alloc(100663296ull);  // [4096][256][48] bf16
  unsigned short* x0b  = (unsigned short*)alloc(81788928ull);
  unsigned short* m1b  = (unsigned short*)alloc(81788928ull);   // aliased as flatb at end
  unsigned short* m2b  = (unsigned short*)alloc(81788928ull);   // aliased as hpart at end
  unsigned short* xln1 = (unsigned short*)alloc(81788928ull);
  unsigned short* h1h  = (unsigned short*)alloc(8388608ull);    // [4096][1024] bf16
  float* sB = (float*)alloc(638976ull);
  float* cB = (float*)alloc(638976ull);
  unsigned short* Wqkv_f = (unsigned short*)alloc(3145728ull);
  float* bqkv_f = (float*)alloc(24576ull);
  unsigned short* W1_f = (unsigned short*)alloc(4194304ull);
  float* b1_f = (float*)alloc(32768ull);
  unsigned short* W2_f = (unsigned short*)alloc(4194304ull);
  unsigned short* mhain_f = (unsigned short*)alloc(393216ull);
  float* mhainb_f = (float*)alloc(3072ull);
  unsigned short* mhaout_f = (unsigned short*)alloc(131072ull);
  unsigned short* Wo1_f = (unsigned short*)alloc(20447232ull);

  unsigned short* flatb = m1b;    // m1b dead after layer-5 mix
  float* hpart = (float*)m2b;     // m2b dead after layer-5 mix; 64MB <= 81.8MB

  // weight prep
  cvt_k<<<8192,256,0,stream>>>(W2, W2_f, 2097152L);
  cvt_k<<<256,256,0,stream>>>(mha_out_w, mhaout_f, 65536L);
  cvt_k<<<39936,256,0,stream>>>(Wo1, Wo1_f, 10223616L);
  prep_qkv_k<<<dim3(768,8),256,0,stream>>>(Wq,Wk,Wv,n1g,Wqkv_f);
  prep_qkvb_k<<<dim3(768,8),256,0,stream>>>(Wq,Wk,Wv,bq,bk,bv,n1b,bqkv_f);
  prep_w1_k<<<dim3(1024,8),256,0,stream>>>(W1,n2g,W1_f);
  prep_w1b_k<<<dim3(1024,8),256,0,stream>>>(W1,b1,n2b,b1_f);
  prep_mha_k<<<768,256,0,stream>>>(mha_in_w, ng, mhain_f);
  prep_mhab_k<<<768,256,0,stream>>>(mha_in_w, mha_in_b, ngb, mhainb_f);

  embed_k<<<159744,256,0,stream>>>(dense_x, sparse_x, W_dense, b_dense, emb, xf, x0b, xln1);

  for (int i = 0; i < 8; ++i){
    qkv_k<<<1248,256,0,stream>>>(xln1, Wqkv_f + (size_t)i*196608, bqkv_f + i*768, qkh, vT);
    attn_sig_k<<<4096,256,0,stream>>>(qkh, vT, xf, sB, cB);
    const int wx = (i==1 || i==3 || i==5) ? 0 : 1;
    ffn_k<<<2496,256,0,stream>>>(xf, sB, cB,
        W1_f + (size_t)i*262144, b1_f + i*1024,
        W2_f + (size_t)i*262144, b2 + i*256, xf, xln1, wx);
    if (i == 1)      mix_k<2><<<4096,256,0,stream>>>(xf, x0b, m1b, m2b, m1b, qvec, 1, xln1);
    else if (i == 3) mix_k<3><<<4096,256,0,stream>>>(xf, x0b, m1b, m2b, m2b, qvec, 2, xln1);
    else if (i == 5) mix_k<4><<<4096,256,0,stream>>>(xf, x0b, m1b, m2b, nullptr, qvec, 3, xln1);
  }
  qkv_k<<<1248,256,0,stream>>>(xln1, mhain_f, mhainb_f, qkh, vT);
  attn_fin_k<<<4096,256,0,stream>>>(qkh, vT, xf, mhaout_f, mha_out_b, flatb);
  hgemm_k<<<1024,256,0,stream>>>(flatb, Wo1_f, hpart);
  hred_k<<<4096,256,0,stream>>>(hpart, bo1, h1h);
  head2_k<<<1024,256,0,stream>>>(h1h, Wo2, bo2, (float*)d_out);
}

// Round 15
// 6192.518 us; speedup vs baseline: 1.5267x; 1.0739x over previous
//
#include <hip/hip_runtime.h>
#include <hip/hip_bf16.h>

typedef __attribute__((ext_vector_type(4))) float f32x4;
typedef __attribute__((ext_vector_type(8))) short short8;
typedef __attribute__((ext_vector_type(4))) unsigned short us4;

static __device__ __forceinline__ unsigned short f2bf(float f){
  return __builtin_bit_cast(unsigned short, __float2bfloat16(f));
}
static __device__ __forceinline__ float bf2f(unsigned short u){
  return __bfloat162float(__builtin_bit_cast(__hip_bfloat16, u));
}
static __device__ __forceinline__ short8 zero8(){
  short8 v;
#pragma unroll
  for (int e=0;e<8;++e) v[e]=0;
  return v;
}
// async global->LDS, 16B/lane; lds dest wave-uniform base + lane*16
static __device__ __forceinline__ void g2l16(const void* g, void* l){
  __builtin_amdgcn_global_load_lds(
    (const __attribute__((address_space(1))) unsigned int*)g,
    (__attribute__((address_space(3))) unsigned int*)l, 16, 0, 0);
}

// ---------------------------------------------------------------------------
// QKV GEMM: out[row][0..767] = xln1[row][:] @ Wqkv^T + bias. 128 rows/block.
// A staged ONCE in 64KB swizzled LDS; B fragments direct from L2 (393KB).
// R15: V-epilogue packs 4 consecutive-tt bf16 into one 8B store (4x fewer
// write transactions); pad rows zeroed once via hipMemsetAsync (no scatter).
// ---------------------------------------------------------------------------
__global__ __launch_bounds__(256)
void qkv_k(const unsigned short* __restrict__ Ap,   // xln1 [..][256]
           const unsigned short* __restrict__ Bp,   // Wqkv [768][256]
           const float* __restrict__ bias,          // [768]
           unsigned short* __restrict__ qk,         // [..][512]
           unsigned short* __restrict__ vT)         // [4096][256][48]
{
  __shared__ __align__(16) unsigned short As[128*256];  // 4 k-tiles [128][64] swizzled

  const int tid = threadIdx.x, lane = tid & 63, w = tid >> 6;
  const int cl = lane & 15, q4 = lane >> 4;
  const long rowBase = (long)blockIdx.x << 7;
  const int wm = (w >> 1) << 6, wn = (w & 1) << 6;

  // stage A: 4096 chunks of 16B; chunk c = kt*1024 + r*8 + x holds global x^(r&7)
#pragma unroll
  for (int it=0; it<16; ++it){
    const int c = (it<<8) + (w<<6) + lane;
    const int kt = c>>10, rem = c & 1023, r = rem>>3, x = rem&7;
    g2l16(Ap + (rowBase + r)*256 + (kt<<6) + (((x ^ (r&7)))<<3),
          As + (((it<<8) + (w<<6))<<3));
  }
  __syncthreads();

  for (int cb=0; cb<6; ++cb){
    f32x4 acc[4][4];
#pragma unroll
    for (int m=0;m<4;++m)
#pragma unroll
      for (int n=0;n<4;++n) acc[m][n] = (f32x4){0.f,0.f,0.f,0.f};
#pragma unroll
    for (int kt=0; kt<4; ++kt)
#pragma unroll
      for (int ks=0; ks<2; ++ks){
        const int kb = ks*64 + (q4<<4);
        short8 af[4], bf_[4];
#pragma unroll
        for (int m=0;m<4;++m){
          const int r = wm + m*16 + cl;
          af[m] = *(const short8*)((const char*)As + (kt<<14) + r*128 + (kb ^ ((r&7)<<4)));
        }
#pragma unroll
        for (int n=0;n<4;++n){
          const long rn = cb*128 + wn + n*16 + cl;
          bf_[n] = *(const short8*)(Bp + rn*256 + (kt<<6) + ks*32 + (q4<<3));
        }
#pragma unroll
        for (int m=0;m<4;++m)
#pragma unroll
          for (int n=0;n<4;++n)
            acc[m][n] = __builtin_amdgcn_mfma_f32_16x16x32_bf16(af[m], bf_[n], acc[m][n], 0,0,0);
      }
    // epilogue for this col-block
#pragma unroll
    for (int n=0;n<4;++n){
      const int col = cb*128 + wn + n*16 + cl;
      const float bi = bias[col];
#pragma unroll
      for (int m=0;m<4;++m){
        const long r0 = rowBase + wm + m*16 + (q4<<2);
        if (col < 512){
#pragma unroll
          for (int i=0;i<4;++i)
            qk[(r0+i)*512 + col] = f2bf(acc[m][n][i] + bi);
        } else {
          const int d = col - 512;
          const int bb0 = (int)(r0 / 39);
          const int tt0 = (int)(r0 - (long)bb0*39);
          if (tt0 <= 35){
            unsigned short pk[4];
#pragma unroll
            for (int i=0;i<4;++i) pk[i] = f2bf(acc[m][n][i] + bi);
            __builtin_memcpy(vT + ((long)bb0*256 + d)*48 + tt0, pk, 8);
          } else {
#pragma unroll
            for (int i=0;i<4;++i){
              const long row = r0 + i;
              const int bb = (int)(row / 39);
              const int tt = (int)(row - (long)bb*39);
              vT[((long)bb*256 + d)*48 + tt] = f2bf(acc[m][n][i] + bi);
            }
          }
        }
      }
    }
  }
}

// ---------------------------------------------------------------------------
// Head GEMM split-K: partial[ks][4096][1024] f32 over K-slice of 2496.
// R15: XCD-affinity encoding — the 32 blocks sharing an A-row-panel (8 cb x
// 4 ks) have id == rb (mod 8) so they land on ONE XCD: A-panel fetched once
// per XCD (654MB -> ~82MB HBM).
// ---------------------------------------------------------------------------
__global__ __launch_bounds__(256)
void hgemm_k(const unsigned short* __restrict__ Ap,   // flatb [4096][9984]
             const unsigned short* __restrict__ Bp,   // Wo1_f [1024][9984]
             float* __restrict__ part)                // [4][4096][1024] f32
{
  const int id = blockIdx.x;
  const int rb = (id & 7) | (((id >> 8) & 3) << 3);   // 0..31
  const int cb = (id >> 3) & 7;                        // 0..7
  const int kslice = (id >> 6) & 3;                    // 0..3
  const long rowBase = (long)rb << 7;
  const long colBase = (long)cb << 7;
  const int kBase = kslice * 2496;
  const int tid = threadIdx.x, lane = tid & 63, w = tid >> 6;
  const int wm = (w >> 1) << 6, wn = (w & 1) << 6;
  const int cl = lane & 15, q4 = lane >> 4;

  __shared__ __align__(16) unsigned short As[128*64];
  __shared__ __align__(16) unsigned short Bs[128*64];

  const char* bSrc[4]; unsigned short* bDst[4];
  const char* aSrc[4]; unsigned short* aDst[4];
#pragma unroll
  for (int g=0; g<4; ++g){
    const int c = (w<<8) + (g<<6) + lane;
    const int r = c>>3, x = c&7, c16 = x ^ (r&7);
    bSrc[g] = (const char*)(Bp + (colBase + r)*9984L + kBase) + c16*16;
    bDst[g] = Bs + (((w<<2)+g)<<9);
    aSrc[g] = (const char*)(Ap + (rowBase + r)*9984L + kBase) + c16*16;
    aDst[g] = As + (((w<<2)+g)<<9);
  }

  f32x4 acc[4][4];
#pragma unroll
  for (int m=0;m<4;++m)
#pragma unroll
    for (int n=0;n<4;++n) acc[m][n] = (f32x4){0.f,0.f,0.f,0.f};

  const int nk = 39;   // 2496 / 64
  for (int t=0; t<nk; ++t){
    if (t) __syncthreads();
    const long tb = (long)t << 7;
#pragma unroll
    for (int g=0; g<4; ++g){
      g2l16(bSrc[g] + tb, bDst[g]);
      g2l16(aSrc[g] + tb, aDst[g]);
    }
    __syncthreads();
#pragma unroll
    for (int ks=0; ks<2; ++ks){
      const int kb = ks*64 + (q4<<4);
      short8 af[4], bf_[4];
#pragma unroll
      for (int m=0;m<4;++m){
        const int r = wm + m*16 + cl;
        af[m] = *(const short8*)((const char*)As + r*128 + (kb ^ ((r&7)<<4)));
      }
#pragma unroll
      for (int n=0;n<4;++n){
        const int r = wn + n*16 + cl;
        bf_[n] = *(const short8*)((const char*)Bs + r*128 + (kb ^ ((r&7)<<4)));
      }
#pragma unroll
      for (int m=0;m<4;++m)
#pragma unroll
        for (int n=0;n<4;++n)
          acc[m][n] = __builtin_amdgcn_mfma_f32_16x16x32_bf16(af[m], bf_[n], acc[m][n], 0,0,0);
    }
  }

#pragma unroll
  for (int n=0;n<4;++n){
    const long col = colBase + wn + n*16 + cl;
#pragma unroll
    for (int m=0;m<4;++m){
      const long r0 = rowBase + wm + m*16 + (q4<<2);
#pragma unroll
      for (int i=0;i<4;++i)
        part[((long)kslice*4096 + r0 + i)*1024 + col] = acc[m][n][i];
    }
  }
}

// reduce 4 K-slices + bias -> relu -> bf16 h1h. 4096 blocks x 256 thr x 4 elems.
__global__ __launch_bounds__(256)
void hred_k(const float* __restrict__ part, const float* __restrict__ bo1,
            unsigned short* __restrict__ h1h)
{
  const long i4 = (((long)blockIdx.x << 8) + threadIdx.x) << 2;
  const int col = (int)(i4 & 1023);
  f32x4 s0 = *(const f32x4*)(part + i4);
  f32x4 s1 = *(const f32x4*)(part + 4194304L + i4);
  f32x4 s2 = *(const f32x4*)(part + 8388608L + i4);
  f32x4 s3 = *(const f32x4*)(part + 12582912L + i4);
  us4 u;
#pragma unroll
  for (int e=0;e<4;++e){
    const float v = s0[e] + s1[e] + s2[e] + s3[e] + bo1[col + e];
    u[e] = f2bf(fmaxf(v, 0.f));
  }
  *(us4*)(h1h + i4) = u;
}

// ---------------------------------------------------------------------------
// Fused FFN (R10 v6, best measured: 305us): 64 rows/block, 256 threads,
// LDS = W1c(32K)+W2c(32K)+Hs(8K) = 72KB -> 2 blocks/CU; regs 112+64=176
// under the (256,2) cap of 256 -> no spill, co-resident staging overlap.
// At its L2-BW roofline: 2496 blocks x 4MB weights = 10GB @ ~33 TB/s.
// ---------------------------------------------------------------------------
__global__ __launch_bounds__(256, 2)
void ffn_k(const float* __restrict__ xf_in,
           const float* __restrict__ sB, const float* __restrict__ cB,
           const unsigned short* __restrict__ W1p,  // [1024][256]
           const float* __restrict__ b1p,           // [1024]
           const unsigned short* __restrict__ W2p,  // [256][1024]
           const float* __restrict__ b2p,           // [256]
           float* __restrict__ xf,
           unsigned short* __restrict__ xln1, int writeXln)
{
  __shared__ __align__(16) unsigned short Wb1[64*256];  // 32KB, 4 k-tiles [64][64]
  __shared__ __align__(16) unsigned short Wb2[256*64];  // 32KB, [256][64] swizzled
  __shared__ __align__(16) unsigned short Hs[64*64];    // 8KB
  // epilogue scratch aliased onto Wb1 (dead after last H phase)
  float* part1 = (float*)Wb1;          // 256 f
  float* part2 = part1 + 256;          // 256 f
  float* sln   = part2 + 256;          // 64 f
  float* cln   = sln + 64;             // 64 f

  const int tid = threadIdx.x, lane = tid & 63, w = tid >> 6;
  const int cl = lane & 15, q4 = lane >> 4;
  const long rowBase = (long)blockIdx.x << 6;   // 64 rows/block

  // ---- A = LN2(x) in registers, MFMA fragment layout ----
  short8 af[8];
  {
    const int row = (w<<4) + cl;
    const float s = sB[rowBase + row], c = cB[rowBase + row];
    const float* src = xf_in + (rowBase + row)*256 + (q4<<3);
#pragma unroll
    for (int kt=0; kt<8; ++kt){
      f32x4 a = *(const f32x4*)(src + kt*32);
      f32x4 b = *(const f32x4*)(src + kt*32 + 4);
      short8 v;
#pragma unroll
      for (int e=0;e<4;++e){ v[e] = (short)f2bf(a[e]*s + c); v[4+e] = (short)f2bf(b[e]*s + c); }
      af[kt] = v;
    }
  }

  // acc: wave w -> rows 0..63 (m), cols [64w, 64w+64) (n)
  f32x4 acc[4][4];
#pragma unroll
  for (int m=0;m<4;++m)
#pragma unroll
    for (int n=0;n<4;++n) acc[m][n] = (f32x4){0.f,0.f,0.f,0.f};

  for (int j=0; j<16; ++j){
    const int ffbase = j<<6;
    __syncthreads();   // prev chunk's W/Hs readers done
    // stage W1c [64 ff][256 k] (2048x16B) + W2c [256 out][64 ff] (2048x16B)
#pragma unroll
    for (int it=0; it<8; ++it){
      const int c = (it<<8) + tid;
      { // W1: 4 k-tiles of [64][64]; chunk c = kt*512 + rr*8 + xs
        const int kt = c>>9, cc = c&511, rr = cc>>3, xs = cc&7;
        g2l16(W1p + ((long)(ffbase+rr))*256 + (kt<<6) + ((xs^(rr&7))<<3),
              Wb1 + (((it<<8) + (w<<6))<<3));
      }
      { // W2: rows = out cols (256), 64-ff slice; chunk c = rr*8 + xs
        const int rr = c>>3, xs = c&7;
        g2l16(W2p + (long)rr*1024 + ffbase + ((xs^(rr&7))<<3),
              Wb2 + (((it<<8) + (w<<6))<<3));
      }
    }
    float b1v[4];
#pragma unroll
    for (int n=0;n<4;++n) b1v[n] = b1p[ffbase + n*16 + cl];
    __syncthreads();   // staged (vmcnt drained by barrier)

    // H = A @ W1c^T : wave w -> rows [16w,16w+16) x 64 ff cols, A from regs
    f32x4 hacc[4];
#pragma unroll
    for (int n=0;n<4;++n) hacc[n] = (f32x4){0.f,0.f,0.f,0.f};
#pragma unroll
    for (int kt2=0; kt2<4; ++kt2)
#pragma unroll
      for (int ks=0; ks<2; ++ks){
        const int kb = ks*64 + (q4<<4);
        const short8 a = af[kt2*2 + ks];
#pragma unroll
        for (int n=0;n<4;++n){
          const int rn = n*16 + cl;
          short8 bf_ = *(const short8*)((const char*)Wb1 + (kt2<<13) + rn*128 + (kb ^ ((rn&7)<<4)));
          hacc[n] = __builtin_amdgcn_mfma_f32_16x16x32_bf16(a, bf_, hacc[n], 0,0,0);
        }
      }
#pragma unroll
    for (int n=0;n<4;++n)
#pragma unroll
      for (int i=0;i<4;++i){
        const int hr = (w<<4) + (q4<<2) + i, hc = n*16 + cl;
        const float hv = fmaxf(hacc[n][i] + b1v[n], 0.f);
        *(unsigned short*)((char*)Hs + hr*128 + ((hc*2) ^ ((hr&7)<<4))) = f2bf(hv);
      }
    __syncthreads();   // Hs visible

    // OUT += Hs @ W2c^T : wave w -> cols [64w,64w+64); both from LDS
#pragma unroll
    for (int ks=0; ks<2; ++ks){
      const int kb = ks*64 + (q4<<4);
      short8 am[4], bm[4];
#pragma unroll
      for (int m=0;m<4;++m){
        const int r = m*16 + cl;
        am[m] = *(const short8*)((const char*)Hs + r*128 + (kb ^ ((r&7)<<4)));
      }
#pragma unroll
      for (int n=0;n<4;++n){
        const int r = (w<<6) + n*16 + cl;
        bm[n] = *(const short8*)((const char*)Wb2 + r*128 + (kb ^ ((r&7)<<4)));
      }
#pragma unroll
      for (int m=0;m<4;++m)
#pragma unroll
        for (int n=0;n<4;++n)
          acc[m][n] = __builtin_amdgcn_mfma_f32_16x16x32_bf16(am[m], bm[n], acc[m][n], 0,0,0);
    }
  }

  // ---- epilogue: residual, xf write, LN1 stats, xln1 write ----
#pragma unroll
  for (int n=0;n<4;++n){
    const int col = (w<<6) + n*16 + cl;
    const float bi = b2p[col];
#pragma unroll
    for (int m=0;m<4;++m)
#pragma unroll
      for (int i=0;i<4;++i){
        const int row = m*16 + (q4<<2) + i;
        const long gi = (rowBase + row)*256 + col;
        const float v = acc[m][n][i] + bi + xf[gi];
        acc[m][n][i] = v;
        xf[gi] = v;
      }
  }
  __syncthreads();   // Wb1/Wb2/Hs fully dead before aliasing scratch
#pragma unroll
  for (int m=0;m<4;++m)
#pragma unroll
    for (int i=0;i<4;++i){
      float s1 = 0.f, s2 = 0.f;
#pragma unroll
      for (int n=0;n<4;++n){ const float v = acc[m][n][i]; s1 += v; s2 += v*v; }
#pragma unroll
      for (int off=8; off; off>>=1){ s1 += __shfl_xor(s1, off, 16); s2 += __shfl_xor(s2, off, 16); }
      const int row = m*16 + (q4<<2) + i;
      if (cl == 0){ part1[row*4 + w] = s1; part2[row*4 + w] = s2; }
    }
  __syncthreads();
  if (tid < 64){
    const float S1 = part1[tid*4]+part1[tid*4+1]+part1[tid*4+2]+part1[tid*4+3];
    const float S2 = part2[tid*4]+part2[tid*4+1]+part2[tid*4+2]+part2[tid*4+3];
    const float mn = S1*(1.f/256.f);
    const float var = S2*(1.f/256.f) - mn*mn;
    const float s = rsqrtf(var + 1e-5f);
    sln[tid] = s; cln[tid] = -mn*s;
  }
  __syncthreads();
  if (writeXln){
#pragma unroll
    for (int m=0;m<4;++m)
#pragma unroll
      for (int i=0;i<4;++i){
        const int row = m*16 + (q4<<2) + i;
        const float s = sln[row], c = cln[row];
#pragma unroll
        for (int n=0;n<4;++n){
          const int col = (w<<6) + n*16 + cl;
          xln1[(rowBase + row)*256 + col] = f2bf(acc[m][n][i]*s + c);
        }
      }
  }
}

// ---------------------------------------------------------------------------
// Sigmoid (HSTU) attention. One block = one batch item, 2 heads/wave.
// ---------------------------------------------------------------------------
__global__ __launch_bounds__(256)
void attn_sig_k(const unsigned short* __restrict__ qkb,
                const unsigned short* __restrict__ vT,
                float* xf, float* __restrict__ sB, float* __restrict__ cB)
{
  __shared__ __align__(16) unsigned short Ps[4*48*64];
  __shared__ float part[312];

  const int b = blockIdx.x;
  const int tid = threadIdx.x, lane = tid & 63, w = tid >> 6;
  const int cl = lane & 15, q4 = lane >> 4;
  unsigned short* P = Ps + w*3072;
  const unsigned short* qb = qkb + (long)b*39*512;
  const unsigned short* vbb = vT + (long)b*256*48;

  if (lane < 48){
    const int r = lane;
    *(short8*)((char*)P + r*128 + (96  ^ ((r&7)<<4))) = zero8();
    *(short8*)((char*)P + r*128 + (112 ^ ((r&7)<<4))) = zero8();
  }

  float ps1[3][4], ps2[3][4];
#pragma unroll
  for (int m=0;m<3;++m)
#pragma unroll
    for (int i=0;i<4;++i){ ps1[m][i]=0.f; ps2[m][i]=0.f; }

#pragma unroll
  for (int hh=0; hh<2; ++hh){
    const int h = (w<<1) + hh;
    f32x4 sac[3][3];
#pragma unroll
    for (int m=0;m<3;++m)
#pragma unroll
      for (int n=0;n<3;++n) sac[m][n] = (f32x4){0.f,0.f,0.f,0.f};
    short8 aq[3], bk8[3];
#pragma unroll
    for (int m=0;m<3;++m){
      const int r = m*16 + cl;
      aq[m] = (r < 39) ? *(const short8*)(qb + (long)r*512 + h*32 + q4*8) : zero8();
    }
#pragma unroll
    for (int n=0;n<3;++n){
      const int r = n*16 + cl;
      bk8[n] = (r < 39) ? *(const short8*)(qb + (long)r*512 + 256 + h*32 + q4*8) : zero8();
    }
#pragma unroll
    for (int m=0;m<3;++m)
#pragma unroll
      for (int n=0;n<3;++n)
        sac[m][n] = __builtin_amdgcn_mfma_f32_16x16x32_bf16(aq[m], bk8[n], sac[m][n], 0,0,0);
#pragma unroll
    for (int m=0;m<3;++m)
#pragma unroll
      for (int n=0;n<3;++n)
#pragma unroll
        for (int i=0;i<4;++i){
          const int row = m*16 + (q4<<2) + i, col = n*16 + cl;
          const float pv = 1.f/(1.f + __expf(-sac[m][n][i]*0.0625f));
          *(unsigned short*)((char*)P + row*128 + ((col*2) ^ ((row&7)<<4))) = f2bf(pv);
        }
    f32x4 aoc[3][2];
#pragma unroll
    for (int m=0;m<3;++m)
#pragma unroll
      for (int n=0;n<2;++n) aoc[m][n] = (f32x4){0.f,0.f,0.f,0.f};
#pragma unroll
    for (int ks=0; ks<2; ++ks){
      const int kb = ks*64 + (q4<<4);
      short8 pa[3], vb[2];
#pragma unroll
      for (int m=0;m<3;++m){
        const int r = m*16 + cl;
        pa[m] = *(const short8*)((const char*)P + r*128 + (kb ^ ((r&7)<<4)));
      }
#pragma unroll
      for (int n=0;n<2;++n){
        vb[n] = zero8();
        if (ks == 0 || q4 < 2)
          vb[n] = *(const short8*)(vbb + (long)(h*32 + n*16 + cl)*48 + ks*32 + q4*8);
      }
#pragma unroll
      for (int m=0;m<3;++m)
#pragma unroll
        for (int n=0;n<2;++n)
          aoc[m][n] = __builtin_amdgcn_mfma_f32_16x16x32_bf16(pa[m], vb[n], aoc[m][n], 0,0,0);
    }
#pragma unroll
    for (int m=0;m<3;++m)
#pragma unroll
      for (int n=0;n<2;++n)
#pragma unroll
        for (int i=0;i<4;++i){
          const int row = m*16 + (q4<<2) + i;
          if (row < 39){
            const long gi = (((long)(b*39+row))<<8) + h*32 + n*16 + cl;
            const float nv = xf[gi] + aoc[m][n][i];
            xf[gi] = nv;
            ps1[m][i] += nv; ps2[m][i] += nv*nv;
          }
        }
  }
#pragma unroll
  for (int m=0;m<3;++m)
#pragma unroll
    for (int i=0;i<4;++i){
      float a1 = ps1[m][i], a2 = ps2[m][i];
#pragma unroll
      for (int off=8; off; off>>=1){ a1 += __shfl_xor(a1, off, 16); a2 += __shfl_xor(a2, off, 16); }
      const int row = m*16 + (q4<<2) + i;
      if (cl == 0 && row < 39){ part[row*8 + (w<<1)] = a1; part[row*8 + (w<<1) + 1] = a2; }
    }
  __syncthreads();
  if (tid < 39){
    const float S1 = part[tid*8]+part[tid*8+2]+part[tid*8+4]+part[tid*8+6];
    const float S2 = part[tid*8+1]+part[tid*8+3]+part[tid*8+5]+part[tid*8+7];
    const float mn = S1*(1.f/256.f);
    const float var = S2*(1.f/256.f) - mn*mn;
    const float s = rsqrtf(var + 1e-5f);
    sB[b*39+tid] = s; cB[b*39+tid] = -mn*s;
  }
}

// ---------------------------------------------------------------------------
// Final softmax MHA + out-proj + residual -> flat bf16 [B][9984]
// ---------------------------------------------------------------------------
__global__ __launch_bounds__(256)
void attn_fin_k(const unsigned short* __restrict__ qkb,
                const unsigned short* __restrict__ vT,
                const float* __restrict__ xf,
                const unsigned short* __restrict__ moW,
                const float* __restrict__ moB,
                unsigned short* __restrict__ flatb)
{
  __shared__ __align__(16) unsigned short Ps[4*48*64];
  __shared__ __align__(16) unsigned short Mo[48*256];

  const int b = blockIdx.x;
  const int tid = threadIdx.x, lane = tid & 63, w = tid >> 6;
  const int cl = lane & 15, q4 = lane >> 4;
  unsigned short* P = Ps + w*3072;
  const unsigned short* qb = qkb + (long)b*39*512;
  const unsigned short* vbb = vT + (long)b*256*48;
  const float SC = 0.17677669529663687f;

  if (lane < 48){
    const int r = lane;
    *(short8*)((char*)P + r*128 + (96  ^ ((r&7)<<4))) = zero8();
    *(short8*)((char*)P + r*128 + (112 ^ ((r&7)<<4))) = zero8();
  }

#pragma unroll
  for (int hh=0; hh<2; ++hh){
    const int h = (w<<1) + hh;
    f32x4 sac[3][3];
#pragma unroll
    for (int m=0;m<3;++m)
#pragma unroll
      for (int n=0;n<3;++n) sac[m][n] = (f32x4){0.f,0.f,0.f,0.f};
    short8 aq[3], bk8[3];
#pragma unroll
    for (int m=0;m<3;++m){
      const int r = m*16 + cl;
      aq[m] = (r < 39) ? *(const short8*)(qb + (long)r*512 + h*32 + q4*8) : zero8();
    }
#pragma unroll
    for (int n=0;n<3;++n){
      const int r = n*16 + cl;
      bk8[n] = (r < 39) ? *(const short8*)(qb + (long)r*512 + 256 + h*32 + q4*8) : zero8();
    }
#pragma unroll
    for (int m=0;m<3;++m)
#pragma unroll
      for (int n=0;n<3;++n)
        sac[m][n] = __builtin_amdgcn_mfma_f32_16x16x32_bf16(aq[m], bk8[n], sac[m][n], 0,0,0);
#pragma unroll
    for (int m=0;m<3;++m)
#pragma unroll
      for (int i=0;i<4;++i){
        const float v0 = sac[m][0][i]*SC, v1 = sac[m][1][i]*SC, v2 = sac[m][2][i]*SC;
        const bool c2ok = (32 + cl) < 39;
        float mx = fmaxf(v0, v1);
        if (c2ok) mx = fmaxf(mx, v2);
#pragma unroll
        for (int off=8; off; off>>=1) mx = fmaxf(mx, __shfl_xor(mx, off, 16));
        const float e0 = __expf(v0-mx), e1 = __expf(v1-mx);
        const float e2 = c2ok ? __expf(v2-mx) : 0.f;
        float s = e0+e1+e2;
#pragma unroll
        for (int off=8; off; off>>=1) s += __shfl_xor(s, off, 16);
        const float inv = 1.f/s;
        const int row = m*16 + (q4<<2) + i;
        *(unsigned short*)((char*)P + row*128 + (((cl   )*2) ^ ((row&7)<<4))) = f2bf(e0*inv);
        *(unsigned short*)((char*)P + row*128 + (((16+cl)*2) ^ ((row&7)<<4))) = f2bf(e1*inv);
        *(unsigned short*)((char*)P + row*128 + (((32+cl)*2) ^ ((row&7)<<4))) = f2bf(e2*inv);
      }
    f32x4 aoc[3][2];
#pragma unroll
    for (int m=0;m<3;++m)
#pragma unroll
      for (int n=0;n<2;++n) aoc[m][n] = (f32x4){0.f,0.f,0.f,0.f};
#pragma unroll
    for (int ks=0; ks<2; ++ks){
      const int kb = ks*64 + (q4<<4);
      short8 pa[3], vb[2];
#pragma unroll
      for (int m=0;m<3;++m){
        const int r = m*16 + cl;
        pa[m] = *(const short8*)((const char*)P + r*128 + (kb ^ ((r&7)<<4)));
      }
#pragma unroll
      for (int n=0;n<2;++n){
        vb[n] = zero8();
        if (ks == 0 || q4 < 2)
          vb[n] = *(const short8*)(vbb + (long)(h*32 + n*16 + cl)*48 + ks*32 + q4*8);
      }
#pragma unroll
      for (int m=0;m<3;++m)
#pragma unroll
        for (int n=0;n<2;++n)
          aoc[m][n] = __builtin_amdgcn_mfma_f32_16x16x32_bf16(pa[m], vb[n], aoc[m][n], 0,0,0);
    }
#pragma unroll
    for (int m=0;m<3;++m)
#pragma unroll
      for (int n=0;n<2;++n)
#pragma unroll
        for (int i=0;i<4;++i){
          const int row = m*16 + (q4<<2) + i;
          const int colq = h*32 + n*16 + cl;
          *(unsigned short*)((char*)Mo + row*512 + ((colq*2) ^ ((row&7)<<4))) = f2bf(aoc[m][n][i]);
        }
  }
  __syncthreads();
  f32x4 oc[3][4];
#pragma unroll
  for (int m=0;m<3;++m)
#pragma unroll
    for (int n=0;n<4;++n) oc[m][n] = (f32x4){0.f,0.f,0.f,0.f};
#pragma unroll
  for (int ks=0; ks<8; ++ks){
    const int kb = ks*64 + (q4<<4);
    short8 am[3], bm[4];
#pragma unroll
    for (int m=0;m<3;++m){
      const int r = m*16 + cl;
      am[m] = *(const short8*)((const char*)Mo + r*512 + (kb ^ ((r&7)<<4)));
    }
#pragma unroll
    for (int n=0;n<4;++n){
      const int nn = (w<<6) + n*16 + cl;
      bm[n] = *(const short8*)(moW + (long)nn*256 + ks*32 + q4*8);
    }
#pragma unroll
    for (int m=0;m<3;++m)
#pragma unroll
      for (int n=0;n<4;++n)
        oc[m][n] = __builtin_amdgcn_mfma_f32_16x16x32_bf16(am[m], bm[n], oc[m][n], 0,0,0);
  }
#pragma unroll
  for (int m=0;m<3;++m)
#pragma unroll
    for (int n=0;n<4;++n)
#pragma unroll
      for (int i=0;i<4;++i){
        const int row = m*16 + (q4<<2) + i;
        if (row < 39){
          const int col = (w<<6) + n*16 + cl;
          const float v = oc[m][n][i] + moB[col] + xf[(((long)(b*39+row))<<8) + col];
          flatb[(long)b*9984 + row*256 + col] = f2bf(v);
        }
      }
}

// ---------------------------------------------------------------------------
// Embedding + x0 bf16 + xln1 (normalized) write
// ---------------------------------------------------------------------------
__global__ __launch_bounds__(256)
void embed_k(const float* __restrict__ dense_x, const int* __restrict__ sparse_x,
             const float* __restrict__ W_dense, const float* __restrict__ b_dense,
             const float* __restrict__ emb,
             float* __restrict__ xf, unsigned short* __restrict__ x0b,
             unsigned short* __restrict__ xln1)
{
  const int bid = blockIdx.x;
  const int b = bid / 39, t = bid - b*39;
  const int c = threadIdx.x;
  float v;
  if (t < 13){
    const int j = t*256 + c;
    v = b_dense[j];
    const float* wr = W_dense + (long)j*13;
    const float* dx = dense_x + (long)b*13;
#pragma unroll
    for (int k2=0;k2<13;++k2) v = fmaf(dx[k2], wr[k2], v);
  } else {
    const int idx = sparse_x[b*26 + (t-13)];
    v = (idx == 0) ? 0.f : emb[((long)(t-13)*10001 + idx)*256 + c];
  }
  const long row = bid;
  xf[row*256 + c] = v;
  x0b[row*256 + c] = f2bf(v);
  float s1 = v, s2 = v*v;
#pragma unroll
  for (int off=32; off; off>>=1){ s1 += __shfl_xor(s1, off); s2 += __shfl_xor(s2, off); }
  __shared__ float r1[4], r2[4];
  const int lane = c & 63, wq = c >> 6;
  if (lane == 0){ r1[wq]=s1; r2[wq]=s2; }
  __syncthreads();
  const float S1 = r1[0]+r1[1]+r1[2]+r1[3];
  const float S2 = r2[0]+r2[1]+r2[2]+r2[3];
  const float mn = S1*(1.f/256.f);
  const float var = S2*(1.f/256.f) - mn*mn;
  const float s = rsqrtf(var+1e-5f);
  xln1[row*256 + c] = f2bf((v - mn)*s);
}

// ---------------------------------------------------------------------------
// AttentionResidual block mixing (+ xln1 write)
// ---------------------------------------------------------------------------
template<int NSRC>
__global__ __launch_bounds__(256)
void mix_k(float* __restrict__ xf,
           const unsigned short* __restrict__ s0,
           const unsigned short* __restrict__ s1p,
           const unsigned short* __restrict__ s2p,
           unsigned short* mout,
           const float* __restrict__ qvec, int qi,
           unsigned short* __restrict__ xln1)
{
  const int b = blockIdx.x;
  const int tid = threadIdx.x, lane = tid&63, w = tid>>6;
  const int c4 = lane << 2;
  f32x4 q = *(const f32x4*)(qvec + qi*256 + c4);
  float qq = q[0]*q[0]+q[1]*q[1]+q[2]*q[2]+q[3]*q[3];
#pragma unroll
  for (int off=32; off; off>>=1) qq += __shfl_xor(qq, off);
  const float qsc = 1.f/fmaxf(sqrtf(qq), 1e-12f);
#pragma unroll
  for (int e=0;e<4;++e) q[e] *= qsc;
  for (int t = w; t < 39; t += 4){
    const long ro = ((long)(b*39+t))*256 + c4;
    f32x4 v[NSRC];
#pragma unroll
    for (int n=0;n<NSRC;++n){
      if (n == NSRC-1) v[n] = *(const f32x4*)(xf + ro);
      else {
        const unsigned short* sp = (n==0)?s0:((n==1)?s1p:s2p);
        us4 u = *(const us4*)(sp + ro);
#pragma unroll
        for (int e=0;e<4;++e) v[n][e] = bf2f(u[e]);
      }
    }
    float lg[NSRC];
#pragma unroll
    for (int n=0;n<NSRC;++n){
      float nn = v[n][0]*v[n][0]+v[n][1]*v[n][1]+v[n][2]*v[n][2]+v[n][3]*v[n][3];
      float dd = q[0]*v[n][0]+q[1]*v[n][1]+q[2]*v[n][2]+q[3]*v[n][3];
#pragma unroll
      for (int off=32; off; off>>=1){ nn += __shfl_xor(nn,off); dd += __shfl_xor(dd,off); }
      lg[n] = dd / fmaxf(sqrtf(nn), 1e-12f);
    }
    float mx = lg[0];
#pragma unroll
    for (int n=1;n<NSRC;++n) mx = fmaxf(mx, lg[n]);
    float es = 0.f, e_[NSRC];
#pragma unroll
    for (int n=0;n<NSRC;++n){ e_[n] = __expf(lg[n]-mx); es += e_[n]; }
    const float inv = 1.f/es;
    f32x4 o = {0.f,0.f,0.f,0.f};
#pragma unroll
    for (int n=0;n<NSRC;++n){
      const float wt = e_[n]*inv;
#pragma unroll
      for (int e=0;e<4;++e) o[e] = fmaf(wt, v[n][e], o[e]);
    }
    *(f32x4*)(xf + ro) = o;
    if (mout){
      us4 u;
#pragma unroll
      for (int e=0;e<4;++e) u[e] = f2bf(o[e]);
      *(us4*)(mout + ro) = u;
    }
    float s1 = o[0]+o[1]+o[2]+o[3];
    float s2 = o[0]*o[0]+o[1]*o[1]+o[2]*o[2]+o[3]*o[3];
#pragma unroll
    for (int off=32; off; off>>=1){ s1 += __shfl_xor(s1,off); s2 += __shfl_xor(s2,off); }
    const float mn = s1*(1.f/256.f);
    const float var = s2*(1.f/256.f)-mn*mn;
    const float s = rsqrtf(var+1e-5f);
    const float c = -mn*s;
    us4 u2;
#pragma unroll
    for (int e=0;e<4;++e) u2[e] = f2bf(o[e]*s + c);
    *(us4*)(xln1 + ro) = u2;
  }
}

__global__ __launch_bounds__(256)
void head2_k(const unsigned short* __restrict__ h1h, const float* __restrict__ Wo2,
             const float* __restrict__ bo2, float* __restrict__ outp)
{
  const int b = blockIdx.x*4 + (threadIdx.x>>6);
  const int lane = threadIdx.x & 63;
  float s = 0.f;
#pragma unroll
  for (int g=0; g<2; ++g){
    const int base = lane*16 + g*8;
    short8 v8 = *(const short8*)(h1h + (long)b*1024 + base);
#pragma unroll
    for (int e=0;e<8;++e) s = fmaf(bf2f((unsigned short)v8[e]), Wo2[base+e], s);
  }
#pragma unroll
  for (int off=32; off; off>>=1) s += __shfl_xor(s, off);
  if (lane==0) outp[b] = s + bo2[0];
}

// ------------------------- weight prep kernels ------------------------------
__global__ void cvt_k(const float* __restrict__ src, unsigned short* __restrict__ dst, long n){
  const long i = (long)blockIdx.x*256 + threadIdx.x;
  if (i < n) dst[i] = f2bf(src[i]);
}
__global__ void prep_qkv_k(const float* Wq, const float* Wk, const float* Wv,
                           const float* g, unsigned short* dst){
  const int n = blockIdx.x, i = blockIdx.y, k = threadIdx.x;
  const int sel = n >> 8, nn = n & 255;
  const float* W = sel==0?Wq:(sel==1?Wk:Wv);
  dst[((long)i*768 + n)*256 + k] = f2bf(W[((long)i*256+nn)*256 + k] * g[i*256+k]);
}
__global__ void prep_qkvb_k(const float* Wq,const float* Wk,const float* Wv,
                            const float* bq,const float* bk,const float* bv,
                            const float* beta, float* dst){
  const int n = blockIdx.x, i = blockIdx.y, k = threadIdx.x;
  const int sel = n>>8, nn = n&255;
  const float* W = sel==0?Wq:(sel==1?Wk:Wv);
  const float* bb = sel==0?bq:(sel==1?bk:bv);
  float v = beta[i*256+k] * W[((long)i*256+nn)*256+k];
  __shared__ float r[4];
#pragma unroll
  for (int off=32; off; off>>=1) v += __shfl_xor(v, off);
  if ((k&63)==0) r[k>>6] = v;
  __syncthreads();
  if (k==0) dst[i*768+n] = bb[i*256+nn] + r[0]+r[1]+r[2]+r[3];
}
__global__ void prep_w1_k(const float* W1, const float* g, unsigned short* dst){
  const int n = blockIdx.x, i = blockIdx.y, k = threadIdx.x;
  const long o = ((long)i*1024+n)*256 + k;
  dst[o] = f2bf(W1[o] * g[i*256+k]);
}
__global__ void prep_w1b_k(const float* W1, const float* b1, const float* beta, float* dst){
  const int n = blockIdx.x, i = blockIdx.y, k = threadIdx.x;
  float v = beta[i*256+k] * W1[((long)i*1024+n)*256+k];
  __shared__ float r[4];
#pragma unroll
  for (int off=32; off; off>>=1) v += __shfl_xor(v, off);
  if ((k&63)==0) r[k>>6] = v;
  __syncthreads();
  if (k==0) dst[i*1024+n] = b1[i*1024+n] + r[0]+r[1]+r[2]+r[3];
}
__global__ void prep_mha_k(const float* W, const float* g, unsigned short* dst){
  const int n = blockIdx.x, k = threadIdx.x;
  dst[n*256+k] = f2bf(W[n*256+k]*g[k]);
}
__global__ void prep_mhab_k(const float* W, const float* bb, const float* beta, float* dst){
  const int n = blockIdx.x, k = threadIdx.x;
  float v = beta[k]*W[n*256+k];
  __shared__ float r[4];
#pragma unroll
  for (int off=32; off; off>>=1) v += __shfl_xor(v, off);
  if ((k&63)==0) r[k>>6] = v;
  __syncthreads();
  if (k==0) dst[n] = bb[n] + r[0]+r[1]+r[2]+r[3];
}

// ---------------------------------------------------------------------------
extern "C" void kernel_launch(void* const* d_in, const int* in_sizes, int n_in,
                              void* d_out, int out_size, void* d_ws, size_t ws_size,
                              hipStream_t stream)
{
  (void)in_sizes; (void)n_in; (void)out_size; (void)ws_size;
  const float* dense_x  = (const float*)d_in[0];
  const int*   sparse_x = (const int*)d_in[1];
  const float* W_dense  = (const float*)d_in[2];
  const float* b_dense  = (const float*)d_in[3];
  const float* emb      = (const float*)d_in[4];
  const float* Wq = (const float*)d_in[5];
  const float* bq = (const float*)d_in[6];
  const float* Wk = (const float*)d_in[7];
  const float* bk = (const float*)d_in[8];
  const float* Wv = (const float*)d_in[9];
  const float* bv = (const float*)d_in[10];
  const float* W1 = (const float*)d_in[11];
  const float* b1 = (const float*)d_in[12];
  const float* W2 = (const float*)d_in[13];
  const float* b2 = (const float*)d_in[14];
  const float* n1g= (const float*)d_in[15];
  const float* n1b= (const float*)d_in[16];
  const float* n2g= (const float*)d_in[17];
  const float* n2b= (const float*)d_in[18];
  const float* qvec=(const float*)d_in[19];
  const float* mha_in_w = (const float*)d_in[20];
  const float* mha_in_b = (const float*)d_in[21];
  const float* mha_out_w= (const float*)d_in[22];
  const float* mha_out_b= (const float*)d_in[23];
  const float* ng = (const float*)d_in[24];
  const float* ngb= (const float*)d_in[25];
  const float* Wo1= (const float*)d_in[26];
  const float* bo1= (const float*)d_in[27];
  const float* Wo2= (const float*)d_in[28];
  const float* bo2= (const float*)d_in[29];

  char* ws = (char*)d_ws;
  size_t off = 0;
  auto alloc = [&](size_t bytes)->void*{ void* p = ws + off; off += (bytes + 255) & ~(size_t)255; return p; };
  float* xf            = (float*)alloc(163577856ull);           // [159744][256] f32
  unsigned short* qkh  = (unsigned short*)alloc(163577856ull);  // [159744][512] bf16 (Q|K)
  unsigned short* vT   = (unsigned short*)alloc(100663296ull);  // [4096][256][48] bf16
  unsigned short* x0b  = (unsigned short*)alloc(81788928ull);
  unsigned short* m1b  = (unsigned short*)alloc(81788928ull);   // aliased as flatb at end
  unsigned short* m2b  = (unsigned short*)alloc(81788928ull);   // aliased as hpart at end
  unsigned short* xln1 = (unsigned short*)alloc(81788928ull);
  unsigned short* h1h  = (unsigned short*)alloc(8388608ull);    // [4096][1024] bf16
  float* sB = (float*)alloc(638976ull);
  float* cB = (float*)alloc(638976ull);
  unsigned short* Wqkv_f = (unsigned short*)alloc(3145728ull);
  float* bqkv_f = (float*)alloc(24576ull);
  unsigned short* W1_f = (unsigned short*)alloc(4194304ull);
  float* b1_f = (float*)alloc(32768ull);
  unsigned short* W2_f = (unsigned short*)alloc(4194304ull);
  unsigned short* mhain_f = (unsigned short*)alloc(393216ull);
  float* mhainb_f = (float*)alloc(3072ull);
  unsigned short* mhaout_f = (unsigned short*)alloc(131072ull);
  unsigned short* Wo1_f = (unsigned short*)alloc(20447232ull);

  unsigned short* flatb = m1b;    // m1b dead after layer-5 mix
  float* hpart = (float*)m2b;     // m2b dead after layer-5 mix; 64MB <= 81.8MB

  // zero vT once (pads rows 39..47 stay zero; qkv only writes tt<39)
  hipMemsetAsync(vT, 0, 100663296ull, stream);

  // weight prep
  cvt_k<<<8192,256,0,stream>>>(W2, W2_f, 2097152L);
  cvt_k<<<256,256,0,stream>>>(mha_out_w, mhaout_f, 65536L);
  cvt_k<<<39936,256,0,stream>>>(Wo1, Wo1_f, 10223616L);
  prep_qkv_k<<<dim3(768,8),256,0,stream>>>(Wq,Wk,Wv,n1g,Wqkv_f);
  prep_qkvb_k<<<dim3(768,8),256,0,stream>>>(Wq,Wk,Wv,bq,bk,bv,n1b,bqkv_f);
  prep_w1_k<<<dim3(1024,8),256,0,stream>>>(W1,n2g,W1_f);
  prep_w1b_k<<<dim3(1024,8),256,0,stream>>>(W1,b1,n2b,b1_f);
  prep_mha_k<<<768,256,0,stream>>>(mha_in_w, ng, mhain_f);
  prep_mhab_k<<<768,256,0,stream>>>(mha_in_w, mha_in_b, ngb, mhainb_f);

  embed_k<<<159744,256,0,stream>>>(dense_x, sparse_x, W_dense, b_dense, emb, xf, x0b, xln1);

  for (int i = 0; i < 8; ++i){
    qkv_k<<<1248,256,0,stream>>>(xln1, Wqkv_f + (size_t)i*196608, bqkv_f + i*768, qkh, vT);
    attn_sig_k<<<4096,256,0,stream>>>(qkh, vT, xf, sB, cB);
    const int wx = (i==1 || i==3 || i==5) ? 0 : 1;
    ffn_k<<<2496,256,0,stream>>>(xf, sB, cB,
        W1_f + (size_t)i*262144, b1_f + i*1024,
        W2_f + (size_t)i*262144, b2 + i*256, xf, xln1, wx);
    if (i == 1)      mix_k<2><<<4096,256,0,stream>>>(xf, x0b, m1b, m2b, m1b, qvec, 1, xln1);
    else if (i == 3) mix_k<3><<<4096,256,0,stream>>>(xf, x0b, m1b, m2b, m2b, qvec, 2, xln1);
    else if (i == 5) mix_k<4><<<4096,256,0,stream>>>(xf, x0b, m1b, m2b, nullptr, qvec, 3, xln1);
  }
  qkv_k<<<1248,256,0,stream>>>(xln1, mhain_f, mhainb_f, qkh, vT);
  attn_fin_k<<<4096,256,0,stream>>>(qkh, vT, xf, mhaout_f, mha_out_b, flatb);
  hgemm_k<<<1024,256,0,stream>>>(flatb, Wo1_f, hpart);
  hred_k<<<4096,256,0,stream>>>(hpart, bo1, h1h);
  head2_k<<<1024,256,0,stream>>>(h1h, Wo2, bo2, (float*)d_out);
}